// Round 5
// baseline (152.426 us; speedup 1.0000x reference)
//
#include <hip/hip_runtime.h>
#include <math.h>

#define B_ 64
#define N_ 200
#define P_ 400
#define T_ 1200
#define STRIDE_ 25
#define EPS_ 1e-9f
#define KPAD 224
#define MB_ 240       // gemm M-tile (1200/5)
#define NPOOLW 11     // max windows spanned by a 240-frame tile (+1)

// ws layout (float offsets)
#define OFF_NPATT  0            // [N_][P_] f32 transposed normalized patterns (80000)
#define OFF_NPB16  80000        // [P_][KPAD] bf16 normalized patterns (89600 u16)
#define OFF_KEYVAL 124800       // [P_][4]
#define OFF_KEYIDX 126400       // [P_][4] int
#define OFF_PES    128000       // [B_][P_]
#define OFF_NORM   153600
#define OFF_ORTH   153601
#define OFF_XN     153604       // [B_][T_][KPAD] bf16 normalized frames (8,601,600)
#define OFF_GPOOL  8755204      // [2][B_][48][400] okey uints (2,457,600)
#define WS_FAST_FLOATS (8755204 + 2457600)

typedef float f4v __attribute__((ext_vector_type(4)));
typedef short s8v __attribute__((ext_vector_type(8)));
typedef short s4v __attribute__((ext_vector_type(4)));

__device__ inline unsigned short f2bf(float f) {
    union { float f; unsigned u; } v; v.f = f;
    unsigned r = v.u + 0x7FFFu + ((v.u >> 16) & 1u);
    return (unsigned short)(r >> 16);
}
__device__ inline unsigned okey(float f) {
    unsigned u = __float_as_uint(f);
    return (u & 0x80000000u) ? ~u : (u | 0x80000000u);
}
__device__ inline float dekey(unsigned k) {
    unsigned u = (k & 0x80000000u) ? (k & 0x7fffffffu) : ~k;
    return __uint_as_float(u);
}

// ---------------- pattern preprocessing: normalize rows, top-3, norm scalar ----
__global__ __launch_bounds__(64) void pat_kernel(const float* __restrict__ patterns,
                                                 float* __restrict__ ws) {
    int p = blockIdx.x;
    int lane = threadIdx.x;

    float v0 = patterns[p * N_ + lane];
    float v1 = patterns[p * N_ + lane + 64];
    float v2 = patterns[p * N_ + lane + 128];
    float v3 = (lane < 8) ? patterns[p * N_ + lane + 192] : 0.0f;

    float ss = v0 * v0 + v1 * v1 + v2 * v2 + v3 * v3;
    for (int off = 32; off; off >>= 1) ss += __shfl_down(ss, off);
    ss = __shfl(ss, 0);

    float rn = 1.0f / sqrtf(ss + EPS_);
    float s0 = v0 * rn, s1 = v1 * rn, s2 = v2 * rn, s3 = v3 * rn;

    float* npatT = ws + OFF_NPATT;
    npatT[(lane) * P_ + p] = s0;
    npatT[(lane + 64) * P_ + p] = s1;
    npatT[(lane + 128) * P_ + p] = s2;
    if (lane < 8) npatT[(lane + 192) * P_ + p] = s3;

    unsigned short* npb = (unsigned short*)(ws + OFF_NPB16);
    npb[p * KPAD + lane] = f2bf(s0);
    npb[p * KPAD + lane + 64] = f2bf(s1);
    npb[p * KPAD + lane + 128] = f2bf(s2);
    if (lane < 8) npb[p * KPAD + lane + 192] = f2bf(s3);
    if (lane < 24) npb[p * KPAD + 200 + lane] = 0;

    float a0 = fabsf(s0), a1 = fabsf(s1), a2 = fabsf(s2);
    float a3 = fabsf(s3);

    int ch0 = -1, ch1 = -1, ch2 = -1;
    float cs0 = 0.f, cs1 = 0.f, cs2 = 0.f;

    for (int r = 0; r < 3; r++) {
        float bv = -1.0f;
        int bi = 1 << 30;
        {
            int n = lane;
            bool sk = (n == ch0) || (n == ch1) || (n == ch2);
            if (!sk && a0 > bv) { bv = a0; bi = n; }
        }
        {
            int n = lane + 64;
            bool sk = (n == ch0) || (n == ch1) || (n == ch2);
            if (!sk && (a1 > bv || (a1 == bv && n < bi))) { bv = a1; bi = n; }
        }
        {
            int n = lane + 128;
            bool sk = (n == ch0) || (n == ch1) || (n == ch2);
            if (!sk && (a2 > bv || (a2 == bv && n < bi))) { bv = a2; bi = n; }
        }
        if (lane < 8) {
            int n = lane + 192;
            bool sk = (n == ch0) || (n == ch1) || (n == ch2);
            if (!sk && (a3 > bv || (a3 == bv && n < bi))) { bv = a3; bi = n; }
        }
        for (int off = 32; off; off >>= 1) {
            float ov = __shfl_down(bv, off);
            int oi = __shfl_down(bi, off);
            if (ov > bv || (ov == bv && oi < bi)) { bv = ov; bi = oi; }
        }
        bi = __shfl(bi, 0);
        int slot = bi >> 6, src = bi & 63;
        float mine = (slot == 0) ? s0 : (slot == 1) ? s1 : (slot == 2) ? s2 : s3;
        float sval = __shfl(mine, src);
        if (r == 0) { ch0 = bi; cs0 = sval; }
        else if (r == 1) { ch1 = bi; cs1 = sval; }
        else { ch2 = bi; cs2 = sval; }
    }

    if (lane == 0) {
        float* keyval = ws + OFF_KEYVAL;
        int* keyidx = (int*)(ws + OFF_KEYIDX);
        keyval[p * 4 + 0] = cs0; keyval[p * 4 + 1] = cs1; keyval[p * 4 + 2] = cs2;
        keyidx[p * 4 + 0] = ch0; keyidx[p * 4 + 1] = ch1; keyidx[p * 4 + 2] = ch2;
        float lenp = sqrtf(ss) * rn;
        float lentopp = sqrtf(cs0 * cs0 + cs1 * cs1 + cs2 * cs2);
        float d = 1.0f - lentopp / lenp;
        atomicAdd(ws + OFF_NORM, d * d * (1.0f / (float)P_));
    }
}

// ---------------- orth regularizer -----------------------------------------
__global__ __launch_bounds__(256) void orth_kernel(float* __restrict__ ws) {
    __shared__ float rowi[N_];
    __shared__ float red[256];
    const float* npatT = ws + OFF_NPATT;
    int i = blockIdx.x;
    for (int k = threadIdx.x; k < N_; k += 256) rowi[k] = npatT[k * P_ + i];
    __syncthreads();

    float partial = 0.0f;
    for (int j = threadIdx.x; j < P_; j += 256) {
        if (j == i) continue;
        float s = 0.0f;
        for (int k = 0; k < N_; k++) s += rowi[k] * npatT[k * P_ + j];
        float t = (fabsf(s) - 0.3f) * (1.0f / 0.70001f);
        if (t > 0.0f) partial += t * t;
    }
    red[threadIdx.x] = partial;
    __syncthreads();
    for (int sft = 128; sft; sft >>= 1) {
        if (threadIdx.x < sft) red[threadIdx.x] += red[threadIdx.x + sft];
        __syncthreads();
    }
    if (threadIdx.x == 0)
        atomicAdd(ws + OFF_ORTH, red[0] * (1.0f / ((float)P_ * (float)P_)));
}

// ---------------- transpose + frame-normalize -> bf16 xn --------------------
__global__ __launch_bounds__(256) void tnorm_kernel(const float* __restrict__ x,
                                                    float* __restrict__ ws) {
    __shared__ unsigned short xt16[64 * 210];
    __shared__ float psums[256];
    __shared__ float rns[64];

    const int tid = threadIdx.x;
    const int t = tid & 63, r = tid >> 6;
    const int b = blockIdx.y;
    const int t0 = blockIdx.x * 64;
    const bool valid = (t0 + t) < T_;

    float ss = 0.0f;
    if (valid) {
        const float* xp = x + (size_t)b * N_ * T_ + t0 + t;
#pragma unroll 5
        for (int i = 0; i < 50; ++i) {
            int n = r * 50 + i;
            float v = xp[(size_t)n * T_];
            ss += v * v;
            xt16[t * 210 + n] = f2bf(v);
        }
    }
    psums[tid] = ss;
    __syncthreads();
    if (tid < 64) {
        float s = psums[tid] + psums[tid + 64] + psums[tid + 128] + psums[tid + 192];
        rns[tid] = rsqrtf(s + EPS_);
    }
    __syncthreads();

    unsigned short* xn = (unsigned short*)(ws + OFF_XN);
#pragma unroll
    for (int j = 0; j < 7; ++j) {
        int idx = tid + 256 * j;
        int tt = idx / 28, s = idx % 28;
        if (t0 + tt >= T_) continue;
        s8v ov = (s8v){0, 0, 0, 0, 0, 0, 0, 0};
        if (s < 25) {
            float rn = rns[tt];
            const unsigned* src = (const unsigned*)&xt16[tt * 210 + s * 8];
            unsigned o[4];
#pragma unroll
            for (int i = 0; i < 4; ++i) {
                unsigned u = src[i];
                float lo = __uint_as_float(u << 16) * rn;
                float hi = __uint_as_float(u & 0xffff0000u) * rn;
                o[i] = (unsigned)f2bf(lo) | ((unsigned)f2bf(hi) << 16);
            }
            ov = (s8v){(short)(o[0] & 0xffff), (short)(o[0] >> 16),
                       (short)(o[1] & 0xffff), (short)(o[1] >> 16),
                       (short)(o[2] & 0xffff), (short)(o[2] >> 16),
                       (short)(o[3] & 0xffff), (short)(o[3] >> 16)};
        }
        *(s8v*)(xn + ((size_t)b * T_ + t0 + tt) * KPAD + s * 8) = ov;
    }
}

// ---------------- reg-only MFMA GEMM + pooling into global okey pool --------
// 1600 blocks (5 pb x 5 mb x 64 b, XCD-swizzled), 320 thr = 5 waves.
// Wave tile: mi=3 (48 frames), ni=5 (80 pats); acc=60 AGPR.
// A and B both stream global->VGPR double-buffered; NO LDS operands,
// NO barriers until epilogue.
__global__ __launch_bounds__(320, 3) void gemm_kernel(const float* __restrict__ ws,
                                                      unsigned* __restrict__ gpool) {
    __shared__ unsigned pool[NPOOLW * 80];   // 3.5 KB

    const int tid = threadIdx.x;
    // bijective XCD swizzle: 1600 blocks, 8 XCDs x 200; 25 consecutive nids
    // (one batch b: all pb,mb) land on one XCD -> A-tile + B fully L2-local.
    int id = blockIdx.x;
    int nid = (id & 7) * 200 + (id >> 3);
    const int pb = nid % 5;
    const int mb = (nid / 5) % 5;
    const int b  = nid / 25;

    const int wv = tid >> 6, lane = tid & 63;
    const int l15 = lane & 15, kg = lane >> 4;

    for (int i = tid; i < NPOOLW * 80; i += 320) pool[i] = 0u;

    const unsigned short* aB = (const unsigned short*)(ws + OFF_XN) +
        ((size_t)b * T_ + mb * MB_ + wv * 48 + l15) * KPAD + kg * 8;
    const unsigned short* bB = (const unsigned short*)(ws + OFF_NPB16) +
        (size_t)(pb * 80 + l15) * KPAD + kg * 8;

    f4v acc[3][5];
#pragma unroll
    for (int mi = 0; mi < 3; ++mi)
#pragma unroll
        for (int ni = 0; ni < 5; ++ni) acc[mi][ni] = (f4v){0.f, 0.f, 0.f, 0.f};

    s8v A0[3], A1[3], Bf0[5], Bf1[5];
#pragma unroll
    for (int mi = 0; mi < 3; ++mi) A0[mi] = *(const s8v*)(aB + mi * 16 * KPAD);
#pragma unroll
    for (int ni = 0; ni < 5; ++ni) Bf0[ni] = *(const s8v*)(bB + ni * 16 * KPAD);

#pragma unroll
    for (int c = 0; c < 7; ++c) {
        if (c < 6) {
            int koff = (c + 1) * 32;
            if ((c & 1) == 0) {
#pragma unroll
                for (int mi = 0; mi < 3; ++mi) A1[mi] = *(const s8v*)(aB + mi * 16 * KPAD + koff);
#pragma unroll
                for (int ni = 0; ni < 5; ++ni) Bf1[ni] = *(const s8v*)(bB + ni * 16 * KPAD + koff);
            } else {
#pragma unroll
                for (int mi = 0; mi < 3; ++mi) A0[mi] = *(const s8v*)(aB + mi * 16 * KPAD + koff);
#pragma unroll
                for (int ni = 0; ni < 5; ++ni) Bf0[ni] = *(const s8v*)(bB + ni * 16 * KPAD + koff);
            }
        }
#pragma unroll
        for (int mi = 0; mi < 3; ++mi) {
            s8v av = ((c & 1) == 0) ? A0[mi] : A1[mi];
#pragma unroll
            for (int ni = 0; ni < 5; ++ni) {
                s8v bv = ((c & 1) == 0) ? Bf0[ni] : Bf1[ni];
                acc[mi][ni] = __builtin_amdgcn_mfma_f32_16x16x32_bf16(av, bv, acc[mi][ni], 0, 0, 0);
            }
        }
    }
    __syncthreads();   // pool init complete; acc ready

    const int wbase = (mb * MB_) / 25;
    for (int pass = 0; pass < 2; ++pass) {
        float sgn = pass ? -1.f : 1.f;
#pragma unroll
        for (int mi = 0; mi < 3; ++mi) {
            int f0 = mb * MB_ + wv * 48 + mi * 16 + kg * 4;
            int w0 = f0 / 25, w3 = (f0 + 3) / 25;
            int wsplit = w3 * 25;
#pragma unroll
            for (int ni = 0; ni < 5; ++ni) {
                int pc = ni * 16 + l15;
                float m0 = -1e30f, m1 = -1e30f;
#pragma unroll
                for (int jj = 0; jj < 4; ++jj) {
                    float v = sgn * acc[mi][ni][jj];
                    if (f0 + jj < wsplit) m0 = fmaxf(m0, v);
                    else m1 = fmaxf(m1, v);
                }
                atomicMax(&pool[(w3 - wbase) * 80 + pc], okey(m1));
                if (w0 != w3) atomicMax(&pool[(w0 - wbase) * 80 + pc], okey(m0));
            }
        }
        __syncthreads();
        // flush LDS pool -> global pool (device-scope atomics)
        unsigned* gp = gpool + (size_t)(pass * B_ + b) * 48 * 400;
        for (int e = tid; e < NPOOLW * 80; e += 320) {
            unsigned v = pool[e];
            int w = wbase + e / 80;
            if (v && w < 48) atomicMax(&gp[w * 400 + pb * 80 + (e % 80)], v);
        }
        if (pass == 0) {
            __syncthreads();
            for (int i = tid; i < NPOOLW * 80; i += 320) pool[i] = 0u;
            __syncthreads();
        }
    }
}

// ---------------- PES finalize: reduce gpool over windows -------------------
__global__ __launch_bounds__(256) void pes_kernel(const unsigned* __restrict__ gpool,
                                                  const int* __restrict__ length,
                                                  float* __restrict__ ws) {
    int idx = blockIdx.x * 256 + threadIdx.x;
    if (idx >= B_ * P_) return;
    int b = idx / P_;
    int p = idx - b * P_;
    float rsap = 1.0f / (float)(length[b] / STRIDE_);
    const unsigned* gp0 = gpool + (size_t)b * 48 * 400 + p;
    const unsigned* gp1 = gpool + (size_t)(B_ + b) * 48 * 400 + p;
    float s = 0.f;
#pragma unroll
    for (int w = 0; w < 48; ++w)
        s += dekey(gp0[w * 400]) + dekey(gp1[w * 400]);
    ws[OFF_PES + b * P_ + p] = s * 0.5f * rsap;
}

// ---------------- fallback fp32 fused GEMM+pool (used if ws too small) ------
__global__ __launch_bounds__(256) void main_kernel(const float* __restrict__ x,
                                                   const int* __restrict__ length,
                                                   const float* __restrict__ ws,
                                                   float* __restrict__ pes) {
    __shared__ float xs[N_][STRIDE_ + 1];
    __shared__ float rnorm[STRIDE_];
    __shared__ float poolp[P_][5];
    __shared__ float pooln[P_][5];

    int w = blockIdx.x;
    int b = blockIdx.y;
    const float* xb = x + (size_t)b * N_ * T_ + (size_t)w * STRIDE_;

    for (int i = threadIdx.x; i < N_ * STRIDE_; i += 256) {
        int n = i / STRIDE_;
        int t = i - n * STRIDE_;
        xs[n][t] = xb[n * T_ + t];
    }
    __syncthreads();

    if (threadIdx.x < STRIDE_) {
        float ssf = 0.0f;
        for (int n = 0; n < N_; n++) { float vv = xs[n][threadIdx.x]; ssf += vv * vv; }
        rnorm[threadIdx.x] = 1.0f / sqrtf(ssf + EPS_);
    }
    __syncthreads();

    int pt = threadIdx.x % 50;
    int tt = threadIdx.x / 50;

    if (tt < 5) {
        float acc[8][5];
#pragma unroll
        for (int i = 0; i < 8; i++)
#pragma unroll
            for (int j = 0; j < 5; j++) acc[i][j] = 0.0f;

        const float4* np4 = (const float4*)(ws + OFF_NPATT);
        int pbq = pt * 2;
        for (int n = 0; n < N_; n++) {
            float4 q0 = np4[n * (P_ / 4) + pbq];
            float4 q1 = np4[n * (P_ / 4) + pbq + 1];
            float qa[8] = { q0.x, q0.y, q0.z, q0.w, q1.x, q1.y, q1.z, q1.w };
            float xv0 = xs[n][tt * 5 + 0];
            float xv1 = xs[n][tt * 5 + 1];
            float xv2 = xs[n][tt * 5 + 2];
            float xv3 = xs[n][tt * 5 + 3];
            float xv4 = xs[n][tt * 5 + 4];
#pragma unroll
            for (int i = 0; i < 8; i++) {
                acc[i][0] += qa[i] * xv0;
                acc[i][1] += qa[i] * xv1;
                acc[i][2] += qa[i] * xv2;
                acc[i][3] += qa[i] * xv3;
                acc[i][4] += qa[i] * xv4;
            }
        }
#pragma unroll
        for (int i = 0; i < 8; i++) {
            float pm = -1e30f, nm = -1e30f;
#pragma unroll
            for (int j = 0; j < 5; j++) {
                float s = acc[i][j] * rnorm[tt * 5 + j];
                pm = fmaxf(pm, s);
                nm = fmaxf(nm, -s);
            }
            poolp[pt * 8 + i][tt] = pm;
            pooln[pt * 8 + i][tt] = nm;
        }
    }
    __syncthreads();

    float rsap = 1.0f / (float)(length[b] / STRIDE_);
    for (int p = threadIdx.x; p < P_; p += 256) {
        float pm = poolp[p][0], nm = pooln[p][0];
#pragma unroll
        for (int q = 1; q < 5; q++) {
            pm = fmaxf(pm, poolp[p][q]);
            nm = fmaxf(nm, pooln[p][q]);
        }
        atomicAdd(&pes[b * P_ + p], (pm + nm) * 0.5f * rsap);
    }
}

// ---------------- sparse graphs assembly + scalar outputs -------------------
__global__ __launch_bounds__(256) void graphs_kernel(const float* __restrict__ ws,
                                                     float* __restrict__ out) {
    int idx = blockIdx.x * 256 + threadIdx.x;
    if (idx == 0) {
        out[(size_t)B_ * N_ * N_] = ws[OFF_NORM];
        out[(size_t)B_ * N_ * N_ + 1] = ws[OFF_ORTH];
    }
    if (idx >= B_ * P_) return;
    int b = idx / P_;
    int p = idx - b * P_;

    float e = ws[OFF_PES + b * P_ + p];
    const float* keyval = ws + OFF_KEYVAL;
    const int* keyidx = (const int*)(ws + OFF_KEYIDX);
    float va[3] = { keyval[p * 4 + 0], keyval[p * 4 + 1], keyval[p * 4 + 2] };
    int ia[3] = { keyidx[p * 4 + 0], keyidx[p * 4 + 1], keyidx[p * 4 + 2] };

    float* g = out + (size_t)b * N_ * N_;
#pragma unroll
    for (int a = 0; a < 3; a++) {
#pragma unroll
        for (int c = 0; c < 3; c++) {
            float scale = (ia[a] == ia[c]) ? 1.0f : 6.0f;
            atomicAdd(&g[ia[a] * N_ + ia[c]], va[a] * va[c] * e * scale);
        }
    }
}

extern "C" void kernel_launch(void* const* d_in, const int* in_sizes, int n_in,
                              void* d_out, int out_size, void* d_ws, size_t ws_size,
                              hipStream_t stream) {
    const float* x = (const float*)d_in[0];
    const float* patterns = (const float*)d_in[1];
    const int* length = (const int*)d_in[2];
    float* out = (float*)d_out;
    float* ws = (float*)d_ws;

    hipMemsetAsync(ws + OFF_NORM, 0, 2 * sizeof(float), stream);
    hipMemsetAsync(d_out, 0, (size_t)B_ * N_ * N_ * sizeof(float), stream);

    pat_kernel<<<P_, 64, 0, stream>>>(patterns, ws);
    orth_kernel<<<P_, 256, 0, stream>>>(ws);

    if (ws_size >= (size_t)WS_FAST_FLOATS * sizeof(float)) {
        unsigned* gpool = (unsigned*)(ws + OFF_GPOOL);
        hipMemsetAsync(gpool, 0, (size_t)2 * B_ * 48 * 400 * sizeof(unsigned), stream);
        tnorm_kernel<<<dim3((T_ + 63) / 64, B_), 256, 0, stream>>>(x, ws);
        gemm_kernel<<<1600, 320, 0, stream>>>(ws, gpool);
        pes_kernel<<<(B_ * P_ + 255) / 256, 256, 0, stream>>>(gpool, length, ws);
    } else {
        hipMemsetAsync(ws + OFF_PES, 0, (size_t)B_ * P_ * sizeof(float), stream);
        main_kernel<<<dim3(T_ / STRIDE_, B_), 256, 0, stream>>>(x, length, ws, ws + OFF_PES);
    }
    graphs_kernel<<<(B_ * P_ + 255) / 256, 256, 0, stream>>>(ws, out);
}

// Round 6
// 137.056 us; speedup vs baseline: 1.1121x; 1.1121x over previous
//
#include <hip/hip_runtime.h>
#include <math.h>

#define B_ 64
#define N_ 200
#define P_ 400
#define T_ 1200
#define STRIDE_ 25
#define EPS_ 1e-9f
#define KPAD 224
#define BSTRIDE 232   // LDS B row stride in shorts: 464B=116dw -> 8 banks, 2-way (free)

// ws layout (float offsets)
#define OFF_NPATT  0            // [N_][P_] f32 transposed normalized patterns (80000)
#define OFF_NPB16  80000        // [P_][KPAD] bf16 normalized patterns (89600 u16)
#define OFF_KEYVAL 124800       // [P_][4]
#define OFF_KEYIDX 126400       // [P_][4] int
#define OFF_PES    128000       // [B_][P_] (memset covers PES..ORTH contiguously)
#define OFF_NORM   153600
#define OFF_ORTH   153601
#define OFF_XN     153604       // [B_][T_][KPAD] bf16 normalized frames
#define WS_FAST_FLOATS (153604 + 8601600)

typedef float f4v __attribute__((ext_vector_type(4)));
typedef short s8v __attribute__((ext_vector_type(8)));
typedef short s4v __attribute__((ext_vector_type(4)));

__device__ inline unsigned short f2bf(float f) {
    union { float f; unsigned u; } v; v.f = f;
    unsigned r = v.u + 0x7FFFu + ((v.u >> 16) & 1u);
    return (unsigned short)(r >> 16);
}

// ================= prep: fused pat (blocks 0..399) + tnorm (400..1615) =======
__device__ void pat_body(const float* __restrict__ patterns, float* __restrict__ ws,
                         int p, int tid) {
    if (tid >= 64) return;
    int lane = tid;

    float v0 = patterns[p * N_ + lane];
    float v1 = patterns[p * N_ + lane + 64];
    float v2 = patterns[p * N_ + lane + 128];
    float v3 = (lane < 8) ? patterns[p * N_ + lane + 192] : 0.0f;

    float ss = v0 * v0 + v1 * v1 + v2 * v2 + v3 * v3;
    for (int off = 32; off; off >>= 1) ss += __shfl_down(ss, off);
    ss = __shfl(ss, 0);

    float rn = 1.0f / sqrtf(ss + EPS_);
    float s0 = v0 * rn, s1 = v1 * rn, s2 = v2 * rn, s3 = v3 * rn;

    float* npatT = ws + OFF_NPATT;
    npatT[(lane) * P_ + p] = s0;
    npatT[(lane + 64) * P_ + p] = s1;
    npatT[(lane + 128) * P_ + p] = s2;
    if (lane < 8) npatT[(lane + 192) * P_ + p] = s3;

    unsigned short* npb = (unsigned short*)(ws + OFF_NPB16);
    npb[p * KPAD + lane] = f2bf(s0);
    npb[p * KPAD + lane + 64] = f2bf(s1);
    npb[p * KPAD + lane + 128] = f2bf(s2);
    if (lane < 8) npb[p * KPAD + lane + 192] = f2bf(s3);
    if (lane < 24) npb[p * KPAD + 200 + lane] = 0;

    float a0 = fabsf(s0), a1 = fabsf(s1), a2 = fabsf(s2), a3 = fabsf(s3);

    int ch0 = -1, ch1 = -1, ch2 = -1;
    float cs0 = 0.f, cs1 = 0.f, cs2 = 0.f;

    for (int r = 0; r < 3; r++) {
        float bv = -1.0f;
        int bi = 1 << 30;
        {
            int n = lane;
            bool sk = (n == ch0) || (n == ch1) || (n == ch2);
            if (!sk && a0 > bv) { bv = a0; bi = n; }
        }
        {
            int n = lane + 64;
            bool sk = (n == ch0) || (n == ch1) || (n == ch2);
            if (!sk && (a1 > bv || (a1 == bv && n < bi))) { bv = a1; bi = n; }
        }
        {
            int n = lane + 128;
            bool sk = (n == ch0) || (n == ch1) || (n == ch2);
            if (!sk && (a2 > bv || (a2 == bv && n < bi))) { bv = a2; bi = n; }
        }
        if (lane < 8) {
            int n = lane + 192;
            bool sk = (n == ch0) || (n == ch1) || (n == ch2);
            if (!sk && (a3 > bv || (a3 == bv && n < bi))) { bv = a3; bi = n; }
        }
        for (int off = 32; off; off >>= 1) {
            float ov = __shfl_down(bv, off);
            int oi = __shfl_down(bi, off);
            if (ov > bv || (ov == bv && oi < bi)) { bv = ov; bi = oi; }
        }
        bi = __shfl(bi, 0);
        int slot = bi >> 6, src = bi & 63;
        float mine = (slot == 0) ? s0 : (slot == 1) ? s1 : (slot == 2) ? s2 : s3;
        float sval = __shfl(mine, src);
        if (r == 0) { ch0 = bi; cs0 = sval; }
        else if (r == 1) { ch1 = bi; cs1 = sval; }
        else { ch2 = bi; cs2 = sval; }
    }

    if (lane == 0) {
        float* keyval = ws + OFF_KEYVAL;
        int* keyidx = (int*)(ws + OFF_KEYIDX);
        keyval[p * 4 + 0] = cs0; keyval[p * 4 + 1] = cs1; keyval[p * 4 + 2] = cs2;
        keyidx[p * 4 + 0] = ch0; keyidx[p * 4 + 1] = ch1; keyidx[p * 4 + 2] = ch2;
        float lenp = sqrtf(ss) * rn;
        float lentopp = sqrtf(cs0 * cs0 + cs1 * cs1 + cs2 * cs2);
        float d = 1.0f - lentopp / lenp;
        atomicAdd(ws + OFF_NORM, d * d * (1.0f / (float)P_));
    }
}

__global__ __launch_bounds__(256) void prep_kernel(const float* __restrict__ x,
                                                   const float* __restrict__ patterns,
                                                   float* __restrict__ ws) {
    __shared__ unsigned short xt16[64 * 210];
    __shared__ float psums[256];
    __shared__ float rns[64];

    if (blockIdx.x < 400) { pat_body(patterns, ws, blockIdx.x, threadIdx.x); return; }

    const int blk = blockIdx.x - 400;
    const int tid = threadIdx.x;
    const int t = tid & 63, r = tid >> 6;
    const int b = blk / 19;
    const int t0 = (blk % 19) * 64;
    const bool valid = (t0 + t) < T_;

    float ss = 0.0f;
    if (valid) {
        const float* xp = x + (size_t)b * N_ * T_ + t0 + t;
#pragma unroll 5
        for (int i = 0; i < 50; ++i) {
            int n = r * 50 + i;
            float v = xp[(size_t)n * T_];
            ss += v * v;
            xt16[t * 210 + n] = f2bf(v);
        }
    }
    psums[tid] = ss;
    __syncthreads();
    if (tid < 64) {
        float s = psums[tid] + psums[tid + 64] + psums[tid + 128] + psums[tid + 192];
        rns[tid] = rsqrtf(s + EPS_);
    }
    __syncthreads();

    unsigned short* xn = (unsigned short*)(ws + OFF_XN);
#pragma unroll
    for (int j = 0; j < 7; ++j) {
        int idx = tid + 256 * j;
        int tt = idx / 28, s = idx % 28;
        if (t0 + tt >= T_) continue;
        s8v ov = (s8v){0, 0, 0, 0, 0, 0, 0, 0};
        if (s < 25) {
            float rn = rns[tt];
            const unsigned* src = (const unsigned*)&xt16[tt * 210 + s * 8];
            unsigned o[4];
#pragma unroll
            for (int i = 0; i < 4; ++i) {
                unsigned u = src[i];
                float lo = __uint_as_float(u << 16) * rn;
                float hi = __uint_as_float(u & 0xffff0000u) * rn;
                o[i] = (unsigned)f2bf(lo) | ((unsigned)f2bf(hi) << 16);
            }
            ov = (s8v){(short)(o[0] & 0xffff), (short)(o[0] >> 16),
                       (short)(o[1] & 0xffff), (short)(o[1] >> 16),
                       (short)(o[2] & 0xffff), (short)(o[2] >> 16),
                       (short)(o[3] & 0xffff), (short)(o[3] >> 16)};
        }
        *(s8v*)(xn + ((size_t)b * T_ + t0 + tt) * KPAD + s * 8) = ov;
    }
}

// ================= work: fused gemm (blocks 0..959) + orth (960..1359) =======
__device__ void orth_body(float* __restrict__ ws, int i, int tid) {
    __shared__ float rowi[N_];
    __shared__ float red[256];
    const float* npatT = ws + OFF_NPATT;
    if (tid < 256) {
        for (int k = tid; k < N_; k += 256) rowi[k] = npatT[k * P_ + i];
    }
    __syncthreads();

    float partial = 0.0f;
    if (tid < 256) {
        for (int j = tid; j < P_; j += 256) {
            if (j == i) continue;
            float s = 0.0f;
            for (int k = 0; k < N_; k++) s += rowi[k] * npatT[k * P_ + j];
            float t = (fabsf(s) - 0.3f) * (1.0f / 0.70001f);
            if (t > 0.0f) partial += t * t;
        }
        red[tid] = partial;
    }
    __syncthreads();
    for (int sft = 128; sft; sft >>= 1) {
        if (tid < sft) red[tid] += red[tid + sft];
        __syncthreads();
    }
    if (tid == 0)
        atomicAdd(ws + OFF_ORTH, red[0] * (1.0f / ((float)P_ * (float)P_)));
}

// gemm blocks: 5 pb x 3 mb x 64 b (XCD-swizzled), 320 thr = 5 waves.
// M=400 frames (16 exact windows), N=80 pats, K=224. B in LDS once; A streamed
// global->VGPR with 2-deep prefetch. Epilogue: shuffle pooling, no atomics.
__global__ __launch_bounds__(320, 2) void work_kernel(float* __restrict__ ws,
                                                      const int* __restrict__ length,
                                                      float* __restrict__ pes) {
    if (blockIdx.x >= 960) { orth_body(ws, blockIdx.x - 960, threadIdx.x); return; }

    __shared__ short ldsB[80 * BSTRIDE];      // 37.1 KB
    __shared__ float wsl[5 * 4 * 2 * 80];     // per-wave window slots, 12.8 KB

    const int tid = threadIdx.x;
    // bijective XCD swizzle over the 960 gemm blocks
    int id = blockIdx.x;
    int nid = (id & 7) * 120 + (id >> 3);
    const int pb = nid % 5;
    const int mb = (nid / 5) % 3;
    const int b  = nid / 15;

    const unsigned short* npb = (const unsigned short*)(ws + OFF_NPB16) + (size_t)(pb * 80) * KPAD;

    // stage B once: 80 rows x 224 shorts
#pragma unroll
    for (int j = 0; j < 7; ++j) {
        int idx = tid + 320 * j;
        int row = idx / 28, seg = idx % 28;
        *(s8v*)(&ldsB[row * BSTRIDE + seg * 8]) = *(const s8v*)(npb + (size_t)row * KPAD + seg * 8);
    }
    for (int i = tid; i < 3200; i += 320) wsl[i] = -1e30f;
    __syncthreads();

    const int wv = tid >> 6;
    const int lane = tid & 63;
    const int l15 = lane & 15, kg = lane >> 4;

    f4v acc[5][5];
#pragma unroll
    for (int mi = 0; mi < 5; ++mi)
#pragma unroll
        for (int ni = 0; ni < 5; ++ni) acc[mi][ni] = (f4v){0.f, 0.f, 0.f, 0.f};

    const unsigned short* xb = (const unsigned short*)(ws + OFF_XN) +
                               ((size_t)b * T_ + (size_t)mb * 400) * KPAD;
    const unsigned short* ar[5];
#pragma unroll
    for (int mi = 0; mi < 5; ++mi)
        ar[mi] = xb + (size_t)(wv * 80 + mi * 16 + l15) * KPAD + kg * 8;

    // 3-buffer rotating A prefetch (2-deep lookahead), fully unrolled
    s8v A[3][5];
#pragma unroll
    for (int mi = 0; mi < 5; ++mi) {
        A[0][mi] = *(const s8v*)(ar[mi]);
        A[1][mi] = *(const s8v*)(ar[mi] + 32);
    }

#pragma unroll
    for (int c = 0; c < 7; ++c) {
        if (c + 2 < 7) {
#pragma unroll
            for (int mi = 0; mi < 5; ++mi)
                A[(c + 2) % 3][mi] = *(const s8v*)(ar[mi] + (c + 2) * 32);
        }
        s8v bf[5];
#pragma unroll
        for (int ni = 0; ni < 5; ++ni)
            bf[ni] = *(const s8v*)(&ldsB[(ni * 16 + l15) * BSTRIDE + c * 32 + kg * 8]);
#pragma unroll
        for (int mi = 0; mi < 5; ++mi) {
#pragma unroll
            for (int ni = 0; ni < 5; ++ni)
                acc[mi][ni] = __builtin_amdgcn_mfma_f32_16x16x32_bf16(A[c % 3][mi], bf[ni], acc[mi][ni], 0, 0, 0);
        }
    }

    // ---- shuffle-pooling epilogue (no LDS atomics) ----
    const int wlo = (wv * 80) / 25;
#pragma unroll
    for (int mi = 0; mi < 5; ++mi) {
        const int F = wv * 80 + mi * 16;           // wave-uniform
        const int Wa = F / 25, Wb = (F + 15) / 25; // windows touched by this 16-tile
        const int S = Wb * 25;                     // split row
        const int rb = F + kg * 4;
#pragma unroll
        for (int ni = 0; ni < 5; ++ni) {
            float pA = -1e30f, pB = -1e30f, nA = -1e30f, nB = -1e30f;
#pragma unroll
            for (int jj = 0; jj < 4; ++jj) {
                float v = acc[mi][ni][jj];
                if (rb + jj >= S) { pB = fmaxf(pB, v); nB = fmaxf(nB, -v); }
                else             { pA = fmaxf(pA, v); nA = fmaxf(nA, -v); }
            }
            // fold kg dimension (rows of the 16-tile) via cross-lane max
#pragma unroll
            for (int d = 16; d < 64; d <<= 1) {
                pA = fmaxf(pA, __shfl_xor(pA, d));
                pB = fmaxf(pB, __shfl_xor(pB, d));
                nA = fmaxf(nA, __shfl_xor(nA, d));
                nB = fmaxf(nB, __shfl_xor(nB, d));
            }
            if (kg == 0) {
                int pc = ni * 16 + l15;
                float* bb = &wsl[((wv * 4 + (Wb - wlo)) * 2 + 0) * 80 + pc];
                bb[0]  = fmaxf(bb[0],  pB);
                bb[80] = fmaxf(bb[80], nB);
                if (Wa != Wb) {
                    float* ba = &wsl[((wv * 4 + (Wa - wlo)) * 2 + 0) * 80 + pc];
                    ba[0]  = fmaxf(ba[0],  pA);
                    ba[80] = fmaxf(ba[80], nA);
                }
            }
        }
    }
    __syncthreads();

    // deterministic reduction: 80 threads, 16 windows each
    if (tid < 80) {
        float s = 0.f;
#pragma unroll
        for (int w = 0; w < 16; ++w) {
            int wvlo = (25 * w) / 80;
            int wvhi = (25 * w + 24) / 80;
            float pos = -1e30f, neg = -1e30f;
            for (int wv2 = wvlo; wv2 <= wvhi; ++wv2) {
                int slot = w - (wv2 * 80) / 25;
                pos = fmaxf(pos, wsl[((wv2 * 4 + slot) * 2 + 0) * 80 + tid]);
                neg = fmaxf(neg, wsl[((wv2 * 4 + slot) * 2 + 1) * 80 + tid]);
            }
            s += pos + neg;
        }
        float rsap = 1.0f / (float)(length[b] / STRIDE_);
        atomicAdd(&pes[(size_t)b * P_ + pb * 80 + tid], s * 0.5f * rsap);
    }
}

// ---------------- fallback fp32 fused GEMM+pool (used if ws too small) ------
__global__ __launch_bounds__(256) void main_kernel(const float* __restrict__ x,
                                                   const int* __restrict__ length,
                                                   const float* __restrict__ ws,
                                                   float* __restrict__ pes) {
    __shared__ float xs[N_][STRIDE_ + 1];
    __shared__ float rnorm[STRIDE_];
    __shared__ float poolp[P_][5];
    __shared__ float pooln[P_][5];

    int w = blockIdx.x;
    int b = blockIdx.y;
    const float* xb = x + (size_t)b * N_ * T_ + (size_t)w * STRIDE_;

    for (int i = threadIdx.x; i < N_ * STRIDE_; i += 256) {
        int n = i / STRIDE_;
        int t = i - n * STRIDE_;
        xs[n][t] = xb[n * T_ + t];
    }
    __syncthreads();

    if (threadIdx.x < STRIDE_) {
        float ssf = 0.0f;
        for (int n = 0; n < N_; n++) { float vv = xs[n][threadIdx.x]; ssf += vv * vv; }
        rnorm[threadIdx.x] = 1.0f / sqrtf(ssf + EPS_);
    }
    __syncthreads();

    int pt = threadIdx.x % 50;
    int tt = threadIdx.x / 50;

    if (tt < 5) {
        float acc[8][5];
#pragma unroll
        for (int i = 0; i < 8; i++)
#pragma unroll
            for (int j = 0; j < 5; j++) acc[i][j] = 0.0f;

        const float4* np4 = (const float4*)(ws + OFF_NPATT);
        int pbq = pt * 2;
        for (int n = 0; n < N_; n++) {
            float4 q0 = np4[n * (P_ / 4) + pbq];
            float4 q1 = np4[n * (P_ / 4) + pbq + 1];
            float qa[8] = { q0.x, q0.y, q0.z, q0.w, q1.x, q1.y, q1.z, q1.w };
            float xv0 = xs[n][tt * 5 + 0];
            float xv1 = xs[n][tt * 5 + 1];
            float xv2 = xs[n][tt * 5 + 2];
            float xv3 = xs[n][tt * 5 + 3];
            float xv4 = xs[n][tt * 5 + 4];
#pragma unroll
            for (int i = 0; i < 8; i++) {
                acc[i][0] += qa[i] * xv0;
                acc[i][1] += qa[i] * xv1;
                acc[i][2] += qa[i] * xv2;
                acc[i][3] += qa[i] * xv3;
                acc[i][4] += qa[i] * xv4;
            }
        }
#pragma unroll
        for (int i = 0; i < 8; i++) {
            float pm = -1e30f, nm = -1e30f;
#pragma unroll
            for (int j = 0; j < 5; j++) {
                float s = acc[i][j] * rnorm[tt * 5 + j];
                pm = fmaxf(pm, s);
                nm = fmaxf(nm, -s);
            }
            poolp[pt * 8 + i][tt] = pm;
            pooln[pt * 8 + i][tt] = nm;
        }
    }
    __syncthreads();

    float rsap = 1.0f / (float)(length[b] / STRIDE_);
    for (int p = threadIdx.x; p < P_; p += 256) {
        float pm = poolp[p][0], nm = pooln[p][0];
#pragma unroll
        for (int q = 1; q < 5; q++) {
            pm = fmaxf(pm, poolp[p][q]);
            nm = fmaxf(nm, pooln[p][q]);
        }
        atomicAdd(&pes[b * P_ + p], (pm + nm) * 0.5f * rsap);
    }
}

// ---------------- sparse graphs assembly + scalar outputs -------------------
__global__ __launch_bounds__(256) void graphs_kernel(const float* __restrict__ ws,
                                                     float* __restrict__ out) {
    int idx = blockIdx.x * 256 + threadIdx.x;
    if (idx == 0) {
        out[(size_t)B_ * N_ * N_] = ws[OFF_NORM];
        out[(size_t)B_ * N_ * N_ + 1] = ws[OFF_ORTH];
    }
    if (idx >= B_ * P_) return;
    int b = idx / P_;
    int p = idx - b * P_;

    float e = ws[OFF_PES + b * P_ + p];
    const float* keyval = ws + OFF_KEYVAL;
    const int* keyidx = (const int*)(ws + OFF_KEYIDX);
    float va[3] = { keyval[p * 4 + 0], keyval[p * 4 + 1], keyval[p * 4 + 2] };
    int ia[3] = { keyidx[p * 4 + 0], keyidx[p * 4 + 1], keyidx[p * 4 + 2] };

    float* g = out + (size_t)b * N_ * N_;
#pragma unroll
    for (int a = 0; a < 3; a++) {
#pragma unroll
        for (int c = 0; c < 3; c++) {
            float scale = (ia[a] == ia[c]) ? 1.0f : 6.0f;
            atomicAdd(&g[ia[a] * N_ + ia[c]], va[a] * va[c] * e * scale);
        }
    }
}

// ---------------- separate pat/orth for fallback path -----------------------
__global__ __launch_bounds__(64) void pat_kernel(const float* __restrict__ patterns,
                                                 float* __restrict__ ws) {
    pat_body(patterns, ws, blockIdx.x, threadIdx.x);
}
__global__ __launch_bounds__(256) void orth_kernel(float* __restrict__ ws) {
    orth_body(ws, blockIdx.x, threadIdx.x);
}

extern "C" void kernel_launch(void* const* d_in, const int* in_sizes, int n_in,
                              void* d_out, int out_size, void* d_ws, size_t ws_size,
                              hipStream_t stream) {
    const float* x = (const float*)d_in[0];
    const float* patterns = (const float*)d_in[1];
    const int* length = (const int*)d_in[2];
    float* out = (float*)d_out;
    float* ws = (float*)d_ws;

    // zero PES..ORTH (contiguous) and graphs output
    hipMemsetAsync(ws + OFF_PES, 0, (size_t)(B_ * P_ + 2) * sizeof(float), stream);
    hipMemsetAsync(d_out, 0, (size_t)B_ * N_ * N_ * sizeof(float), stream);

    if (ws_size >= (size_t)WS_FAST_FLOATS * sizeof(float)) {
        prep_kernel<<<400 + 19 * B_, 256, 0, stream>>>(x, patterns, ws);
        work_kernel<<<960 + 400, 320, 0, stream>>>(ws, length, ws + OFF_PES);
    } else {
        pat_kernel<<<P_, 64, 0, stream>>>(patterns, ws);
        orth_kernel<<<P_, 256, 0, stream>>>(ws);
        main_kernel<<<dim3(T_ / STRIDE_, B_), 256, 0, stream>>>(x, length, ws, ws + OFF_PES);
    }
    graphs_kernel<<<(B_ * P_ + 255) / 256, 256, 0, stream>>>(ws, out);
}

// Round 7
// 123.782 us; speedup vs baseline: 1.2314x; 1.1072x over previous
//
#include <hip/hip_runtime.h>
#include <math.h>

#define B_ 64
#define N_ 200
#define P_ 400
#define T_ 1200
#define STRIDE_ 25
#define EPS_ 1e-9f
#define KPAD 224
#define BSTRIDE 232   // LDS B row stride in shorts

// ws layout (float offsets)
#define OFF_NPATT  0            // [N_][P_] f32 transposed normalized patterns (80000)
#define OFF_NPB16  80000        // [P_][KPAD] bf16 row-major patterns (44800)
#define OFF_KEYVAL 124800       // [P_][4]
#define OFF_KEYIDX 126400       // [P_][4] int
#define OFF_PES    128000       // [B_][P_] (+NORM/ORTH contiguous for memset)
#define OFF_NORM   153600
#define OFF_ORTH   153601
#define OFF_NPBT   153604       // [28][P_][8] bf16 K-outer patterns (44800)
#define OFF_XN     198404       // [B_][28][T_][8] bf16 K-outer normalized frames
#define WS_FAST_FLOATS (198404 + 8601600)

typedef float f4v __attribute__((ext_vector_type(4)));
typedef short s8v __attribute__((ext_vector_type(8)));

__device__ inline unsigned short f2bf(float f) {
    union { float f; unsigned u; } v; v.f = f;
    unsigned r = v.u + 0x7FFFu + ((v.u >> 16) & 1u);
    return (unsigned short)(r >> 16);
}
__device__ inline unsigned okey(float f) {
    unsigned u = __float_as_uint(f);
    return (u & 0x80000000u) ? ~u : (u | 0x80000000u);
}
__device__ inline float dekey(unsigned k) {
    unsigned u = (k & 0x80000000u) ? (k & 0x7fffffffu) : ~k;
    return __uint_as_float(u);
}

// ================= pat body: normalize, top-3, bf16 copies ===================
__device__ void pat_body(const float* __restrict__ patterns, float* __restrict__ ws,
                         int p, int tid) {
    if (tid >= 64) return;
    int lane = tid;

    float v0 = patterns[p * N_ + lane];
    float v1 = patterns[p * N_ + lane + 64];
    float v2 = patterns[p * N_ + lane + 128];
    float v3 = (lane < 8) ? patterns[p * N_ + lane + 192] : 0.0f;

    float ss = v0 * v0 + v1 * v1 + v2 * v2 + v3 * v3;
    for (int off = 32; off; off >>= 1) ss += __shfl_down(ss, off);
    ss = __shfl(ss, 0);

    float rn = 1.0f / sqrtf(ss + EPS_);
    float s0 = v0 * rn, s1 = v1 * rn, s2 = v2 * rn, s3 = v3 * rn;

    float* npatT = ws + OFF_NPATT;
    npatT[(lane) * P_ + p] = s0;
    npatT[(lane + 64) * P_ + p] = s1;
    npatT[(lane + 128) * P_ + p] = s2;
    if (lane < 8) npatT[(lane + 192) * P_ + p] = s3;

    unsigned short* npb = (unsigned short*)(ws + OFF_NPB16);
    unsigned short b0 = f2bf(s0), b1 = f2bf(s1), b2 = f2bf(s2), b3 = f2bf(s3);
    npb[p * KPAD + lane] = b0;
    npb[p * KPAD + lane + 64] = b1;
    npb[p * KPAD + lane + 128] = b2;
    if (lane < 8) npb[p * KPAD + lane + 192] = b3;
    if (lane < 24) npb[p * KPAD + 200 + lane] = 0;

    // K-outer copy: npbT[k/8][p][k%8]
    unsigned short* npbT = (unsigned short*)(ws + OFF_NPBT);
    {
        int k0 = lane, k1 = lane + 64, k2 = lane + 128;
        npbT[(k0 >> 3) * (P_ * 8) + p * 8 + (k0 & 7)] = b0;
        npbT[(k1 >> 3) * (P_ * 8) + p * 8 + (k1 & 7)] = b1;
        npbT[(k2 >> 3) * (P_ * 8) + p * 8 + (k2 & 7)] = b2;
        if (lane < 8) {
            int k3 = lane + 192;
            npbT[(k3 >> 3) * (P_ * 8) + p * 8 + (k3 & 7)] = b3;
        }
        if (lane < 24) {
            int k4 = 200 + lane;
            npbT[(k4 >> 3) * (P_ * 8) + p * 8 + (k4 & 7)] = 0;
        }
    }

    float a0 = fabsf(s0), a1 = fabsf(s1), a2 = fabsf(s2), a3 = fabsf(s3);

    int ch0 = -1, ch1 = -1, ch2 = -1;
    float cs0 = 0.f, cs1 = 0.f, cs2 = 0.f;

    for (int r = 0; r < 3; r++) {
        float bv = -1.0f;
        int bi = 1 << 30;
        {
            int n = lane;
            bool sk = (n == ch0) || (n == ch1) || (n == ch2);
            if (!sk && a0 > bv) { bv = a0; bi = n; }
        }
        {
            int n = lane + 64;
            bool sk = (n == ch0) || (n == ch1) || (n == ch2);
            if (!sk && (a1 > bv || (a1 == bv && n < bi))) { bv = a1; bi = n; }
        }
        {
            int n = lane + 128;
            bool sk = (n == ch0) || (n == ch1) || (n == ch2);
            if (!sk && (a2 > bv || (a2 == bv && n < bi))) { bv = a2; bi = n; }
        }
        if (lane < 8) {
            int n = lane + 192;
            bool sk = (n == ch0) || (n == ch1) || (n == ch2);
            if (!sk && (a3 > bv || (a3 == bv && n < bi))) { bv = a3; bi = n; }
        }
        for (int off = 32; off; off >>= 1) {
            float ov = __shfl_down(bv, off);
            int oi = __shfl_down(bi, off);
            if (ov > bv || (ov == bv && oi < bi)) { bv = ov; bi = oi; }
        }
        bi = __shfl(bi, 0);
        int slot = bi >> 6, src = bi & 63;
        float mine = (slot == 0) ? s0 : (slot == 1) ? s1 : (slot == 2) ? s2 : s3;
        float sval = __shfl(mine, src);
        if (r == 0) { ch0 = bi; cs0 = sval; }
        else if (r == 1) { ch1 = bi; cs1 = sval; }
        else { ch2 = bi; cs2 = sval; }
    }

    if (lane == 0) {
        float* keyval = ws + OFF_KEYVAL;
        int* keyidx = (int*)(ws + OFF_KEYIDX);
        keyval[p * 4 + 0] = cs0; keyval[p * 4 + 1] = cs1; keyval[p * 4 + 2] = cs2;
        keyidx[p * 4 + 0] = ch0; keyidx[p * 4 + 1] = ch1; keyidx[p * 4 + 2] = ch2;
        float lenp = sqrtf(ss) * rn;
        float lentopp = sqrtf(cs0 * cs0 + cs1 * cs1 + cs2 * cs2);
        float d = 1.0f - lentopp / lenp;
        atomicAdd(ws + OFF_NORM, d * d * (1.0f / (float)P_));
    }
}

// ================= prep: pat (0..399) + tnorm K-outer (400..1615) ============
__global__ __launch_bounds__(256) void prep_kernel(const float* __restrict__ x,
                                                   const float* __restrict__ patterns,
                                                   float* __restrict__ ws) {
    __shared__ unsigned short xt16[64 * 210];
    __shared__ float psums[256];
    __shared__ float rns[64];

    if (blockIdx.x < 400) { pat_body(patterns, ws, blockIdx.x, threadIdx.x); return; }

    const int blk = blockIdx.x - 400;
    const int tid = threadIdx.x;
    const int t = tid & 63, r = tid >> 6;
    const int b = blk / 19;
    const int t0 = (blk % 19) * 64;
    const bool valid = (t0 + t) < T_;

    float ss = 0.0f;
    if (valid) {
        const float* xp = x + (size_t)b * N_ * T_ + t0 + t;
#pragma unroll 5
        for (int i = 0; i < 50; ++i) {
            int n = r * 50 + i;
            float v = xp[(size_t)n * T_];
            ss += v * v;
            xt16[t * 210 + n] = f2bf(v);
        }
    }
    psums[tid] = ss;
    __syncthreads();
    if (tid < 64) {
        float s = psums[tid] + psums[tid + 64] + psums[tid + 128] + psums[tid + 192];
        rns[tid] = rsqrtf(s + EPS_);
    }
    __syncthreads();

    // write K-outer: xnT[b][seg][t][8]; consecutive tids -> consecutive t (coalesced)
    unsigned short* xnT = (unsigned short*)(ws + OFF_XN);
#pragma unroll
    for (int j = 0; j < 7; ++j) {
        int idx = tid + 256 * j;            // 1792 = 28 segs x 64 t
        int seg = idx >> 6, tt = idx & 63;
        if (t0 + tt >= T_) continue;
        s8v ov = (s8v){0, 0, 0, 0, 0, 0, 0, 0};
        if (seg < 25) {
            float rn = rns[tt];
            const unsigned* src = (const unsigned*)&xt16[tt * 210 + seg * 8];
            unsigned o[4];
#pragma unroll
            for (int i = 0; i < 4; ++i) {
                unsigned u = src[i];
                float lo = __uint_as_float(u << 16) * rn;
                float hi = __uint_as_float(u & 0xffff0000u) * rn;
                o[i] = (unsigned)f2bf(lo) | ((unsigned)f2bf(hi) << 16);
            }
            ov = (s8v){(short)(o[0] & 0xffff), (short)(o[0] >> 16),
                       (short)(o[1] & 0xffff), (short)(o[1] >> 16),
                       (short)(o[2] & 0xffff), (short)(o[2] >> 16),
                       (short)(o[3] & 0xffff), (short)(o[3] >> 16)};
        }
        *(s8v*)(xnT + (((size_t)b * 28 + seg) * T_ + t0 + tt) * 8) = ov;
    }
}

// ================= work: gemm blocks (nid 0..959) + orth blocks (960..964) ===
// 320 thr = 5 waves. gemm: M=400 frames x N=80 pats, K=224; A coalesced from
// K-outer xnT, B in LDS once, R4-proven okey pooling epilogue.
// orth: same K-loop with A=npbT (M=400 patterns) -> simpp tile epilogue.
__global__ __launch_bounds__(320, 2) void work_kernel(float* __restrict__ ws,
                                                      const int* __restrict__ length,
                                                      float* __restrict__ pes) {
    __shared__ short ldsB[80 * BSTRIDE];
    __shared__ unsigned pool[16 * 80];
    __shared__ float psum[80];

    const int tid = threadIdx.x;
    // bijective XCD swizzle over 965 blocks (m204): q=120, r=5
    int orig = blockIdx.x;
    int xcd = orig & 7, rem = orig >> 3;
    int nid = (xcd < 5 ? xcd * 121 : 5 * 121 + (xcd - 5) * 120) + rem;

    const bool isOrth = (nid >= 960);
    const int pb = isOrth ? (nid - 960) : (nid % 5);
    const int mb = isOrth ? 0 : ((nid / 5) % 3);
    const int b  = isOrth ? 0 : (nid / 15);

    const unsigned short* npb = (const unsigned short*)(ws + OFF_NPB16) + (size_t)(pb * 80) * KPAD;

    // stage B once: 80 rows x 224 shorts
#pragma unroll
    for (int j = 0; j < 7; ++j) {
        int idx = tid + 320 * j;
        int row = idx / 28, seg = idx % 28;
        *(s8v*)(&ldsB[row * BSTRIDE + seg * 8]) = *(const s8v*)(npb + (size_t)row * KPAD + seg * 8);
    }
    for (int i = tid; i < 1280; i += 320) pool[i] = 0u;
    if (tid < 80) psum[tid] = 0.f;
    __syncthreads();

    const int wv = tid >> 6;
    const int lane = tid & 63;
    const int l15 = lane & 15, kg = lane >> 4;

    f4v acc[5][5];
#pragma unroll
    for (int mi = 0; mi < 5; ++mi)
#pragma unroll
        for (int ni = 0; ni < 5; ++ni) acc[mi][ni] = (f4v){0.f, 0.f, 0.f, 0.f};

    // A base: K-outer [seg][TT rows][8]; lane addr = (kg*TT + row)*8
    const int TT = isOrth ? P_ : T_;
    const unsigned short* abase = isOrth
        ? (const unsigned short*)(ws + OFF_NPBT)
        : (const unsigned short*)(ws + OFF_XN) + (size_t)b * 28 * T_ * 8;
    const int segstep = 4 * TT * 8;                   // shorts per K-chunk
    const unsigned short* ar[5];
#pragma unroll
    for (int mi = 0; mi < 5; ++mi)
        ar[mi] = abase + ((size_t)kg * TT + (mb * 400 + wv * 80 + mi * 16 + l15)) * 8;

    // 2-deep rotating A prefetch
    s8v A[3][5];
#pragma unroll
    for (int mi = 0; mi < 5; ++mi) {
        A[0][mi] = *(const s8v*)(ar[mi]);
        A[1][mi] = *(const s8v*)(ar[mi] + segstep);
    }

#pragma unroll
    for (int c = 0; c < 7; ++c) {
        if (c + 2 < 7) {
#pragma unroll
            for (int mi = 0; mi < 5; ++mi)
                A[(c + 2) % 3][mi] = *(const s8v*)(ar[mi] + (c + 2) * segstep);
        }
        s8v bf[5];
#pragma unroll
        for (int ni = 0; ni < 5; ++ni)
            bf[ni] = *(const s8v*)(&ldsB[(ni * 16 + l15) * BSTRIDE + c * 32 + kg * 8]);
#pragma unroll
        for (int mi = 0; mi < 5; ++mi) {
#pragma unroll
            for (int ni = 0; ni < 5; ++ni)
                acc[mi][ni] = __builtin_amdgcn_mfma_f32_16x16x32_bf16(A[c % 3][mi], bf[ni], acc[mi][ni], 0, 0, 0);
        }
    }
    __syncthreads();

    if (isOrth) {
        // simpp tile [400 x 80]: relu((|s|-0.3)/0.70001)^2, excl diag
        float part = 0.f;
#pragma unroll
        for (int mi = 0; mi < 5; ++mi) {
            int rb = wv * 80 + mi * 16 + kg * 4;
#pragma unroll
            for (int ni = 0; ni < 5; ++ni) {
                int col = pb * 80 + ni * 16 + l15;
#pragma unroll
                for (int jj = 0; jj < 4; ++jj) {
                    if (rb + jj == col) continue;
                    float t = (fabsf(acc[mi][ni][jj]) - 0.3f) * (1.0f / 0.70001f);
                    if (t > 0.0f) part += t * t;
                }
            }
        }
        // wave reduce then block reduce via pool scratch
        for (int off = 32; off; off >>= 1) part += __shfl_down(part, off);
        float* red = (float*)pool;
        if (lane == 0) red[wv] = part;
        __syncthreads();
        if (tid == 0) {
            float s = red[0] + red[1] + red[2] + red[3] + red[4];
            atomicAdd(ws + OFF_ORTH, s * (1.0f / ((float)P_ * (float)P_)));
        }
        return;
    }

    // ---- R4-proven pooling epilogue ----
    unsigned stash[4];
    const int pp = tid % 80, wg = tid / 80;
    for (int pass = 0; pass < 2; ++pass) {
        float sgn = pass ? -1.f : 1.f;
#pragma unroll
        for (int mi = 0; mi < 5; ++mi) {
            int f0 = wv * 80 + mi * 16 + kg * 4;
            int w0 = f0 / 25, w3 = (f0 + 3) / 25;
            int wsplit = w3 * 25;
#pragma unroll
            for (int ni = 0; ni < 5; ++ni) {
                int pc = ni * 16 + l15;
                float m0 = -1e30f, m1 = -1e30f;
#pragma unroll
                for (int jj = 0; jj < 4; ++jj) {
                    float v = sgn * acc[mi][ni][jj];
                    if (f0 + jj < wsplit) m0 = fmaxf(m0, v);
                    else m1 = fmaxf(m1, v);
                }
                atomicMax(&pool[w3 * 80 + pc], okey(m1));
                if (w0 != w3) atomicMax(&pool[w0 * 80 + pc], okey(m0));
            }
        }
        __syncthreads();
        if (pass == 0) {
#pragma unroll
            for (int i2 = 0; i2 < 4; ++i2) stash[i2] = pool[(wg * 4 + i2) * 80 + pp];
            __syncthreads();
            for (int i2 = tid; i2 < 1280; i2 += 320) pool[i2] = 0u;
            __syncthreads();
        } else {
            float part = 0.f;
#pragma unroll
            for (int i2 = 0; i2 < 4; ++i2)
                part += dekey(stash[i2]) + dekey(pool[(wg * 4 + i2) * 80 + pp]);
            atomicAdd(&psum[pp], part);
        }
    }
    __syncthreads();
    if (tid < 80) {
        float rsap = 1.0f / (float)(length[b] / STRIDE_);
        atomicAdd(&pes[(size_t)b * P_ + pb * 80 + tid], psum[tid] * 0.5f * rsap);
    }
}

// ---------------- fallback fp32 fused GEMM+pool ------------------------------
__global__ __launch_bounds__(256) void main_kernel(const float* __restrict__ x,
                                                   const int* __restrict__ length,
                                                   const float* __restrict__ ws,
                                                   float* __restrict__ pes) {
    __shared__ float xs[N_][STRIDE_ + 1];
    __shared__ float rnorm[STRIDE_];
    __shared__ float poolp[P_][5];
    __shared__ float pooln[P_][5];

    int w = blockIdx.x;
    int b = blockIdx.y;
    const float* xb = x + (size_t)b * N_ * T_ + (size_t)w * STRIDE_;

    for (int i = threadIdx.x; i < N_ * STRIDE_; i += 256) {
        int n = i / STRIDE_;
        int t = i - n * STRIDE_;
        xs[n][t] = xb[n * T_ + t];
    }
    __syncthreads();

    if (threadIdx.x < STRIDE_) {
        float ssf = 0.0f;
        for (int n = 0; n < N_; n++) { float vv = xs[n][threadIdx.x]; ssf += vv * vv; }
        rnorm[threadIdx.x] = 1.0f / sqrtf(ssf + EPS_);
    }
    __syncthreads();

    int pt = threadIdx.x % 50;
    int tt = threadIdx.x / 50;

    if (tt < 5) {
        float acc[8][5];
#pragma unroll
        for (int i = 0; i < 8; i++)
#pragma unroll
            for (int j = 0; j < 5; j++) acc[i][j] = 0.0f;

        const float4* np4 = (const float4*)(ws + OFF_NPATT);
        int pbq = pt * 2;
        for (int n = 0; n < N_; n++) {
            float4 q0 = np4[n * (P_ / 4) + pbq];
            float4 q1 = np4[n * (P_ / 4) + pbq + 1];
            float qa[8] = { q0.x, q0.y, q0.z, q0.w, q1.x, q1.y, q1.z, q1.w };
            float xv0 = xs[n][tt * 5 + 0];
            float xv1 = xs[n][tt * 5 + 1];
            float xv2 = xs[n][tt * 5 + 2];
            float xv3 = xs[n][tt * 5 + 3];
            float xv4 = xs[n][tt * 5 + 4];
#pragma unroll
            for (int i = 0; i < 8; i++) {
                acc[i][0] += qa[i] * xv0;
                acc[i][1] += qa[i] * xv1;
                acc[i][2] += qa[i] * xv2;
                acc[i][3] += qa[i] * xv3;
                acc[i][4] += qa[i] * xv4;
            }
        }
#pragma unroll
        for (int i = 0; i < 8; i++) {
            float pm = -1e30f, nm = -1e30f;
#pragma unroll
            for (int j = 0; j < 5; j++) {
                float s = acc[i][j] * rnorm[tt * 5 + j];
                pm = fmaxf(pm, s);
                nm = fmaxf(nm, -s);
            }
            poolp[pt * 8 + i][tt] = pm;
            pooln[pt * 8 + i][tt] = nm;
        }
    }
    __syncthreads();

    float rsap = 1.0f / (float)(length[b] / STRIDE_);
    for (int p = threadIdx.x; p < P_; p += 256) {
        float pm = poolp[p][0], nm = pooln[p][0];
#pragma unroll
        for (int q = 1; q < 5; q++) {
            pm = fmaxf(pm, poolp[p][q]);
            nm = fmaxf(nm, pooln[p][q]);
        }
        atomicAdd(&pes[b * P_ + p], (pm + nm) * 0.5f * rsap);
    }
}

// ---------------- sparse graphs assembly + scalar outputs --------------------
__global__ __launch_bounds__(256) void graphs_kernel(const float* __restrict__ ws,
                                                     float* __restrict__ out) {
    int idx = blockIdx.x * 256 + threadIdx.x;
    if (idx == 0) {
        out[(size_t)B_ * N_ * N_] = ws[OFF_NORM];
        out[(size_t)B_ * N_ * N_ + 1] = ws[OFF_ORTH];
    }
    if (idx >= B_ * P_) return;
    int b = idx / P_;
    int p = idx - b * P_;

    float e = ws[OFF_PES + b * P_ + p];
    const float* keyval = ws + OFF_KEYVAL;
    const int* keyidx = (const int*)(ws + OFF_KEYIDX);
    float va[3] = { keyval[p * 4 + 0], keyval[p * 4 + 1], keyval[p * 4 + 2] };
    int ia[3] = { keyidx[p * 4 + 0], keyidx[p * 4 + 1], keyidx[p * 4 + 2] };

    float* g = out + (size_t)b * N_ * N_;
#pragma unroll
    for (int a = 0; a < 3; a++) {
#pragma unroll
        for (int c = 0; c < 3; c++) {
            float scale = (ia[a] == ia[c]) ? 1.0f : 6.0f;
            atomicAdd(&g[ia[a] * N_ + ia[c]], va[a] * va[c] * e * scale);
        }
    }
}

// ---------------- standalone pat/orth for fallback path ----------------------
__global__ __launch_bounds__(64) void pat_kernel(const float* __restrict__ patterns,
                                                 float* __restrict__ ws) {
    pat_body(patterns, ws, blockIdx.x, threadIdx.x);
}
__global__ __launch_bounds__(256) void orth_kernel(float* __restrict__ ws) {
    __shared__ float rowi[N_];
    __shared__ float red[256];
    const float* npatT = ws + OFF_NPATT;
    int i = blockIdx.x;
    for (int k = threadIdx.x; k < N_; k += 256) rowi[k] = npatT[k * P_ + i];
    __syncthreads();

    float partial = 0.0f;
    for (int j = threadIdx.x; j < P_; j += 256) {
        if (j == i) continue;
        float s = 0.0f;
        for (int k = 0; k < N_; k++) s += rowi[k] * npatT[k * P_ + j];
        float t = (fabsf(s) - 0.3f) * (1.0f / 0.70001f);
        if (t > 0.0f) partial += t * t;
    }
    red[threadIdx.x] = partial;
    __syncthreads();
    for (int sft = 128; sft; sft >>= 1) {
        if (threadIdx.x < sft) red[threadIdx.x] += red[threadIdx.x + sft];
        __syncthreads();
    }
    if (threadIdx.x == 0)
        atomicAdd(ws + OFF_ORTH, red[0] * (1.0f / ((float)P_ * (float)P_)));
}

extern "C" void kernel_launch(void* const* d_in, const int* in_sizes, int n_in,
                              void* d_out, int out_size, void* d_ws, size_t ws_size,
                              hipStream_t stream) {
    const float* x = (const float*)d_in[0];
    const float* patterns = (const float*)d_in[1];
    const int* length = (const int*)d_in[2];
    float* out = (float*)d_out;
    float* ws = (float*)d_ws;

    hipMemsetAsync(ws + OFF_PES, 0, (size_t)(B_ * P_ + 2) * sizeof(float), stream);
    hipMemsetAsync(d_out, 0, (size_t)B_ * N_ * N_ * sizeof(float), stream);

    if (ws_size >= (size_t)WS_FAST_FLOATS * sizeof(float)) {
        prep_kernel<<<400 + 19 * B_, 256, 0, stream>>>(x, patterns, ws);
        work_kernel<<<965, 320, 0, stream>>>(ws, length, ws + OFF_PES);
    } else {
        pat_kernel<<<P_, 64, 0, stream>>>(patterns, ws);
        orth_kernel<<<P_, 256, 0, stream>>>(ws);
        main_kernel<<<dim3(T_ / STRIDE_, B_), 256, 0, stream>>>(x, length, ws, ws + OFF_PES);
    }
    graphs_kernel<<<(B_ * P_ + 255) / 256, 256, 0, stream>>>(ws, out);
}

// Round 8
// 98.719 us; speedup vs baseline: 1.5440x; 1.2539x over previous
//
#include <hip/hip_runtime.h>
#include <math.h>

#define B_ 64
#define N_ 200
#define P_ 400
#define T_ 1200
#define TPAD 1280
#define PPAD 512
#define STRIDE_ 25
#define EPS_ 1e-9f
#define KPAD 224
#define BSTRIDE 232   // LDS B row stride in shorts

// ws layout (float offsets)
#define OFF_NPATT  0            // [N_][P_] f32 transposed normalized patterns (80000)
#define OFF_NPB16  80000        // [P_][KPAD] bf16 row-major patterns (44800)
#define OFF_KEYVAL 124800       // [P_][4]
#define OFF_KEYIDX 126400       // [P_][4] int
#define OFF_PES    128000       // [B_][P_] (fallback path)
#define OFF_NORM   153600
#define OFF_ORTH   153601
#define OFF_NPBT   153604       // [28][PPAD][8] bf16 K-outer patterns (57344 f32)
#define OFF_XN     210948       // [B_][28][TPAD][8] bf16 K-outer frames (9175040 f32)
#define OFF_GPOOL  9385988      // [2][B_][48][400] okey uints (2457600)
#define WS_FAST_FLOATS (9385988 + 2457600)

typedef float f4v __attribute__((ext_vector_type(4)));
typedef short s8v __attribute__((ext_vector_type(8)));

__device__ inline unsigned short f2bf(float f) {
    union { float f; unsigned u; } v; v.f = f;
    unsigned r = v.u + 0x7FFFu + ((v.u >> 16) & 1u);
    return (unsigned short)(r >> 16);
}
__device__ inline unsigned okey(float f) {
    unsigned u = __float_as_uint(f);
    return (u & 0x80000000u) ? ~u : (u | 0x80000000u);
}
__device__ inline float dekey(unsigned k) {
    unsigned u = (k & 0x80000000u) ? (k & 0x7fffffffu) : ~k;
    return __uint_as_float(u);
}

// ================= pat body: normalize, top-3, bf16 copies ===================
__device__ void pat_body(const float* __restrict__ patterns, float* __restrict__ ws,
                         int p, int tid) {
    if (tid >= 64) return;
    int lane = tid;

    float v0 = patterns[p * N_ + lane];
    float v1 = patterns[p * N_ + lane + 64];
    float v2 = patterns[p * N_ + lane + 128];
    float v3 = (lane < 8) ? patterns[p * N_ + lane + 192] : 0.0f;

    float ss = v0 * v0 + v1 * v1 + v2 * v2 + v3 * v3;
    for (int off = 32; off; off >>= 1) ss += __shfl_down(ss, off);
    ss = __shfl(ss, 0);

    float rn = 1.0f / sqrtf(ss + EPS_);
    float s0 = v0 * rn, s1 = v1 * rn, s2 = v2 * rn, s3 = v3 * rn;

    float* npatT = ws + OFF_NPATT;
    npatT[(lane) * P_ + p] = s0;
    npatT[(lane + 64) * P_ + p] = s1;
    npatT[(lane + 128) * P_ + p] = s2;
    if (lane < 8) npatT[(lane + 192) * P_ + p] = s3;

    unsigned short* npb = (unsigned short*)(ws + OFF_NPB16);
    unsigned short b0 = f2bf(s0), b1 = f2bf(s1), b2 = f2bf(s2), b3 = f2bf(s3);
    npb[p * KPAD + lane] = b0;
    npb[p * KPAD + lane + 64] = b1;
    npb[p * KPAD + lane + 128] = b2;
    if (lane < 8) npb[p * KPAD + lane + 192] = b3;
    if (lane < 24) npb[p * KPAD + 200 + lane] = 0;

    // K-outer copy: npbT[k/8][p][k%8] (rows >= 400 pre-zeroed by memset)
    unsigned short* npbT = (unsigned short*)(ws + OFF_NPBT);
    {
        int k0 = lane, k1 = lane + 64, k2 = lane + 128;
        npbT[(k0 >> 3) * (PPAD * 8) + p * 8 + (k0 & 7)] = b0;
        npbT[(k1 >> 3) * (PPAD * 8) + p * 8 + (k1 & 7)] = b1;
        npbT[(k2 >> 3) * (PPAD * 8) + p * 8 + (k2 & 7)] = b2;
        if (lane < 8) {
            int k3 = lane + 192;
            npbT[(k3 >> 3) * (PPAD * 8) + p * 8 + (k3 & 7)] = b3;
        }
        if (lane < 24) {
            int k4 = 200 + lane;
            npbT[(k4 >> 3) * (PPAD * 8) + p * 8 + (k4 & 7)] = 0;
        }
    }

    float a0 = fabsf(s0), a1 = fabsf(s1), a2 = fabsf(s2), a3 = fabsf(s3);

    int ch0 = -1, ch1 = -1, ch2 = -1;
    float cs0 = 0.f, cs1 = 0.f, cs2 = 0.f;

    for (int r = 0; r < 3; r++) {
        float bv = -1.0f;
        int bi = 1 << 30;
        {
            int n = lane;
            bool sk = (n == ch0) || (n == ch1) || (n == ch2);
            if (!sk && a0 > bv) { bv = a0; bi = n; }
        }
        {
            int n = lane + 64;
            bool sk = (n == ch0) || (n == ch1) || (n == ch2);
            if (!sk && (a1 > bv || (a1 == bv && n < bi))) { bv = a1; bi = n; }
        }
        {
            int n = lane + 128;
            bool sk = (n == ch0) || (n == ch1) || (n == ch2);
            if (!sk && (a2 > bv || (a2 == bv && n < bi))) { bv = a2; bi = n; }
        }
        if (lane < 8) {
            int n = lane + 192;
            bool sk = (n == ch0) || (n == ch1) || (n == ch2);
            if (!sk && (a3 > bv || (a3 == bv && n < bi))) { bv = a3; bi = n; }
        }
        for (int off = 32; off; off >>= 1) {
            float ov = __shfl_down(bv, off);
            int oi = __shfl_down(bi, off);
            if (ov > bv || (ov == bv && oi < bi)) { bv = ov; bi = oi; }
        }
        bi = __shfl(bi, 0);
        int slot = bi >> 6, src = bi & 63;
        float mine = (slot == 0) ? s0 : (slot == 1) ? s1 : (slot == 2) ? s2 : s3;
        float sval = __shfl(mine, src);
        if (r == 0) { ch0 = bi; cs0 = sval; }
        else if (r == 1) { ch1 = bi; cs1 = sval; }
        else { ch2 = bi; cs2 = sval; }
    }

    if (lane == 0) {
        float* keyval = ws + OFF_KEYVAL;
        int* keyidx = (int*)(ws + OFF_KEYIDX);
        keyval[p * 4 + 0] = cs0; keyval[p * 4 + 1] = cs1; keyval[p * 4 + 2] = cs2;
        keyidx[p * 4 + 0] = ch0; keyidx[p * 4 + 1] = ch1; keyidx[p * 4 + 2] = ch2;
        float lenp = sqrtf(ss) * rn;
        float lentopp = sqrtf(cs0 * cs0 + cs1 * cs1 + cs2 * cs2);
        float d = 1.0f - lentopp / lenp;
        atomicAdd(ws + OFF_NORM, d * d * (1.0f / (float)P_));
    }
}

// ================= prep: pat (0..399) + tnorm K-outer (400..1679) ============
__global__ __launch_bounds__(256) void prep_kernel(const float* __restrict__ x,
                                                   const float* __restrict__ patterns,
                                                   float* __restrict__ ws) {
    __shared__ unsigned short xt16[64 * 210];
    __shared__ float psums[256];
    __shared__ float rns[64];

    if (blockIdx.x < 400) { pat_body(patterns, ws, blockIdx.x, threadIdx.x); return; }

    const int blk = blockIdx.x - 400;
    const int tid = threadIdx.x;
    const int t = tid & 63, r = tid >> 6;
    const int b = blk / 20;
    const int t0 = (blk % 20) * 64;          // covers 0..1279 (pad frames zeroed)
    const bool valid = (t0 + t) < T_;

    float ss = 0.0f;
    if (valid) {
        const float* xp = x + (size_t)b * N_ * T_ + t0 + t;
#pragma unroll 5
        for (int i = 0; i < 50; ++i) {
            int n = r * 50 + i;
            float v = xp[(size_t)n * T_];
            ss += v * v;
            xt16[t * 210 + n] = f2bf(v);
        }
    }
    psums[tid] = ss;
    __syncthreads();
    if (tid < 64) {
        float s = psums[tid] + psums[tid + 64] + psums[tid + 128] + psums[tid + 192];
        rns[tid] = rsqrtf(s + EPS_);
    }
    __syncthreads();

    // K-outer write: xnT[b][seg][t][8]; invalid/pad -> zeros
    unsigned short* xnT = (unsigned short*)(ws + OFF_XN);
#pragma unroll
    for (int j = 0; j < 7; ++j) {
        int idx = tid + 256 * j;            // 1792 = 28 segs x 64 t
        int seg = idx >> 6, tt = idx & 63;
        s8v ov = (s8v){0, 0, 0, 0, 0, 0, 0, 0};
        if (seg < 25 && (t0 + tt) < T_) {
            float rn = rns[tt];
            const unsigned* src = (const unsigned*)&xt16[tt * 210 + seg * 8];
            unsigned o[4];
#pragma unroll
            for (int i = 0; i < 4; ++i) {
                unsigned u = src[i];
                float lo = __uint_as_float(u << 16) * rn;
                float hi = __uint_as_float(u & 0xffff0000u) * rn;
                o[i] = (unsigned)f2bf(lo) | ((unsigned)f2bf(hi) << 16);
            }
            ov = (s8v){(short)(o[0] & 0xffff), (short)(o[0] >> 16),
                       (short)(o[1] & 0xffff), (short)(o[1] >> 16),
                       (short)(o[2] & 0xffff), (short)(o[2] >> 16),
                       (short)(o[3] & 0xffff), (short)(o[3] >> 16)};
        }
        *(s8v*)(xnT + (((size_t)b * 28 + seg) * TPAD + t0 + tt) * 8) = ov;
    }
}

// ================= work: gemm (nid 0..3199) + orth (3200..3219) ==============
// 256 thr = 4 waves; wave tile 32 rows x 80 pats (acc[2][5] = 40 AGPR).
// M-tile 128 (ragged via zero-padded xn), B in LDS once, 4-deep A prefetch,
// okey pooling -> global gpool (w<48 guard).
__global__ __launch_bounds__(256, 4) void work_kernel(float* __restrict__ ws,
                                                      unsigned* __restrict__ gpool) {
    __shared__ short ldsB[80 * BSTRIDE];       // 37.1 KB
    __shared__ unsigned pool[2 * 7 * 80];      // pos/neg window slots

    const int tid = threadIdx.x;
    // bijective XCD swizzle over 3220 blocks: q=402, r=4
    int orig = blockIdx.x;
    int xcd = orig & 7, rem = orig >> 3;
    int nid = (xcd < 4 ? xcd * 403 : 4 * 403 + (xcd - 4) * 402) + rem;

    const bool isOrth = (nid >= 3200);
    int pb, mb, b;
    if (isOrth) { int o = nid - 3200; pb = o % 5; mb = o / 5; b = 0; }
    else        { pb = nid % 5; mb = (nid / 5) % 10; b = nid / 50; }

    const unsigned short* npb = (const unsigned short*)(ws + OFF_NPB16) + (size_t)(pb * 80) * KPAD;

    // stage B once: 80 rows x 224 shorts = 2240 16B units
#pragma unroll
    for (int j = 0; j < 9; ++j) {
        int idx = tid + 256 * j;
        if (idx < 2240) {
            int row = idx / 28, seg = idx % 28;
            *(s8v*)(&ldsB[row * BSTRIDE + seg * 8]) = *(const s8v*)(npb + (size_t)row * KPAD + seg * 8);
        }
    }
    for (int i = tid; i < 1120; i += 256) pool[i] = 0u;
    __syncthreads();

    const int wv = tid >> 6;
    const int lane = tid & 63;
    const int l15 = lane & 15, kg = lane >> 4;

    f4v acc[2][5];
#pragma unroll
    for (int mi = 0; mi < 2; ++mi)
#pragma unroll
        for (int ni = 0; ni < 5; ++ni) acc[mi][ni] = (f4v){0.f, 0.f, 0.f, 0.f};

    // A: K-outer [seg][rows][8]; seg = 4c+kg
    const int ROWS = isOrth ? PPAD : TPAD;
    const unsigned short* abase = isOrth
        ? (const unsigned short*)(ws + OFF_NPBT)
        : (const unsigned short*)(ws + OFF_XN) + (size_t)b * 28 * TPAD * 8;
    const int segstep = 4 * ROWS * 8;
    const int row0 = mb * 128 + wv * 32 + l15;
    const unsigned short* ar0 = abase + ((size_t)kg * ROWS + row0) * 8;
    const unsigned short* ar1 = ar0 + 16 * 8;            // mi=1 rows +16

    // 4-deep rotating prefetch
    s8v A[4][2];
#pragma unroll
    for (int c = 0; c < 4; ++c) {
        A[c][0] = *(const s8v*)(ar0 + c * segstep);
        A[c][1] = *(const s8v*)(ar1 + c * segstep);
    }

#pragma unroll
    for (int c = 0; c < 7; ++c) {
        if (c + 4 < 7) {
            A[(c + 4) & 3][0] = *(const s8v*)(ar0 + (c + 4) * segstep);
            A[(c + 4) & 3][1] = *(const s8v*)(ar1 + (c + 4) * segstep);
        }
        s8v bf[5];
#pragma unroll
        for (int ni = 0; ni < 5; ++ni)
            bf[ni] = *(const s8v*)(&ldsB[(ni * 16 + l15) * BSTRIDE + c * 32 + kg * 8]);
#pragma unroll
        for (int ni = 0; ni < 5; ++ni) {
            acc[0][ni] = __builtin_amdgcn_mfma_f32_16x16x32_bf16(A[c & 3][0], bf[ni], acc[0][ni], 0, 0, 0);
            acc[1][ni] = __builtin_amdgcn_mfma_f32_16x16x32_bf16(A[c & 3][1], bf[ni], acc[1][ni], 0, 0, 0);
        }
    }

    if (isOrth) {
        // simpp tile: relu((|s|-0.3)/0.70001)^2 excl diag; pad rows give s=0
        float part = 0.f;
#pragma unroll
        for (int mi = 0; mi < 2; ++mi) {
            int rb = mb * 128 + wv * 32 + mi * 16 + kg * 4;
#pragma unroll
            for (int ni = 0; ni < 5; ++ni) {
                int col = pb * 80 + ni * 16 + l15;
#pragma unroll
                for (int jj = 0; jj < 4; ++jj) {
                    if (rb + jj == col) continue;
                    float t = (fabsf(acc[mi][ni][jj]) - 0.3f) * (1.0f / 0.70001f);
                    if (t > 0.0f) part += t * t;
                }
            }
        }
        for (int off = 32; off; off >>= 1) part += __shfl_down(part, off);
        __syncthreads();
        float* red = (float*)pool;
        if (lane == 0) red[wv] = part;
        __syncthreads();
        if (tid == 0)
            atomicAdd(ws + OFF_ORTH, (red[0] + red[1] + red[2] + red[3]) *
                                     (1.0f / ((float)P_ * (float)P_)));
        return;
    }

    // ---- okey pooling into LDS slots (single pass, pos+neg) ----
    const int wbase = (mb * 128) / 25;
#pragma unroll
    for (int mi = 0; mi < 2; ++mi) {
        int f0 = mb * 128 + wv * 32 + mi * 16 + kg * 4;
        int w0 = f0 / 25, w3 = (f0 + 3) / 25;
        int wsplit = w3 * 25;
#pragma unroll
        for (int ni = 0; ni < 5; ++ni) {
            int pc = ni * 16 + l15;
            float p0 = -1e30f, p1 = -1e30f, n0 = -1e30f, n1 = -1e30f;
#pragma unroll
            for (int jj = 0; jj < 4; ++jj) {
                float v = acc[mi][ni][jj];
                if (f0 + jj < wsplit) { p0 = fmaxf(p0, v); n0 = fmaxf(n0, -v); }
                else                 { p1 = fmaxf(p1, v); n1 = fmaxf(n1, -v); }
            }
            atomicMax(&pool[(0 * 7 + (w3 - wbase)) * 80 + pc], okey(p1));
            atomicMax(&pool[(1 * 7 + (w3 - wbase)) * 80 + pc], okey(n1));
            if (w0 != w3) {
                atomicMax(&pool[(0 * 7 + (w0 - wbase)) * 80 + pc], okey(p0));
                atomicMax(&pool[(1 * 7 + (w0 - wbase)) * 80 + pc], okey(n0));
            }
        }
    }
    __syncthreads();

    // flush to global pool
    for (int e = tid; e < 1120; e += 256) {
        unsigned v = pool[e];
        if (!v) continue;
        int pass = e / 560, r2 = e % 560;
        int w = wbase + r2 / 80, p = r2 % 80;
        if (w < 48)
            atomicMax(&gpool[((size_t)(pass * B_ + b) * 48 + w) * 400 + pb * 80 + p], v);
    }
}

// ============== finalize: PES from gpool + graphs scatter + scalars ==========
__global__ __launch_bounds__(256) void graphs_kernel(const unsigned* __restrict__ gpool,
                                                     const int* __restrict__ length,
                                                     const float* __restrict__ ws,
                                                     float* __restrict__ out) {
    int idx = blockIdx.x * 256 + threadIdx.x;
    if (idx == 0) {
        out[(size_t)B_ * N_ * N_] = ws[OFF_NORM];
        out[(size_t)B_ * N_ * N_ + 1] = ws[OFF_ORTH];
    }
    if (idx >= B_ * P_) return;
    int b = idx / P_;
    int p = idx - b * P_;

    const unsigned* gp0 = gpool + (size_t)b * 48 * 400 + p;
    const unsigned* gp1 = gpool + (size_t)(B_ + b) * 48 * 400 + p;
    float s = 0.f;
#pragma unroll
    for (int w = 0; w < 48; ++w)
        s += dekey(gp0[w * 400]) + dekey(gp1[w * 400]);
    float rsap = 1.0f / (float)(length[b] / STRIDE_);
    float e = s * 0.5f * rsap;

    const float* keyval = ws + OFF_KEYVAL;
    const int* keyidx = (const int*)(ws + OFF_KEYIDX);
    float va[3] = { keyval[p * 4 + 0], keyval[p * 4 + 1], keyval[p * 4 + 2] };
    int ia[3] = { keyidx[p * 4 + 0], keyidx[p * 4 + 1], keyidx[p * 4 + 2] };

    float* g = out + (size_t)b * N_ * N_;
#pragma unroll
    for (int a = 0; a < 3; a++) {
#pragma unroll
        for (int c = 0; c < 3; c++) {
            float scale = (ia[a] == ia[c]) ? 1.0f : 6.0f;
            atomicAdd(&g[ia[a] * N_ + ia[c]], va[a] * va[c] * e * scale);
        }
    }
}

// ---------------- fallback path (fp32, correct, ws-independent) --------------
__global__ __launch_bounds__(256) void main_kernel(const float* __restrict__ x,
                                                   const int* __restrict__ length,
                                                   const float* __restrict__ ws,
                                                   float* __restrict__ pes) {
    __shared__ float xs[N_][STRIDE_ + 1];
    __shared__ float rnorm[STRIDE_];
    __shared__ float poolp[P_][5];
    __shared__ float pooln[P_][5];

    int w = blockIdx.x;
    int b = blockIdx.y;
    const float* xb = x + (size_t)b * N_ * T_ + (size_t)w * STRIDE_;

    for (int i = threadIdx.x; i < N_ * STRIDE_; i += 256) {
        int n = i / STRIDE_;
        int t = i - n * STRIDE_;
        xs[n][t] = xb[n * T_ + t];
    }
    __syncthreads();

    if (threadIdx.x < STRIDE_) {
        float ssf = 0.0f;
        for (int n = 0; n < N_; n++) { float vv = xs[n][threadIdx.x]; ssf += vv * vv; }
        rnorm[threadIdx.x] = 1.0f / sqrtf(ssf + EPS_);
    }
    __syncthreads();

    int pt = threadIdx.x % 50;
    int tt = threadIdx.x / 50;

    if (tt < 5) {
        float acc[8][5];
#pragma unroll
        for (int i = 0; i < 8; i++)
#pragma unroll
            for (int j = 0; j < 5; j++) acc[i][j] = 0.0f;

        const float4* np4 = (const float4*)(ws + OFF_NPATT);
        int pbq = pt * 2;
        for (int n = 0; n < N_; n++) {
            float4 q0 = np4[n * (P_ / 4) + pbq];
            float4 q1 = np4[n * (P_ / 4) + pbq + 1];
            float qa[8] = { q0.x, q0.y, q0.z, q0.w, q1.x, q1.y, q1.z, q1.w };
            float xv0 = xs[n][tt * 5 + 0];
            float xv1 = xs[n][tt * 5 + 1];
            float xv2 = xs[n][tt * 5 + 2];
            float xv3 = xs[n][tt * 5 + 3];
            float xv4 = xs[n][tt * 5 + 4];
#pragma unroll
            for (int i = 0; i < 8; i++) {
                acc[i][0] += qa[i] * xv0;
                acc[i][1] += qa[i] * xv1;
                acc[i][2] += qa[i] * xv2;
                acc[i][3] += qa[i] * xv3;
                acc[i][4] += qa[i] * xv4;
            }
        }
#pragma unroll
        for (int i = 0; i < 8; i++) {
            float pm = -1e30f, nm = -1e30f;
#pragma unroll
            for (int j = 0; j < 5; j++) {
                float s = acc[i][j] * rnorm[tt * 5 + j];
                pm = fmaxf(pm, s);
                nm = fmaxf(nm, -s);
            }
            poolp[pt * 8 + i][tt] = pm;
            pooln[pt * 8 + i][tt] = nm;
        }
    }
    __syncthreads();

    float rsap = 1.0f / (float)(length[b] / STRIDE_);
    for (int p = threadIdx.x; p < P_; p += 256) {
        float pm = poolp[p][0], nm = pooln[p][0];
#pragma unroll
        for (int q = 1; q < 5; q++) {
            pm = fmaxf(pm, poolp[p][q]);
            nm = fmaxf(nm, pooln[p][q]);
        }
        atomicAdd(&pes[b * P_ + p], (pm + nm) * 0.5f * rsap);
    }
}

__global__ __launch_bounds__(256) void fb_graphs_kernel(const float* __restrict__ ws,
                                                        float* __restrict__ out) {
    int idx = blockIdx.x * 256 + threadIdx.x;
    if (idx == 0) {
        out[(size_t)B_ * N_ * N_] = ws[OFF_NORM];
        out[(size_t)B_ * N_ * N_ + 1] = ws[OFF_ORTH];
    }
    if (idx >= B_ * P_) return;
    int b = idx / P_;
    int p = idx - b * P_;
    float e = ws[OFF_PES + b * P_ + p];
    const float* keyval = ws + OFF_KEYVAL;
    const int* keyidx = (const int*)(ws + OFF_KEYIDX);
    float va[3] = { keyval[p * 4 + 0], keyval[p * 4 + 1], keyval[p * 4 + 2] };
    int ia[3] = { keyidx[p * 4 + 0], keyidx[p * 4 + 1], keyidx[p * 4 + 2] };
    float* g = out + (size_t)b * N_ * N_;
#pragma unroll
    for (int a = 0; a < 3; a++)
#pragma unroll
        for (int c = 0; c < 3; c++) {
            float scale = (ia[a] == ia[c]) ? 1.0f : 6.0f;
            atomicAdd(&g[ia[a] * N_ + ia[c]], va[a] * va[c] * e * scale);
        }
}

__global__ __launch_bounds__(64) void pat_kernel(const float* __restrict__ patterns,
                                                 float* __restrict__ ws) {
    pat_body(patterns, ws, blockIdx.x, threadIdx.x);
}
__global__ __launch_bounds__(256) void orth_kernel(float* __restrict__ ws) {
    __shared__ float rowi[N_];
    __shared__ float red[256];
    const float* npatT = ws + OFF_NPATT;
    int i = blockIdx.x;
    for (int k = threadIdx.x; k < N_; k += 256) rowi[k] = npatT[k * P_ + i];
    __syncthreads();
    float partial = 0.0f;
    for (int j = threadIdx.x; j < P_; j += 256) {
        if (j == i) continue;
        float s = 0.0f;
        for (int k = 0; k < N_; k++) s += rowi[k] * npatT[k * P_ + j];
        float t = (fabsf(s) - 0.3f) * (1.0f / 0.70001f);
        if (t > 0.0f) partial += t * t;
    }
    red[threadIdx.x] = partial;
    __syncthreads();
    for (int sft = 128; sft; sft >>= 1) {
        if (threadIdx.x < sft) red[threadIdx.x] += red[threadIdx.x + sft];
        __syncthreads();
    }
    if (threadIdx.x == 0)
        atomicAdd(ws + OFF_ORTH, red[0] * (1.0f / ((float)P_ * (float)P_)));
}

extern "C" void kernel_launch(void* const* d_in, const int* in_sizes, int n_in,
                              void* d_out, int out_size, void* d_ws, size_t ws_size,
                              hipStream_t stream) {
    const float* x = (const float*)d_in[0];
    const float* patterns = (const float*)d_in[1];
    const int* length = (const int*)d_in[2];
    float* out = (float*)d_out;
    float* ws = (float*)d_ws;

    hipMemsetAsync(ws + OFF_PES, 0, (size_t)(B_ * P_ + 2) * sizeof(float), stream);
    hipMemsetAsync(d_out, 0, (size_t)B_ * N_ * N_ * sizeof(float), stream);

    if (ws_size >= (size_t)WS_FAST_FLOATS * sizeof(float)) {
        unsigned* gpool = (unsigned*)(ws + OFF_GPOOL);
        hipMemsetAsync(ws + OFF_NPBT, 0, (size_t)57344 * sizeof(float), stream);
        hipMemsetAsync(gpool, 0, (size_t)2 * B_ * 48 * 400 * sizeof(unsigned), stream);
        prep_kernel<<<400 + 20 * B_, 256, 0, stream>>>(x, patterns, ws);
        work_kernel<<<3220, 256, 0, stream>>>(ws, gpool);
        graphs_kernel<<<(B_ * P_ + 255) / 256, 256, 0, stream>>>(gpool, length, ws, out);
    } else {
        pat_kernel<<<P_, 64, 0, stream>>>(patterns, ws);
        orth_kernel<<<P_, 256, 0, stream>>>(ws);
        main_kernel<<<dim3(T_ / STRIDE_, B_), 256, 0, stream>>>(x, length, ws, ws + OFF_PES);
        fb_graphs_kernel<<<(B_ * P_ + 255) / 256, 256, 0, stream>>>(ws, out);
    }
}

// Round 9
// 82.509 us; speedup vs baseline: 1.8474x; 1.1965x over previous
//
#include <hip/hip_runtime.h>
#include <math.h>

#define B_ 64
#define N_ 200
#define P_ 400
#define T_ 1200
#define TPAD 1280
#define PPAD 512
#define STRIDE_ 25
#define EPS_ 1e-9f
#define KPAD 224
#define BSTRIDE 232   // LDS B row stride in shorts (464B row: 2-way max, free)

// ws layout (float offsets)
#define OFF_NPATT  0            // [N_][P_] f32 (fallback orth path)
#define OFF_NPB16  80000        // [P_][KPAD] bf16 row-major patterns
#define OFF_KEYVAL 124800       // [P_][4]
#define OFF_KEYIDX 126400       // [P_][4] int
#define OFF_PES    128000       // [B_][P_] (fallback only)
#define OFF_NORMB  153600       // [100] per-pat-block norm partials
#define OFF_ORTHB  153700       // [20] per-orth-block partials
#define OFF_NORM   OFF_NORMB    // fallback scalar slot
#define OFF_ORTH   OFF_ORTHB
#define OFF_NPBT   153728       // [28][PPAD][8] bf16 K-outer patterns (57344 f32)
#define OFF_XN     211072       // [B_][28][TPAD][8] bf16 K-outer frames (9175040 f32)
#define OFF_GPOOL  9386112      // [2][B_][48][400] okey uints (2457600)
#define WS_FAST_FLOATS (9386112 + 2457600)

#define PAT_BLKS 100
#define TN_BLKS  (20 * B_)      // 1280
#define ZG_BLKS  40
#define ZP_BLKS  2
#define PREP_BLKS (PAT_BLKS + TN_BLKS + ZG_BLKS + ZP_BLKS)

typedef float f4v __attribute__((ext_vector_type(4)));
typedef short s8v __attribute__((ext_vector_type(8)));

__device__ inline unsigned short f2bf(float f) {
    union { float f; unsigned u; } v; v.f = f;
    unsigned r = v.u + 0x7FFFu + ((v.u >> 16) & 1u);
    return (unsigned short)(r >> 16);
}
__device__ inline unsigned okey(float f) {
    unsigned u = __float_as_uint(f);
    return (u & 0x80000000u) ? ~u : (u | 0x80000000u);
}
__device__ inline float dekey(unsigned k) {
    unsigned u = (k & 0x80000000u) ? (k & 0x7fffffffu) : ~k;
    return __uint_as_float(u);
}

// ======= pat body (one wave, one pattern). Returns lane0's norm term. =======
__device__ float pat_body(const float* __restrict__ patterns, float* __restrict__ ws,
                          int p, int lane) {
    float v0 = patterns[p * N_ + lane];
    float v1 = patterns[p * N_ + lane + 64];
    float v2 = patterns[p * N_ + lane + 128];
    float v3 = (lane < 8) ? patterns[p * N_ + lane + 192] : 0.0f;

    float ss = v0 * v0 + v1 * v1 + v2 * v2 + v3 * v3;
    for (int off = 32; off; off >>= 1) ss += __shfl_down(ss, off);
    ss = __shfl(ss, 0);

    float rn = 1.0f / sqrtf(ss + EPS_);
    float s0 = v0 * rn, s1 = v1 * rn, s2 = v2 * rn, s3 = v3 * rn;

    float* npatT = ws + OFF_NPATT;
    npatT[(lane) * P_ + p] = s0;
    npatT[(lane + 64) * P_ + p] = s1;
    npatT[(lane + 128) * P_ + p] = s2;
    if (lane < 8) npatT[(lane + 192) * P_ + p] = s3;

    unsigned short* npb = (unsigned short*)(ws + OFF_NPB16);
    unsigned short b0 = f2bf(s0), b1 = f2bf(s1), b2 = f2bf(s2), b3 = f2bf(s3);
    npb[p * KPAD + lane] = b0;
    npb[p * KPAD + lane + 64] = b1;
    npb[p * KPAD + lane + 128] = b2;
    if (lane < 8) npb[p * KPAD + lane + 192] = b3;
    if (lane < 24) npb[p * KPAD + 200 + lane] = 0;

    unsigned short* npbT = (unsigned short*)(ws + OFF_NPBT);
    {
        int k0 = lane, k1 = lane + 64, k2 = lane + 128;
        npbT[(k0 >> 3) * (PPAD * 8) + p * 8 + (k0 & 7)] = b0;
        npbT[(k1 >> 3) * (PPAD * 8) + p * 8 + (k1 & 7)] = b1;
        npbT[(k2 >> 3) * (PPAD * 8) + p * 8 + (k2 & 7)] = b2;
        if (lane < 8) {
            int k3 = lane + 192;
            npbT[(k3 >> 3) * (PPAD * 8) + p * 8 + (k3 & 7)] = b3;
        }
        if (lane < 24) {
            int k4 = 200 + lane;
            npbT[(k4 >> 3) * (PPAD * 8) + p * 8 + (k4 & 7)] = 0;
        }
    }

    float a0 = fabsf(s0), a1 = fabsf(s1), a2 = fabsf(s2), a3 = fabsf(s3);

    int ch0 = -1, ch1 = -1, ch2 = -1;
    float cs0 = 0.f, cs1 = 0.f, cs2 = 0.f;

    for (int r = 0; r < 3; r++) {
        float bv = -1.0f;
        int bi = 1 << 30;
        {
            int n = lane;
            bool sk = (n == ch0) || (n == ch1) || (n == ch2);
            if (!sk && a0 > bv) { bv = a0; bi = n; }
        }
        {
            int n = lane + 64;
            bool sk = (n == ch0) || (n == ch1) || (n == ch2);
            if (!sk && (a1 > bv || (a1 == bv && n < bi))) { bv = a1; bi = n; }
        }
        {
            int n = lane + 128;
            bool sk = (n == ch0) || (n == ch1) || (n == ch2);
            if (!sk && (a2 > bv || (a2 == bv && n < bi))) { bv = a2; bi = n; }
        }
        if (lane < 8) {
            int n = lane + 192;
            bool sk = (n == ch0) || (n == ch1) || (n == ch2);
            if (!sk && (a3 > bv || (a3 == bv && n < bi))) { bv = a3; bi = n; }
        }
        for (int off = 32; off; off >>= 1) {
            float ov = __shfl_down(bv, off);
            int oi = __shfl_down(bi, off);
            if (ov > bv || (ov == bv && oi < bi)) { bv = ov; bi = oi; }
        }
        bi = __shfl(bi, 0);
        int slot = bi >> 6, src = bi & 63;
        float mine = (slot == 0) ? s0 : (slot == 1) ? s1 : (slot == 2) ? s2 : s3;
        float sval = __shfl(mine, src);
        if (r == 0) { ch0 = bi; cs0 = sval; }
        else if (r == 1) { ch1 = bi; cs1 = sval; }
        else { ch2 = bi; cs2 = sval; }
    }

    float d2 = 0.f;
    if (lane == 0) {
        float* keyval = ws + OFF_KEYVAL;
        int* keyidx = (int*)(ws + OFF_KEYIDX);
        keyval[p * 4 + 0] = cs0; keyval[p * 4 + 1] = cs1; keyval[p * 4 + 2] = cs2;
        keyidx[p * 4 + 0] = ch0; keyidx[p * 4 + 1] = ch1; keyidx[p * 4 + 2] = ch2;
        float lenp = sqrtf(ss) * rn;
        float lentopp = sqrtf(cs0 * cs0 + cs1 * cs1 + cs2 * cs2);
        float d = 1.0f - lentopp / lenp;
        d2 = d * d * (1.0f / (float)P_);
    }
    return d2;
}

// ======= prep: pat(0..99) + tnorm(100..1379) + zero gpool/npbT-pad ==========
__global__ __launch_bounds__(256) void prep_kernel(const float* __restrict__ x,
                                                   const float* __restrict__ patterns,
                                                   float* __restrict__ ws) {
    __shared__ float xt[64 * 210];          // f32 staging (53.8 KB)
    __shared__ float psums[256];
    __shared__ float rns[64];
    __shared__ float sh4[4];

    const int tid = threadIdx.x;

    if (blockIdx.x < PAT_BLKS) {
        int wv = tid >> 6, lane = tid & 63;
        int p = blockIdx.x * 4 + wv;
        float d2 = pat_body(patterns, ws, p, lane);
        if (lane == 0) sh4[wv] = d2;
        __syncthreads();
        if (tid == 0)
            ws[OFF_NORMB + blockIdx.x] = sh4[0] + sh4[1] + sh4[2] + sh4[3];
        return;
    }
    if (blockIdx.x >= PAT_BLKS + TN_BLKS) {
        int zb = blockIdx.x - PAT_BLKS - TN_BLKS;
        if (zb < ZG_BLKS) {
            // zero gpool: 614400 uint4 over 40 blocks
            uint4* gp4 = (uint4*)(ws + OFF_GPOOL);
            int base = zb * 15360 + tid;
#pragma unroll
            for (int i = 0; i < 60; ++i)
                gp4[base + i * 256] = make_uint4(0, 0, 0, 0);
        } else {
            // zero npbT pad rows [400..512) for all 28 segs: 12544 u32
            unsigned* p32 = (unsigned*)(ws + OFF_NPBT);
            int lb = zb - ZG_BLKS;     // 0..1
            for (int e = lb * 256 + tid; e < 12544; e += ZP_BLKS * 256) {
                int seg = e / 448, r32 = e % 448;
                p32[seg * 2048 + 1600 + r32] = 0u;
            }
        }
        return;
    }

    const int blk = blockIdx.x - PAT_BLKS;
    const int t = tid & 63, r = tid >> 6;
    const int b = blk / 20;
    const int t0 = (blk % 20) * 64;          // 0..1216 (pad t zeroed below)
    const bool valid = (t0 + t) < T_;

    float ss = 0.0f;
    if (valid) {
        const float* xp = x + (size_t)b * N_ * T_ + t0 + t;
#pragma unroll 5
        for (int i = 0; i < 50; ++i) {
            int n = r * 50 + i;
            float v = xp[(size_t)n * T_];
            ss += v * v;
            xt[t * 210 + n] = v;
        }
    }
    psums[tid] = ss;
    __syncthreads();
    if (tid < 64) {
        float s = psums[tid] + psums[tid + 64] + psums[tid + 128] + psums[tid + 192];
        rns[tid] = rsqrtf(s + EPS_);
    }
    __syncthreads();

    // K-outer write: xnT[b][seg][t][8], single bf16 rounding of x*rn
    unsigned short* xnT = (unsigned short*)(ws + OFF_XN);
#pragma unroll
    for (int j = 0; j < 7; ++j) {
        int idx = tid + 256 * j;            // 1792 = 28 segs x 64 t
        int seg = idx >> 6, tt = idx & 63;
        s8v ov = (s8v){0, 0, 0, 0, 0, 0, 0, 0};
        if (seg < 25 && (t0 + tt) < T_) {
            float rn = rns[tt];
            const float* src = &xt[tt * 210 + seg * 8];
            unsigned o[4];
#pragma unroll
            for (int i = 0; i < 4; ++i)
                o[i] = (unsigned)f2bf(src[2 * i] * rn) |
                       ((unsigned)f2bf(src[2 * i + 1] * rn) << 16);
            ov = (s8v){(short)(o[0] & 0xffff), (short)(o[0] >> 16),
                       (short)(o[1] & 0xffff), (short)(o[1] >> 16),
                       (short)(o[2] & 0xffff), (short)(o[2] >> 16),
                       (short)(o[3] & 0xffff), (short)(o[3] >> 16)};
        }
        *(s8v*)(xnT + (((size_t)b * 28 + seg) * TPAD + t0 + tt) * 8) = ov;
    }
}

// ======= work: gemm (nid 0..639, 5 mb-tiles each) + orth (640..659) =========
__global__ __launch_bounds__(256, 4) void work_kernel(float* __restrict__ ws,
                                                      unsigned* __restrict__ gpool) {
    __shared__ short ldsB[80 * BSTRIDE];       // 37.1 KB
    __shared__ unsigned pool[2 * 7 * 80];      // 4.5 KB

    const int tid = threadIdx.x;
    // bijective XCD swizzle over 660 blocks: q=82, r=4
    int orig = blockIdx.x;
    int xcd = orig & 7, rem = orig >> 3;
    int nid = (xcd < 4 ? xcd * 83 : 4 * 83 + (xcd - 4) * 82) + rem;

    const bool isOrth = (nid >= 640);
    int pb, mbg, b;
    if (isOrth) { int o = nid - 640; pb = o % 5; mbg = o / 5; b = 0; }
    else        { pb = nid % 5; mbg = (nid / 5) % 2; b = nid / 10; }

    const unsigned short* npb = (const unsigned short*)(ws + OFF_NPB16) + (size_t)(pb * 80) * KPAD;

    // stage B once: 80 rows x 224 shorts = 2240 16B units
#pragma unroll
    for (int j = 0; j < 9; ++j) {
        int idx = tid + 256 * j;
        if (idx < 2240) {
            int row = idx / 28, seg = idx % 28;
            *(s8v*)(&ldsB[row * BSTRIDE + seg * 8]) = *(const s8v*)(npb + (size_t)row * KPAD + seg * 8);
        }
    }
    for (int i = tid; i < 1120; i += 256) pool[i] = 0u;
    __syncthreads();

    const int wv = tid >> 6;
    const int lane = tid & 63;
    const int l15 = lane & 15, kg = lane >> 4;

    const int ROWS = isOrth ? PPAD : TPAD;
    const unsigned short* abase = isOrth
        ? (const unsigned short*)(ws + OFF_NPBT)
        : (const unsigned short*)(ws + OFF_XN) + (size_t)b * 28 * TPAD * 8;
    const int segstep = 4 * ROWS * 8;
    const int niter = isOrth ? 1 : 5;

    float orthpart = 0.f;

    for (int it = 0; it < niter; ++it) {
        const int mb = isOrth ? mbg : (mbg * 5 + it);
        const int row0 = mb * 128 + wv * 32 + l15;
        const unsigned short* ar0 = abase + ((size_t)kg * ROWS + row0) * 8;
        const unsigned short* ar1 = ar0 + 16 * 8;

        f4v acc[2][5];
#pragma unroll
        for (int mi = 0; mi < 2; ++mi)
#pragma unroll
            for (int ni = 0; ni < 5; ++ni) acc[mi][ni] = (f4v){0.f, 0.f, 0.f, 0.f};

        s8v A[4][2];
#pragma unroll
        for (int c = 0; c < 4; ++c) {
            A[c][0] = *(const s8v*)(ar0 + c * segstep);
            A[c][1] = *(const s8v*)(ar1 + c * segstep);
        }

#pragma unroll
        for (int c = 0; c < 7; ++c) {
            if (c + 4 < 7) {
                A[(c + 4) & 3][0] = *(const s8v*)(ar0 + (c + 4) * segstep);
                A[(c + 4) & 3][1] = *(const s8v*)(ar1 + (c + 4) * segstep);
            }
            s8v bf[5];
#pragma unroll
            for (int ni = 0; ni < 5; ++ni)
                bf[ni] = *(const s8v*)(&ldsB[(ni * 16 + l15) * BSTRIDE + c * 32 + kg * 8]);
#pragma unroll
            for (int ni = 0; ni < 5; ++ni) {
                acc[0][ni] = __builtin_amdgcn_mfma_f32_16x16x32_bf16(A[c & 3][0], bf[ni], acc[0][ni], 0, 0, 0);
                acc[1][ni] = __builtin_amdgcn_mfma_f32_16x16x32_bf16(A[c & 3][1], bf[ni], acc[1][ni], 0, 0, 0);
            }
        }

        if (isOrth) {
#pragma unroll
            for (int mi = 0; mi < 2; ++mi) {
                int rb = mb * 128 + wv * 32 + mi * 16 + kg * 4;
#pragma unroll
                for (int ni = 0; ni < 5; ++ni) {
                    int col = pb * 80 + ni * 16 + l15;
#pragma unroll
                    for (int jj = 0; jj < 4; ++jj) {
                        if (rb + jj == col) continue;
                        float t = (fabsf(acc[mi][ni][jj]) - 0.3f) * (1.0f / 0.70001f);
                        if (t > 0.0f) orthpart += t * t;
                    }
                }
            }
            break;
        }

        // okey pooling into LDS slots (single pass, pos+neg) — proven numerics
        const int wbase = (mb * 128) / 25;
#pragma unroll
        for (int mi = 0; mi < 2; ++mi) {
            int f0 = mb * 128 + wv * 32 + mi * 16 + kg * 4;
            int w0 = f0 / 25, w3 = (f0 + 3) / 25;
            int wsplit = w3 * 25;
#pragma unroll
            for (int ni = 0; ni < 5; ++ni) {
                int pc = ni * 16 + l15;
                float p0 = -1e30f, p1 = -1e30f, n0 = -1e30f, n1 = -1e30f;
#pragma unroll
                for (int jj = 0; jj < 4; ++jj) {
                    float v = acc[mi][ni][jj];
                    if (f0 + jj < wsplit) { p0 = fmaxf(p0, v); n0 = fmaxf(n0, -v); }
                    else                 { p1 = fmaxf(p1, v); n1 = fmaxf(n1, -v); }
                }
                atomicMax(&pool[(0 * 7 + (w3 - wbase)) * 80 + pc], okey(p1));
                atomicMax(&pool[(1 * 7 + (w3 - wbase)) * 80 + pc], okey(n1));
                if (w0 != w3) {
                    atomicMax(&pool[(0 * 7 + (w0 - wbase)) * 80 + pc], okey(p0));
                    atomicMax(&pool[(1 * 7 + (w0 - wbase)) * 80 + pc], okey(n0));
                }
            }
        }
        __syncthreads();
        // flush to global pool, re-zeroing in the same pass
        for (int e = tid; e < 1120; e += 256) {
            unsigned v = pool[e];
            pool[e] = 0u;
            if (!v) continue;
            int pass = e / 560, r2 = e % 560;
            int w = wbase + r2 / 80, p = r2 % 80;
            if (w < 48)
                atomicMax(&gpool[((size_t)(pass * B_ + b) * 48 + w) * 400 + pb * 80 + p], v);
        }
        __syncthreads();
    }

    if (isOrth) {
        for (int off = 32; off; off >>= 1) orthpart += __shfl_down(orthpart, off);
        __syncthreads();
        float* red = (float*)pool;
        if (lane == 0) red[wv] = orthpart;
        __syncthreads();
        if (tid == 0)
            ws[OFF_ORTHB + (nid - 640)] = (red[0] + red[1] + red[2] + red[3]) *
                                          (1.0f / ((float)P_ * (float)P_));
    }
}

// ======= finalize: PES from gpool + graphs scatter + scalars ================
__global__ __launch_bounds__(256) void graphs_kernel(const unsigned* __restrict__ gpool,
                                                     const int* __restrict__ length,
                                                     const float* __restrict__ ws,
                                                     float* __restrict__ out) {
    int idx = blockIdx.x * 256 + threadIdx.x;
    if (idx == 0) {
        float sn = 0.f;
        for (int i = 0; i < PAT_BLKS; ++i) sn += ws[OFF_NORMB + i];
        out[(size_t)B_ * N_ * N_] = sn;
        float so = 0.f;
        for (int i = 0; i < 20; ++i) so += ws[OFF_ORTHB + i];
        out[(size_t)B_ * N_ * N_ + 1] = so;
    }
    if (idx >= B_ * P_) return;
    int b = idx / P_;
    int p = idx - b * P_;

    const unsigned* gp0 = gpool + (size_t)b * 48 * 400 + p;
    const unsigned* gp1 = gpool + (size_t)(B_ + b) * 48 * 400 + p;
    float s = 0.f;
#pragma unroll
    for (int w = 0; w < 48; ++w)
        s += dekey(gp0[w * 400]) + dekey(gp1[w * 400]);
    float rsap = 1.0f / (float)(length[b] / STRIDE_);
    float e = s * 0.5f * rsap;

    const float* keyval = ws + OFF_KEYVAL;
    const int* keyidx = (const int*)(ws + OFF_KEYIDX);
    float va[3] = { keyval[p * 4 + 0], keyval[p * 4 + 1], keyval[p * 4 + 2] };
    int ia[3] = { keyidx[p * 4 + 0], keyidx[p * 4 + 1], keyidx[p * 4 + 2] };

    float* g = out + (size_t)b * N_ * N_;
#pragma unroll
    for (int a = 0; a < 3; a++) {
#pragma unroll
        for (int c = 0; c < 3; c++) {
            float scale = (ia[a] == ia[c]) ? 1.0f : 6.0f;
            atomicAdd(&g[ia[a] * N_ + ia[c]], va[a] * va[c] * e * scale);
        }
    }
}

// ---------------- fallback path (fp32, ws-size independent) -----------------
__global__ __launch_bounds__(256) void main_kernel(const float* __restrict__ x,
                                                   const int* __restrict__ length,
                                                   const float* __restrict__ ws,
                                                   float* __restrict__ pes) {
    __shared__ float xs[N_][STRIDE_ + 1];
    __shared__ float rnorm[STRIDE_];
    __shared__ float poolp[P_][5];
    __shared__ float pooln[P_][5];

    int w = blockIdx.x;
    int b = blockIdx.y;
    const float* xb = x + (size_t)b * N_ * T_ + (size_t)w * STRIDE_;

    for (int i = threadIdx.x; i < N_ * STRIDE_; i += 256) {
        int n = i / STRIDE_;
        int t = i - n * STRIDE_;
        xs[n][t] = xb[n * T_ + t];
    }
    __syncthreads();

    if (threadIdx.x < STRIDE_) {
        float ssf = 0.0f;
        for (int n = 0; n < N_; n++) { float vv = xs[n][threadIdx.x]; ssf += vv * vv; }
        rnorm[threadIdx.x] = 1.0f / sqrtf(ssf + EPS_);
    }
    __syncthreads();

    int pt = threadIdx.x % 50;
    int tt = threadIdx.x / 50;

    if (tt < 5) {
        float acc[8][5];
#pragma unroll
        for (int i = 0; i < 8; i++)
#pragma unroll
            for (int j = 0; j < 5; j++) acc[i][j] = 0.0f;

        const float4* np4 = (const float4*)(ws + OFF_NPATT);
        int pbq = pt * 2;
        for (int n = 0; n < N_; n++) {
            float4 q0 = np4[n * (P_ / 4) + pbq];
            float4 q1 = np4[n * (P_ / 4) + pbq + 1];
            float qa[8] = { q0.x, q0.y, q0.z, q0.w, q1.x, q1.y, q1.z, q1.w };
            float xv0 = xs[n][tt * 5 + 0];
            float xv1 = xs[n][tt * 5 + 1];
            float xv2 = xs[n][tt * 5 + 2];
            float xv3 = xs[n][tt * 5 + 3];
            float xv4 = xs[n][tt * 5 + 4];
#pragma unroll
            for (int i = 0; i < 8; i++) {
                acc[i][0] += qa[i] * xv0;
                acc[i][1] += qa[i] * xv1;
                acc[i][2] += qa[i] * xv2;
                acc[i][3] += qa[i] * xv3;
                acc[i][4] += qa[i] * xv4;
            }
        }
#pragma unroll
        for (int i = 0; i < 8; i++) {
            float pm = -1e30f, nm = -1e30f;
#pragma unroll
            for (int j = 0; j < 5; j++) {
                float s = acc[i][j] * rnorm[tt * 5 + j];
                pm = fmaxf(pm, s);
                nm = fmaxf(nm, -s);
            }
            poolp[pt * 8 + i][tt] = pm;
            pooln[pt * 8 + i][tt] = nm;
        }
    }
    __syncthreads();

    float rsap = 1.0f / (float)(length[b] / STRIDE_);
    for (int p = threadIdx.x; p < P_; p += 256) {
        float pm = poolp[p][0], nm = pooln[p][0];
#pragma unroll
        for (int q = 1; q < 5; q++) {
            pm = fmaxf(pm, poolp[p][q]);
            nm = fmaxf(nm, pooln[p][q]);
        }
        atomicAdd(&pes[b * P_ + p], (pm + nm) * 0.5f * rsap);
    }
}

__global__ __launch_bounds__(256) void fb_graphs_kernel(const float* __restrict__ ws,
                                                        float* __restrict__ out) {
    int idx = blockIdx.x * 256 + threadIdx.x;
    if (idx == 0) {
        out[(size_t)B_ * N_ * N_] = ws[OFF_NORM];
        out[(size_t)B_ * N_ * N_ + 1] = ws[OFF_ORTH];
    }
    if (idx >= B_ * P_) return;
    int b = idx / P_;
    int p = idx - b * P_;
    float e = ws[OFF_PES + b * P_ + p];
    const float* keyval = ws + OFF_KEYVAL;
    const int* keyidx = (const int*)(ws + OFF_KEYIDX);
    float va[3] = { keyval[p * 4 + 0], keyval[p * 4 + 1], keyval[p * 4 + 2] };
    int ia[3] = { keyidx[p * 4 + 0], keyidx[p * 4 + 1], keyidx[p * 4 + 2] };
    float* g = out + (size_t)b * N_ * N_;
#pragma unroll
    for (int a = 0; a < 3; a++)
#pragma unroll
        for (int c = 0; c < 3; c++) {
            float scale = (ia[a] == ia[c]) ? 1.0f : 6.0f;
            atomicAdd(&g[ia[a] * N_ + ia[c]], va[a] * va[c] * e * scale);
        }
}

__global__ __launch_bounds__(64) void pat_kernel(const float* __restrict__ patterns,
                                                 float* __restrict__ ws) {
    float d2 = pat_body(patterns, ws, blockIdx.x, threadIdx.x & 63);
    if (threadIdx.x == 0) atomicAdd(ws + OFF_NORM, d2);
}
__global__ __launch_bounds__(256) void orth_kernel(float* __restrict__ ws) {
    __shared__ float rowi[N_];
    __shared__ float red[256];
    const float* npatT = ws + OFF_NPATT;
    int i = blockIdx.x;
    for (int k = threadIdx.x; k < N_; k += 256) rowi[k] = npatT[k * P_ + i];
    __syncthreads();
    float partial = 0.0f;
    for (int j = threadIdx.x; j < P_; j += 256) {
        if (j == i) continue;
        float s = 0.0f;
        for (int k = 0; k < N_; k++) s += rowi[k] * npatT[k * P_ + j];
        float t = (fabsf(s) - 0.3f) * (1.0f / 0.70001f);
        if (t > 0.0f) partial += t * t;
    }
    red[threadIdx.x] = partial;
    __syncthreads();
    for (int sft = 128; sft; sft >>= 1) {
        if (threadIdx.x < sft) red[threadIdx.x] += red[threadIdx.x + sft];
        __syncthreads();
    }
    if (threadIdx.x == 0)
        atomicAdd(ws + OFF_ORTH, red[0] * (1.0f / ((float)P_ * (float)P_)));
}

extern "C" void kernel_launch(void* const* d_in, const int* in_sizes, int n_in,
                              void* d_out, int out_size, void* d_ws, size_t ws_size,
                              hipStream_t stream) {
    const float* x = (const float*)d_in[0];
    const float* patterns = (const float*)d_in[1];
    const int* length = (const int*)d_in[2];
    float* out = (float*)d_out;
    float* ws = (float*)d_ws;

    hipMemsetAsync(d_out, 0, (size_t)B_ * N_ * N_ * sizeof(float), stream);

    if (ws_size >= (size_t)WS_FAST_FLOATS * sizeof(float)) {
        unsigned* gpool = (unsigned*)(ws + OFF_GPOOL);
        prep_kernel<<<PREP_BLKS, 256, 0, stream>>>(x, patterns, ws);
        work_kernel<<<660, 256, 0, stream>>>(ws, gpool);
        graphs_kernel<<<(B_ * P_ + 255) / 256, 256, 0, stream>>>(gpool, length, ws, out);
    } else {
        hipMemsetAsync(ws + OFF_PES, 0, (size_t)(B_ * P_) * sizeof(float), stream);
        hipMemsetAsync(ws + OFF_NORM, 0, sizeof(float), stream);
        hipMemsetAsync(ws + OFF_ORTH, 0, sizeof(float), stream);
        pat_kernel<<<P_, 64, 0, stream>>>(patterns, ws);
        orth_kernel<<<P_, 256, 0, stream>>>(ws);
        main_kernel<<<dim3(T_ / STRIDE_, B_), 256, 0, stream>>>(x, length, ws, ws + OFF_PES);
        fb_graphs_kernel<<<(B_ * P_ + 255) / 256, 256, 0, stream>>>(ws, out);
    }
}

// Round 10
// 77.723 us; speedup vs baseline: 1.9611x; 1.0616x over previous
//
#include <hip/hip_runtime.h>
#include <math.h>

#define B_ 64
#define N_ 200
#define P_ 400
#define T_ 1200
#define TPAD 1280
#define PPAD 512
#define STRIDE_ 25
#define EPS_ 1e-9f
#define KPAD 224
#define BSTRIDE 232   // LDS B row stride in shorts (464B row: 2-way max, free)

// ws layout (float offsets)
#define OFF_NPATT  0            // [N_][P_] f32 (fallback orth path)
#define OFF_NPB16  80000        // [P_][KPAD] bf16 row-major patterns
#define OFF_KEYVAL 124800       // [P_][4]
#define OFF_KEYIDX 126400       // [P_][4] int
#define OFF_PES    128000       // [B_][P_] (fallback only)
#define OFF_NORMB  153600       // [100] per-pat-block norm partials
#define OFF_ORTHB  153700       // [20] per-orth-block partials
#define OFF_NORM   OFF_NORMB    // fallback scalar slot
#define OFF_ORTH   OFF_ORTHB
#define OFF_NPBT   153728       // [28][PPAD][8] bf16 K-outer patterns (57344 f32)
#define OFF_XN     211072       // [B_][28][TPAD][8] bf16 K-outer frames (9175040 f32)
#define OFF_GPOOL  9386112      // [2][B_][48][400] okey uints (2457600)
#define WS_FAST_FLOATS (9386112 + 2457600)

#define PAT_BLKS 100
#define TN_BLKS  (20 * B_)      // 1280
#define ZG_BLKS  40
#define ZP_BLKS  2
#define ZO_BLKS  160            // zero d_out (2.56M floats = 640000 uint4)
#define PREP_BLKS (PAT_BLKS + TN_BLKS + ZG_BLKS + ZP_BLKS + ZO_BLKS)

typedef float f4v __attribute__((ext_vector_type(4)));
typedef short s8v __attribute__((ext_vector_type(8)));

__device__ inline unsigned short f2bf(float f) {
    union { float f; unsigned u; } v; v.f = f;
    unsigned r = v.u + 0x7FFFu + ((v.u >> 16) & 1u);
    return (unsigned short)(r >> 16);
}
__device__ inline unsigned okey(float f) {
    unsigned u = __float_as_uint(f);
    return (u & 0x80000000u) ? ~u : (u | 0x80000000u);
}
__device__ inline float dekey(unsigned k) {
    unsigned u = (k & 0x80000000u) ? (k & 0x7fffffffu) : ~k;
    return __uint_as_float(u);
}

// ======= pat body (one wave, one pattern). Returns lane0's norm term. =======
__device__ float pat_body(const float* __restrict__ patterns, float* __restrict__ ws,
                          int p, int lane) {
    float v0 = patterns[p * N_ + lane];
    float v1 = patterns[p * N_ + lane + 64];
    float v2 = patterns[p * N_ + lane + 128];
    float v3 = (lane < 8) ? patterns[p * N_ + lane + 192] : 0.0f;

    float ss = v0 * v0 + v1 * v1 + v2 * v2 + v3 * v3;
    for (int off = 32; off; off >>= 1) ss += __shfl_down(ss, off);
    ss = __shfl(ss, 0);

    float rn = 1.0f / sqrtf(ss + EPS_);
    float s0 = v0 * rn, s1 = v1 * rn, s2 = v2 * rn, s3 = v3 * rn;

    float* npatT = ws + OFF_NPATT;
    npatT[(lane) * P_ + p] = s0;
    npatT[(lane + 64) * P_ + p] = s1;
    npatT[(lane + 128) * P_ + p] = s2;
    if (lane < 8) npatT[(lane + 192) * P_ + p] = s3;

    unsigned short* npb = (unsigned short*)(ws + OFF_NPB16);
    unsigned short b0 = f2bf(s0), b1 = f2bf(s1), b2 = f2bf(s2), b3 = f2bf(s3);
    npb[p * KPAD + lane] = b0;
    npb[p * KPAD + lane + 64] = b1;
    npb[p * KPAD + lane + 128] = b2;
    if (lane < 8) npb[p * KPAD + lane + 192] = b3;
    if (lane < 24) npb[p * KPAD + 200 + lane] = 0;

    unsigned short* npbT = (unsigned short*)(ws + OFF_NPBT);
    {
        int k0 = lane, k1 = lane + 64, k2 = lane + 128;
        npbT[(k0 >> 3) * (PPAD * 8) + p * 8 + (k0 & 7)] = b0;
        npbT[(k1 >> 3) * (PPAD * 8) + p * 8 + (k1 & 7)] = b1;
        npbT[(k2 >> 3) * (PPAD * 8) + p * 8 + (k2 & 7)] = b2;
        if (lane < 8) {
            int k3 = lane + 192;
            npbT[(k3 >> 3) * (PPAD * 8) + p * 8 + (k3 & 7)] = b3;
        }
        if (lane < 24) {
            int k4 = 200 + lane;
            npbT[(k4 >> 3) * (PPAD * 8) + p * 8 + (k4 & 7)] = 0;
        }
    }

    float a0 = fabsf(s0), a1 = fabsf(s1), a2 = fabsf(s2), a3 = fabsf(s3);

    int ch0 = -1, ch1 = -1, ch2 = -1;
    float cs0 = 0.f, cs1 = 0.f, cs2 = 0.f;

    for (int r = 0; r < 3; r++) {
        float bv = -1.0f;
        int bi = 1 << 30;
        {
            int n = lane;
            bool sk = (n == ch0) || (n == ch1) || (n == ch2);
            if (!sk && a0 > bv) { bv = a0; bi = n; }
        }
        {
            int n = lane + 64;
            bool sk = (n == ch0) || (n == ch1) || (n == ch2);
            if (!sk && (a1 > bv || (a1 == bv && n < bi))) { bv = a1; bi = n; }
        }
        {
            int n = lane + 128;
            bool sk = (n == ch0) || (n == ch1) || (n == ch2);
            if (!sk && (a2 > bv || (a2 == bv && n < bi))) { bv = a2; bi = n; }
        }
        if (lane < 8) {
            int n = lane + 192;
            bool sk = (n == ch0) || (n == ch1) || (n == ch2);
            if (!sk && (a3 > bv || (a3 == bv && n < bi))) { bv = a3; bi = n; }
        }
        for (int off = 32; off; off >>= 1) {
            float ov = __shfl_down(bv, off);
            int oi = __shfl_down(bi, off);
            if (ov > bv || (ov == bv && oi < bi)) { bv = ov; bi = oi; }
        }
        bi = __shfl(bi, 0);
        int slot = bi >> 6, src = bi & 63;
        float mine = (slot == 0) ? s0 : (slot == 1) ? s1 : (slot == 2) ? s2 : s3;
        float sval = __shfl(mine, src);
        if (r == 0) { ch0 = bi; cs0 = sval; }
        else if (r == 1) { ch1 = bi; cs1 = sval; }
        else { ch2 = bi; cs2 = sval; }
    }

    float d2 = 0.f;
    if (lane == 0) {
        float* keyval = ws + OFF_KEYVAL;
        int* keyidx = (int*)(ws + OFF_KEYIDX);
        keyval[p * 4 + 0] = cs0; keyval[p * 4 + 1] = cs1; keyval[p * 4 + 2] = cs2;
        keyidx[p * 4 + 0] = ch0; keyidx[p * 4 + 1] = ch1; keyidx[p * 4 + 2] = ch2;
        float lenp = sqrtf(ss) * rn;
        float lentopp = sqrtf(cs0 * cs0 + cs1 * cs1 + cs2 * cs2);
        float d = 1.0f - lentopp / lenp;
        d2 = d * d * (1.0f / (float)P_);
    }
    return d2;
}

// == prep: pat(0..99) + tnorm(100..1379) + zero gpool/npbT-pad + zero d_out ==
__global__ __launch_bounds__(256) void prep_kernel(const float* __restrict__ x,
                                                   const float* __restrict__ patterns,
                                                   float* __restrict__ ws,
                                                   float* __restrict__ out) {
    __shared__ float xt[64 * 210];          // f32 staging (53.8 KB)
    __shared__ float psums[256];
    __shared__ float rns[64];
    __shared__ float sh4[4];

    const int tid = threadIdx.x;

    if (blockIdx.x < PAT_BLKS) {
        int wv = tid >> 6, lane = tid & 63;
        int p = blockIdx.x * 4 + wv;
        float d2 = pat_body(patterns, ws, p, lane);
        if (lane == 0) sh4[wv] = d2;
        __syncthreads();
        if (tid == 0)
            ws[OFF_NORMB + blockIdx.x] = sh4[0] + sh4[1] + sh4[2] + sh4[3];
        return;
    }
    if (blockIdx.x >= PAT_BLKS + TN_BLKS) {
        int zb = blockIdx.x - PAT_BLKS - TN_BLKS;
        if (zb < ZG_BLKS) {
            // zero gpool: 614400 uint4 over 40 blocks
            uint4* gp4 = (uint4*)(ws + OFF_GPOOL);
            int base = zb * 15360 + tid;
#pragma unroll
            for (int i = 0; i < 60; ++i)
                gp4[base + i * 256] = make_uint4(0, 0, 0, 0);
        } else if (zb < ZG_BLKS + ZP_BLKS) {
            // zero npbT pad rows [400..512) for all 28 segs: 12544 u32
            unsigned* p32 = (unsigned*)(ws + OFF_NPBT);
            int lb = zb - ZG_BLKS;     // 0..1
            for (int e = lb * 256 + tid; e < 12544; e += ZP_BLKS * 256) {
                int seg = e / 448, r32 = e % 448;
                p32[seg * 2048 + 1600 + r32] = 0u;
            }
        } else {
            // zero d_out graphs region: 640000 uint4 (B_*N_*N_ floats)
            int zo = zb - ZG_BLKS - ZP_BLKS;   // 0..159
            uint4* o4 = (uint4*)out;
            for (int i = zo * 256 + tid; i < 640000; i += ZO_BLKS * 256)
                o4[i] = make_uint4(0, 0, 0, 0);
        }
        return;
    }

    const int blk = blockIdx.x - PAT_BLKS;
    const int t = tid & 63, r = tid >> 6;
    const int b = blk / 20;
    const int t0 = (blk % 20) * 64;          // 0..1216 (pad t zeroed below)
    const bool valid = (t0 + t) < T_;

    float ss = 0.0f;
    if (valid) {
        const float* xp = x + (size_t)b * N_ * T_ + t0 + t;
#pragma unroll 5
        for (int i = 0; i < 50; ++i) {
            int n = r * 50 + i;
            float v = xp[(size_t)n * T_];
            ss += v * v;
            xt[t * 210 + n] = v;
        }
    }
    psums[tid] = ss;
    __syncthreads();
    if (tid < 64) {
        float s = psums[tid] + psums[tid + 64] + psums[tid + 128] + psums[tid + 192];
        rns[tid] = rsqrtf(s + EPS_);
    }
    __syncthreads();

    // K-outer write: xnT[b][seg][t][8], single bf16 rounding of x*rn
    unsigned short* xnT = (unsigned short*)(ws + OFF_XN);
#pragma unroll
    for (int j = 0; j < 7; ++j) {
        int idx = tid + 256 * j;            // 1792 = 28 segs x 64 t
        int seg = idx >> 6, tt = idx & 63;
        s8v ov = (s8v){0, 0, 0, 0, 0, 0, 0, 0};
        if (seg < 25 && (t0 + tt) < T_) {
            float rn = rns[tt];
            const float* src = &xt[tt * 210 + seg * 8];
            unsigned o[4];
#pragma unroll
            for (int i = 0; i < 4; ++i)
                o[i] = (unsigned)f2bf(src[2 * i] * rn) |
                       ((unsigned)f2bf(src[2 * i + 1] * rn) << 16);
            ov = (s8v){(short)(o[0] & 0xffff), (short)(o[0] >> 16),
                       (short)(o[1] & 0xffff), (short)(o[1] >> 16),
                       (short)(o[2] & 0xffff), (short)(o[2] >> 16),
                       (short)(o[3] & 0xffff), (short)(o[3] >> 16)};
        }
        *(s8v*)(xnT + (((size_t)b * 28 + seg) * TPAD + t0 + tt) * 8) = ov;
    }
}

// ======= work: gemm (nid 0..639, 5 mb-tiles each) + orth (640..659) =========
__global__ __launch_bounds__(256, 4) void work_kernel(float* __restrict__ ws,
                                                      unsigned* __restrict__ gpool) {
    __shared__ short ldsB[80 * BSTRIDE];       // 37.1 KB
    __shared__ unsigned pool[2 * 7 * 80];      // 4.5 KB

    const int tid = threadIdx.x;
    // bijective XCD swizzle over 660 blocks: q=82, r=4
    int orig = blockIdx.x;
    int xcd = orig & 7, rem = orig >> 3;
    int nid = (xcd < 4 ? xcd * 83 : 4 * 83 + (xcd - 4) * 82) + rem;

    const bool isOrth = (nid >= 640);
    int pb, mbg, b;
    if (isOrth) { int o = nid - 640; pb = o % 5; mbg = o / 5; b = 0; }
    else        { pb = nid % 5; mbg = (nid / 5) % 2; b = nid / 10; }

    const unsigned short* npb = (const unsigned short*)(ws + OFF_NPB16) + (size_t)(pb * 80) * KPAD;

    // stage B once: 80 rows x 224 shorts = 2240 16B units
#pragma unroll
    for (int j = 0; j < 9; ++j) {
        int idx = tid + 256 * j;
        if (idx < 2240) {
            int row = idx / 28, seg = idx % 28;
            *(s8v*)(&ldsB[row * BSTRIDE + seg * 8]) = *(const s8v*)(npb + (size_t)row * KPAD + seg * 8);
        }
    }
    for (int i = tid; i < 1120; i += 256) pool[i] = 0u;
    __syncthreads();

    const int wv = tid >> 6;
    const int lane = tid & 63;
    const int l15 = lane & 15, kg = lane >> 4;

    const int ROWS = isOrth ? PPAD : TPAD;
    const unsigned short* abase = isOrth
        ? (const unsigned short*)(ws + OFF_NPBT)
        : (const unsigned short*)(ws + OFF_XN) + (size_t)b * 28 * TPAD * 8;
    const int segstep = 4 * ROWS * 8;
    const int niter = isOrth ? 1 : 5;

    float orthpart = 0.f;

    for (int it = 0; it < niter; ++it) {
        const int mb = isOrth ? mbg : (mbg * 5 + it);
        const int row0 = mb * 128 + wv * 32 + l15;
        const unsigned short* ar0 = abase + ((size_t)kg * ROWS + row0) * 8;
        const unsigned short* ar1 = ar0 + 16 * 8;

        f4v acc[2][5];
#pragma unroll
        for (int mi = 0; mi < 2; ++mi)
#pragma unroll
            for (int ni = 0; ni < 5; ++ni) acc[mi][ni] = (f4v){0.f, 0.f, 0.f, 0.f};

        s8v A[4][2];
#pragma unroll
        for (int c = 0; c < 4; ++c) {
            A[c][0] = *(const s8v*)(ar0 + c * segstep);
            A[c][1] = *(const s8v*)(ar1 + c * segstep);
        }

#pragma unroll
        for (int c = 0; c < 7; ++c) {
            if (c + 4 < 7) {
                A[(c + 4) & 3][0] = *(const s8v*)(ar0 + (c + 4) * segstep);
                A[(c + 4) & 3][1] = *(const s8v*)(ar1 + (c + 4) * segstep);
            }
            s8v bf[5];
#pragma unroll
            for (int ni = 0; ni < 5; ++ni)
                bf[ni] = *(const s8v*)(&ldsB[(ni * 16 + l15) * BSTRIDE + c * 32 + kg * 8]);
#pragma unroll
            for (int ni = 0; ni < 5; ++ni) {
                acc[0][ni] = __builtin_amdgcn_mfma_f32_16x16x32_bf16(A[c & 3][0], bf[ni], acc[0][ni], 0, 0, 0);
                acc[1][ni] = __builtin_amdgcn_mfma_f32_16x16x32_bf16(A[c & 3][1], bf[ni], acc[1][ni], 0, 0, 0);
            }
        }

        if (isOrth) {
#pragma unroll
            for (int mi = 0; mi < 2; ++mi) {
                int rb = mb * 128 + wv * 32 + mi * 16 + kg * 4;
#pragma unroll
                for (int ni = 0; ni < 5; ++ni) {
                    int col = pb * 80 + ni * 16 + l15;
#pragma unroll
                    for (int jj = 0; jj < 4; ++jj) {
                        if (rb + jj == col) continue;
                        float t = (fabsf(acc[mi][ni][jj]) - 0.3f) * (1.0f / 0.70001f);
                        if (t > 0.0f) orthpart += t * t;
                    }
                }
            }
            break;
        }

        // okey pooling into LDS slots (single pass, pos+neg) — proven numerics
        const int wbase = (mb * 128) / 25;
#pragma unroll
        for (int mi = 0; mi < 2; ++mi) {
            int f0 = mb * 128 + wv * 32 + mi * 16 + kg * 4;
            int w0 = f0 / 25, w3 = (f0 + 3) / 25;
            int wsplit = w3 * 25;
#pragma unroll
            for (int ni = 0; ni < 5; ++ni) {
                int pc = ni * 16 + l15;
                float p0 = -1e30f, p1 = -1e30f, n0 = -1e30f, n1 = -1e30f;
#pragma unroll
                for (int jj = 0; jj < 4; ++jj) {
                    float v = acc[mi][ni][jj];
                    if (f0 + jj < wsplit) { p0 = fmaxf(p0, v); n0 = fmaxf(n0, -v); }
                    else                 { p1 = fmaxf(p1, v); n1 = fmaxf(n1, -v); }
                }
                atomicMax(&pool[(0 * 7 + (w3 - wbase)) * 80 + pc], okey(p1));
                atomicMax(&pool[(1 * 7 + (w3 - wbase)) * 80 + pc], okey(n1));
                if (w0 != w3) {
                    atomicMax(&pool[(0 * 7 + (w0 - wbase)) * 80 + pc], okey(p0));
                    atomicMax(&pool[(1 * 7 + (w0 - wbase)) * 80 + pc], okey(n0));
                }
            }
        }
        __syncthreads();
        // flush to global pool, re-zeroing in the same pass
        for (int e = tid; e < 1120; e += 256) {
            unsigned v = pool[e];
            pool[e] = 0u;
            if (!v) continue;
            int pass = e / 560, r2 = e % 560;
            int w = wbase + r2 / 80, p = r2 % 80;
            if (w < 48)
                atomicMax(&gpool[((size_t)(pass * B_ + b) * 48 + w) * 400 + pb * 80 + p], v);
        }
        __syncthreads();
    }

    if (isOrth) {
        for (int off = 32; off; off >>= 1) orthpart += __shfl_down(orthpart, off);
        __syncthreads();
        float* red = (float*)pool;
        if (lane == 0) red[wv] = orthpart;
        __syncthreads();
        if (tid == 0)
            ws[OFF_ORTHB + (nid - 640)] = (red[0] + red[1] + red[2] + red[3]) *
                                          (1.0f / ((float)P_ * (float)P_));
    }
}

// ======= finalize: PES from gpool + graphs scatter + scalars ================
__global__ __launch_bounds__(256) void graphs_kernel(const unsigned* __restrict__ gpool,
                                                     const int* __restrict__ length,
                                                     const float* __restrict__ ws,
                                                     float* __restrict__ out) {
    int idx = blockIdx.x * 256 + threadIdx.x;
    if (idx == 0) {
        float sn = 0.f;
        for (int i = 0; i < PAT_BLKS; ++i) sn += ws[OFF_NORMB + i];
        out[(size_t)B_ * N_ * N_] = sn;
        float so = 0.f;
        for (int i = 0; i < 20; ++i) so += ws[OFF_ORTHB + i];
        out[(size_t)B_ * N_ * N_ + 1] = so;
    }
    if (idx >= B_ * P_) return;
    int b = idx / P_;
    int p = idx - b * P_;

    const unsigned* gp0 = gpool + (size_t)b * 48 * 400 + p;
    const unsigned* gp1 = gpool + (size_t)(B_ + b) * 48 * 400 + p;
    float s = 0.f;
#pragma unroll
    for (int w = 0; w < 48; ++w)
        s += dekey(gp0[w * 400]) + dekey(gp1[w * 400]);
    float rsap = 1.0f / (float)(length[b] / STRIDE_);
    float e = s * 0.5f * rsap;

    const float* keyval = ws + OFF_KEYVAL;
    const int* keyidx = (const int*)(ws + OFF_KEYIDX);
    float va[3] = { keyval[p * 4 + 0], keyval[p * 4 + 1], keyval[p * 4 + 2] };
    int ia[3] = { keyidx[p * 4 + 0], keyidx[p * 4 + 1], keyidx[p * 4 + 2] };

    float* g = out + (size_t)b * N_ * N_;
#pragma unroll
    for (int a = 0; a < 3; a++) {
#pragma unroll
        for (int c = 0; c < 3; c++) {
            float scale = (ia[a] == ia[c]) ? 1.0f : 6.0f;
            atomicAdd(&g[ia[a] * N_ + ia[c]], va[a] * va[c] * e * scale);
        }
    }
}

// ---------------- fallback path (fp32, ws-size independent) -----------------
__global__ __launch_bounds__(256) void main_kernel(const float* __restrict__ x,
                                                   const int* __restrict__ length,
                                                   const float* __restrict__ ws,
                                                   float* __restrict__ pes) {
    __shared__ float xs[N_][STRIDE_ + 1];
    __shared__ float rnorm[STRIDE_];
    __shared__ float poolp[P_][5];
    __shared__ float pooln[P_][5];

    int w = blockIdx.x;
    int b = blockIdx.y;
    const float* xb = x + (size_t)b * N_ * T_ + (size_t)w * STRIDE_;

    for (int i = threadIdx.x; i < N_ * STRIDE_; i += 256) {
        int n = i / STRIDE_;
        int t = i - n * STRIDE_;
        xs[n][t] = xb[n * T_ + t];
    }
    __syncthreads();

    if (threadIdx.x < STRIDE_) {
        float ssf = 0.0f;
        for (int n = 0; n < N_; n++) { float vv = xs[n][threadIdx.x]; ssf += vv * vv; }
        rnorm[threadIdx.x] = 1.0f / sqrtf(ssf + EPS_);
    }
    __syncthreads();

    int pt = threadIdx.x % 50;
    int tt = threadIdx.x / 50;

    if (tt < 5) {
        float acc[8][5];
#pragma unroll
        for (int i = 0; i < 8; i++)
#pragma unroll
            for (int j = 0; j < 5; j++) acc[i][j] = 0.0f;

        const float4* np4 = (const float4*)(ws + OFF_NPATT);
        int pbq = pt * 2;
        for (int n = 0; n < N_; n++) {
            float4 q0 = np4[n * (P_ / 4) + pbq];
            float4 q1 = np4[n * (P_ / 4) + pbq + 1];
            float qa[8] = { q0.x, q0.y, q0.z, q0.w, q1.x, q1.y, q1.z, q1.w };
            float xv0 = xs[n][tt * 5 + 0];
            float xv1 = xs[n][tt * 5 + 1];
            float xv2 = xs[n][tt * 5 + 2];
            float xv3 = xs[n][tt * 5 + 3];
            float xv4 = xs[n][tt * 5 + 4];
#pragma unroll
            for (int i = 0; i < 8; i++) {
                acc[i][0] += qa[i] * xv0;
                acc[i][1] += qa[i] * xv1;
                acc[i][2] += qa[i] * xv2;
                acc[i][3] += qa[i] * xv3;
                acc[i][4] += qa[i] * xv4;
            }
        }
#pragma unroll
        for (int i = 0; i < 8; i++) {
            float pm = -1e30f, nm = -1e30f;
#pragma unroll
            for (int j = 0; j < 5; j++) {
                float s = acc[i][j] * rnorm[tt * 5 + j];
                pm = fmaxf(pm, s);
                nm = fmaxf(nm, -s);
            }
            poolp[pt * 8 + i][tt] = pm;
            pooln[pt * 8 + i][tt] = nm;
        }
    }
    __syncthreads();

    float rsap = 1.0f / (float)(length[b] / STRIDE_);
    for (int p = threadIdx.x; p < P_; p += 256) {
        float pm = poolp[p][0], nm = pooln[p][0];
#pragma unroll
        for (int q = 1; q < 5; q++) {
            pm = fmaxf(pm, poolp[p][q]);
            nm = fmaxf(nm, pooln[p][q]);
        }
        atomicAdd(&pes[b * P_ + p], (pm + nm) * 0.5f * rsap);
    }
}

__global__ __launch_bounds__(256) void fb_graphs_kernel(const float* __restrict__ ws,
                                                        float* __restrict__ out) {
    int idx = blockIdx.x * 256 + threadIdx.x;
    if (idx == 0) {
        out[(size_t)B_ * N_ * N_] = ws[OFF_NORM];
        out[(size_t)B_ * N_ * N_ + 1] = ws[OFF_ORTH];
    }
    if (idx >= B_ * P_) return;
    int b = idx / P_;
    int p = idx - b * P_;
    float e = ws[OFF_PES + b * P_ + p];
    const float* keyval = ws + OFF_KEYVAL;
    const int* keyidx = (const int*)(ws + OFF_KEYIDX);
    float va[3] = { keyval[p * 4 + 0], keyval[p * 4 + 1], keyval[p * 4 + 2] };
    int ia[3] = { keyidx[p * 4 + 0], keyidx[p * 4 + 1], keyidx[p * 4 + 2] };
    float* g = out + (size_t)b * N_ * N_;
#pragma unroll
    for (int a = 0; a < 3; a++)
#pragma unroll
        for (int c = 0; c < 3; c++) {
            float scale = (ia[a] == ia[c]) ? 1.0f : 6.0f;
            atomicAdd(&g[ia[a] * N_ + ia[c]], va[a] * va[c] * e * scale);
        }
}

__global__ __launch_bounds__(64) void pat_kernel(const float* __restrict__ patterns,
                                                 float* __restrict__ ws) {
    float d2 = pat_body(patterns, ws, blockIdx.x, threadIdx.x & 63);
    if (threadIdx.x == 0) atomicAdd(ws + OFF_NORM, d2);
}
__global__ __launch_bounds__(256) void orth_kernel(float* __restrict__ ws) {
    __shared__ float rowi[N_];
    __shared__ float red[256];
    const float* npatT = ws + OFF_NPATT;
    int i = blockIdx.x;
    for (int k = threadIdx.x; k < N_; k += 256) rowi[k] = npatT[k * P_ + i];
    __syncthreads();
    float partial = 0.0f;
    for (int j = threadIdx.x; j < P_; j += 256) {
        if (j == i) continue;
        float s = 0.0f;
        for (int k = 0; k < N_; k++) s += rowi[k] * npatT[k * P_ + j];
        float t = (fabsf(s) - 0.3f) * (1.0f / 0.70001f);
        if (t > 0.0f) partial += t * t;
    }
    red[threadIdx.x] = partial;
    __syncthreads();
    for (int sft = 128; sft; sft >>= 1) {
        if (threadIdx.x < sft) red[threadIdx.x] += red[threadIdx.x + sft];
        __syncthreads();
    }
    if (threadIdx.x == 0)
        atomicAdd(ws + OFF_ORTH, red[0] * (1.0f / ((float)P_ * (float)P_)));
}

extern "C" void kernel_launch(void* const* d_in, const int* in_sizes, int n_in,
                              void* d_out, int out_size, void* d_ws, size_t ws_size,
                              hipStream_t stream) {
    const float* x = (const float*)d_in[0];
    const float* patterns = (const float*)d_in[1];
    const int* length = (const int*)d_in[2];
    float* out = (float*)d_out;
    float* ws = (float*)d_ws;

    if (ws_size >= (size_t)WS_FAST_FLOATS * sizeof(float)) {
        unsigned* gpool = (unsigned*)(ws + OFF_GPOOL);
        prep_kernel<<<PREP_BLKS, 256, 0, stream>>>(x, patterns, ws, out);
        work_kernel<<<660, 256, 0, stream>>>(ws, gpool);
        graphs_kernel<<<(B_ * P_ + 255) / 256, 256, 0, stream>>>(gpool, length, ws, out);
    } else {
        hipMemsetAsync(d_out, 0, (size_t)B_ * N_ * N_ * sizeof(float), stream);
        hipMemsetAsync(ws + OFF_PES, 0, (size_t)(B_ * P_) * sizeof(float), stream);
        hipMemsetAsync(ws + OFF_NORM, 0, sizeof(float), stream);
        hipMemsetAsync(ws + OFF_ORTH, 0, sizeof(float), stream);
        pat_kernel<<<P_, 64, 0, stream>>>(patterns, ws);
        orth_kernel<<<P_, 256, 0, stream>>>(ws);
        main_kernel<<<dim3(T_ / STRIDE_, B_), 256, 0, stream>>>(x, length, ws, ws + OFF_PES);
        fb_graphs_kernel<<<(B_ * P_ + 255) / 256, 256, 0, stream>>>(ws, out);
    }
}

// Round 11
// 75.531 us; speedup vs baseline: 2.0181x; 1.0290x over previous
//
#include <hip/hip_runtime.h>
#include <math.h>

#define B_ 64
#define N_ 200
#define P_ 400
#define T_ 1200
#define TPAD 1280
#define PPAD 512
#define STRIDE_ 25
#define EPS_ 1e-9f
#define KPAD 224
#define BSTRIDE 232   // LDS B row stride in shorts (464B row: 2-way max, free)

// ws layout (float offsets)
#define OFF_NPATT  0            // [N_][P_] f32 (fallback orth path)
#define OFF_NPB16  80000        // [P_][KPAD] bf16 row-major patterns
#define OFF_KEYVAL 124800       // [P_][4]
#define OFF_KEYIDX 126400       // [P_][4] int
#define OFF_PES    128000       // [B_][P_] (fallback only)
#define OFF_NORMB  153600       // [100] per-pat-block norm partials
#define OFF_ORTHB  153700       // [20] per-orth-block partials
#define OFF_NORM   OFF_NORMB    // fallback scalar slot
#define OFF_ORTH   OFF_ORTHB
#define OFF_NPBT   153728       // [28][PPAD][8] bf16 K-outer patterns (57344 f32)
#define OFF_XN     211072       // [B_][28][TPAD][8] bf16 K-outer frames (9175040 f32)
#define OFF_GPOOL  9386112      // [2][B_][48][400] okey uints (2457600)
#define WS_FAST_FLOATS (9386112 + 2457600)

// prep block roles: zeroers FIRST so they overlap the tnorm wave-front
#define ZO_BLKS  160            // zero d_out (2.56M floats = 640000 uint4)
#define ZG_BLKS  40             // zero gpool
#define ZP_BLKS  2              // zero npbT pad rows
#define PAT_BLKS 100
#define TN_BLKS  (20 * B_)      // 1280
#define Z_ALL    (ZO_BLKS + ZG_BLKS + ZP_BLKS)
#define PREP_BLKS (Z_ALL + PAT_BLKS + TN_BLKS)

typedef float f4v __attribute__((ext_vector_type(4)));
typedef short s8v __attribute__((ext_vector_type(8)));

__device__ inline unsigned short f2bf(float f) {
    union { float f; unsigned u; } v; v.f = f;
    unsigned r = v.u + 0x7FFFu + ((v.u >> 16) & 1u);
    return (unsigned short)(r >> 16);
}
__device__ inline unsigned okey(float f) {
    unsigned u = __float_as_uint(f);
    return (u & 0x80000000u) ? ~u : (u | 0x80000000u);
}
__device__ inline float dekey(unsigned k) {
    unsigned u = (k & 0x80000000u) ? (k & 0x7fffffffu) : ~k;
    return __uint_as_float(u);
}

// ======= pat body (one wave, one pattern). Returns lane0's norm term. =======
__device__ float pat_body(const float* __restrict__ patterns, float* __restrict__ ws,
                          int p, int lane) {
    float v0 = patterns[p * N_ + lane];
    float v1 = patterns[p * N_ + lane + 64];
    float v2 = patterns[p * N_ + lane + 128];
    float v3 = (lane < 8) ? patterns[p * N_ + lane + 192] : 0.0f;

    float ss = v0 * v0 + v1 * v1 + v2 * v2 + v3 * v3;
    for (int off = 32; off; off >>= 1) ss += __shfl_down(ss, off);
    ss = __shfl(ss, 0);

    float rn = 1.0f / sqrtf(ss + EPS_);
    float s0 = v0 * rn, s1 = v1 * rn, s2 = v2 * rn, s3 = v3 * rn;

    float* npatT = ws + OFF_NPATT;
    npatT[(lane) * P_ + p] = s0;
    npatT[(lane + 64) * P_ + p] = s1;
    npatT[(lane + 128) * P_ + p] = s2;
    if (lane < 8) npatT[(lane + 192) * P_ + p] = s3;

    unsigned short* npb = (unsigned short*)(ws + OFF_NPB16);
    unsigned short b0 = f2bf(s0), b1 = f2bf(s1), b2 = f2bf(s2), b3 = f2bf(s3);
    npb[p * KPAD + lane] = b0;
    npb[p * KPAD + lane + 64] = b1;
    npb[p * KPAD + lane + 128] = b2;
    if (lane < 8) npb[p * KPAD + lane + 192] = b3;
    if (lane < 24) npb[p * KPAD + 200 + lane] = 0;

    unsigned short* npbT = (unsigned short*)(ws + OFF_NPBT);
    {
        int k0 = lane, k1 = lane + 64, k2 = lane + 128;
        npbT[(k0 >> 3) * (PPAD * 8) + p * 8 + (k0 & 7)] = b0;
        npbT[(k1 >> 3) * (PPAD * 8) + p * 8 + (k1 & 7)] = b1;
        npbT[(k2 >> 3) * (PPAD * 8) + p * 8 + (k2 & 7)] = b2;
        if (lane < 8) {
            int k3 = lane + 192;
            npbT[(k3 >> 3) * (PPAD * 8) + p * 8 + (k3 & 7)] = b3;
        }
        if (lane < 24) {
            int k4 = 200 + lane;
            npbT[(k4 >> 3) * (PPAD * 8) + p * 8 + (k4 & 7)] = 0;
        }
    }

    float a0 = fabsf(s0), a1 = fabsf(s1), a2 = fabsf(s2), a3 = fabsf(s3);

    int ch0 = -1, ch1 = -1, ch2 = -1;
    float cs0 = 0.f, cs1 = 0.f, cs2 = 0.f;

    for (int r = 0; r < 3; r++) {
        float bv = -1.0f;
        int bi = 1 << 30;
        {
            int n = lane;
            bool sk = (n == ch0) || (n == ch1) || (n == ch2);
            if (!sk && a0 > bv) { bv = a0; bi = n; }
        }
        {
            int n = lane + 64;
            bool sk = (n == ch0) || (n == ch1) || (n == ch2);
            if (!sk && (a1 > bv || (a1 == bv && n < bi))) { bv = a1; bi = n; }
        }
        {
            int n = lane + 128;
            bool sk = (n == ch0) || (n == ch1) || (n == ch2);
            if (!sk && (a2 > bv || (a2 == bv && n < bi))) { bv = a2; bi = n; }
        }
        if (lane < 8) {
            int n = lane + 192;
            bool sk = (n == ch0) || (n == ch1) || (n == ch2);
            if (!sk && (a3 > bv || (a3 == bv && n < bi))) { bv = a3; bi = n; }
        }
        for (int off = 32; off; off >>= 1) {
            float ov = __shfl_down(bv, off);
            int oi = __shfl_down(bi, off);
            if (ov > bv || (ov == bv && oi < bi)) { bv = ov; bi = oi; }
        }
        bi = __shfl(bi, 0);
        int slot = bi >> 6, src = bi & 63;
        float mine = (slot == 0) ? s0 : (slot == 1) ? s1 : (slot == 2) ? s2 : s3;
        float sval = __shfl(mine, src);
        if (r == 0) { ch0 = bi; cs0 = sval; }
        else if (r == 1) { ch1 = bi; cs1 = sval; }
        else { ch2 = bi; cs2 = sval; }
    }

    float d2 = 0.f;
    if (lane == 0) {
        float* keyval = ws + OFF_KEYVAL;
        int* keyidx = (int*)(ws + OFF_KEYIDX);
        keyval[p * 4 + 0] = cs0; keyval[p * 4 + 1] = cs1; keyval[p * 4 + 2] = cs2;
        keyidx[p * 4 + 0] = ch0; keyidx[p * 4 + 1] = ch1; keyidx[p * 4 + 2] = ch2;
        float lenp = sqrtf(ss) * rn;
        float lentopp = sqrtf(cs0 * cs0 + cs1 * cs1 + cs2 * cs2);
        float d = 1.0f - lentopp / lenp;
        d2 = d * d * (1.0f / (float)P_);
    }
    return d2;
}

// == prep: zero d_out/gpool/pad (0..201) + pat (202..301) + tnorm (302..1581) ==
__global__ __launch_bounds__(256) void prep_kernel(const float* __restrict__ x,
                                                   const float* __restrict__ patterns,
                                                   float* __restrict__ ws,
                                                   float* __restrict__ out) {
    __shared__ unsigned short xt16[64 * 210];   // bf16 staging (26.9 KB)
    __shared__ float psums[256];
    __shared__ float rns[64];
    __shared__ float sh4[4];

    const int tid = threadIdx.x;

    if (blockIdx.x < Z_ALL) {
        int zb = blockIdx.x;
        if (zb < ZO_BLKS) {
            // zero d_out graphs region: 640000 uint4 (B_*N_*N_ floats)
            uint4* o4 = (uint4*)out;
            for (int i = zb * 256 + tid; i < 640000; i += ZO_BLKS * 256)
                o4[i] = make_uint4(0, 0, 0, 0);
        } else if (zb < ZO_BLKS + ZG_BLKS) {
            // zero gpool: 614400 uint4 over 40 blocks
            uint4* gp4 = (uint4*)(ws + OFF_GPOOL);
            int base = (zb - ZO_BLKS) * 15360 + tid;
#pragma unroll
            for (int i = 0; i < 60; ++i)
                gp4[base + i * 256] = make_uint4(0, 0, 0, 0);
        } else {
            // zero npbT pad rows [400..512) for all 28 segs: 12544 u32
            unsigned* p32 = (unsigned*)(ws + OFF_NPBT);
            int lb = zb - ZO_BLKS - ZG_BLKS;     // 0..1
            for (int e = lb * 256 + tid; e < 12544; e += ZP_BLKS * 256) {
                int seg = e / 448, r32 = e % 448;
                p32[seg * 2048 + 1600 + r32] = 0u;
            }
        }
        return;
    }

    if (blockIdx.x < Z_ALL + PAT_BLKS) {
        int pblk = blockIdx.x - Z_ALL;
        int wv = tid >> 6, lane = tid & 63;
        int p = pblk * 4 + wv;
        float d2 = pat_body(patterns, ws, p, lane);
        if (lane == 0) sh4[wv] = d2;
        __syncthreads();
        if (tid == 0)
            ws[OFF_NORMB + pblk] = sh4[0] + sh4[1] + sh4[2] + sh4[3];
        return;
    }

    const int blk = blockIdx.x - Z_ALL - PAT_BLKS;
    const int t = tid & 63, r = tid >> 6;
    const int b = blk / 20;
    const int t0 = (blk % 20) * 64;          // 0..1216 (pad t zeroed below)
    const bool valid = (t0 + t) < T_;

    float ss = 0.0f;
    if (valid) {
        const float* xp = x + (size_t)b * N_ * T_ + t0 + t;
#pragma unroll 5
        for (int i = 0; i < 50; ++i) {
            int n = r * 50 + i;
            float v = xp[(size_t)n * T_];
            ss += v * v;
            xt16[t * 210 + n] = f2bf(v);
        }
    }
    psums[tid] = ss;
    __syncthreads();
    if (tid < 64) {
        float s = psums[tid] + psums[tid + 64] + psums[tid + 128] + psums[tid + 192];
        rns[tid] = rsqrtf(s + EPS_);
    }
    __syncthreads();

    // K-outer write: xnT[b][seg][t][8]; pad -> zeros
    unsigned short* xnT = (unsigned short*)(ws + OFF_XN);
#pragma unroll
    for (int j = 0; j < 7; ++j) {
        int idx = tid + 256 * j;            // 1792 = 28 segs x 64 t
        int seg = idx >> 6, tt = idx & 63;
        s8v ov = (s8v){0, 0, 0, 0, 0, 0, 0, 0};
        if (seg < 25 && (t0 + tt) < T_) {
            float rn = rns[tt];
            const unsigned* src = (const unsigned*)&xt16[tt * 210 + seg * 8];
            unsigned o[4];
#pragma unroll
            for (int i = 0; i < 4; ++i) {
                unsigned u = src[i];
                float lo = __uint_as_float(u << 16) * rn;
                float hi = __uint_as_float(u & 0xffff0000u) * rn;
                o[i] = (unsigned)f2bf(lo) | ((unsigned)f2bf(hi) << 16);
            }
            ov = (s8v){(short)(o[0] & 0xffff), (short)(o[0] >> 16),
                       (short)(o[1] & 0xffff), (short)(o[1] >> 16),
                       (short)(o[2] & 0xffff), (short)(o[2] >> 16),
                       (short)(o[3] & 0xffff), (short)(o[3] >> 16)};
        }
        *(s8v*)(xnT + (((size_t)b * 28 + seg) * TPAD + t0 + tt) * 8) = ov;
    }
}

// ======= work: gemm (nid 0..639, 5 mb-tiles each) + orth (640..659) =========
__global__ __launch_bounds__(256, 4) void work_kernel(float* __restrict__ ws,
                                                      unsigned* __restrict__ gpool) {
    __shared__ short ldsB[80 * BSTRIDE];       // 37.1 KB
    __shared__ unsigned pool[2 * 7 * 80];      // 4.5 KB

    const int tid = threadIdx.x;
    // bijective XCD swizzle over 660 blocks: q=82, r=4
    int orig = blockIdx.x;
    int xcd = orig & 7, rem = orig >> 3;
    int nid = (xcd < 4 ? xcd * 83 : 4 * 83 + (xcd - 4) * 82) + rem;

    const bool isOrth = (nid >= 640);
    int pb, mbg, b;
    if (isOrth) { int o = nid - 640; pb = o % 5; mbg = o / 5; b = 0; }
    else        { pb = nid % 5; mbg = (nid / 5) % 2; b = nid / 10; }

    const unsigned short* npb = (const unsigned short*)(ws + OFF_NPB16) + (size_t)(pb * 80) * KPAD;

    // stage B once: 80 rows x 224 shorts = 2240 16B units
#pragma unroll
    for (int j = 0; j < 9; ++j) {
        int idx = tid + 256 * j;
        if (idx < 2240) {
            int row = idx / 28, seg = idx % 28;
            *(s8v*)(&ldsB[row * BSTRIDE + seg * 8]) = *(const s8v*)(npb + (size_t)row * KPAD + seg * 8);
        }
    }
    for (int i = tid; i < 1120; i += 256) pool[i] = 0u;
    __syncthreads();

    const int wv = tid >> 6;
    const int lane = tid & 63;
    const int l15 = lane & 15, kg = lane >> 4;

    const int ROWS = isOrth ? PPAD : TPAD;
    const unsigned short* abase = isOrth
        ? (const unsigned short*)(ws + OFF_NPBT)
        : (const unsigned short*)(ws + OFF_XN) + (size_t)b * 28 * TPAD * 8;
    const int segstep = 4 * ROWS * 8;
    const int niter = isOrth ? 1 : 5;

    float orthpart = 0.f;

    for (int it = 0; it < niter; ++it) {
        const int mb = isOrth ? mbg : (mbg * 5 + it);
        const int row0 = mb * 128 + wv * 32 + l15;
        const unsigned short* ar0 = abase + ((size_t)kg * ROWS + row0) * 8;
        const unsigned short* ar1 = ar0 + 16 * 8;

        f4v acc[2][5];
#pragma unroll
        for (int mi = 0; mi < 2; ++mi)
#pragma unroll
            for (int ni = 0; ni < 5; ++ni) acc[mi][ni] = (f4v){0.f, 0.f, 0.f, 0.f};

        s8v A[4][2];
#pragma unroll
        for (int c = 0; c < 4; ++c) {
            A[c][0] = *(const s8v*)(ar0 + c * segstep);
            A[c][1] = *(const s8v*)(ar1 + c * segstep);
        }

#pragma unroll
        for (int c = 0; c < 7; ++c) {
            if (c + 4 < 7) {
                A[(c + 4) & 3][0] = *(const s8v*)(ar0 + (c + 4) * segstep);
                A[(c + 4) & 3][1] = *(const s8v*)(ar1 + (c + 4) * segstep);
            }
            s8v bf[5];
#pragma unroll
            for (int ni = 0; ni < 5; ++ni)
                bf[ni] = *(const s8v*)(&ldsB[(ni * 16 + l15) * BSTRIDE + c * 32 + kg * 8]);
#pragma unroll
            for (int ni = 0; ni < 5; ++ni) {
                acc[0][ni] = __builtin_amdgcn_mfma_f32_16x16x32_bf16(A[c & 3][0], bf[ni], acc[0][ni], 0, 0, 0);
                acc[1][ni] = __builtin_amdgcn_mfma_f32_16x16x32_bf16(A[c & 3][1], bf[ni], acc[1][ni], 0, 0, 0);
            }
        }

        if (isOrth) {
#pragma unroll
            for (int mi = 0; mi < 2; ++mi) {
                int rb = mb * 128 + wv * 32 + mi * 16 + kg * 4;
#pragma unroll
                for (int ni = 0; ni < 5; ++ni) {
                    int col = pb * 80 + ni * 16 + l15;
#pragma unroll
                    for (int jj = 0; jj < 4; ++jj) {
                        if (rb + jj == col) continue;
                        float t = (fabsf(acc[mi][ni][jj]) - 0.3f) * (1.0f / 0.70001f);
                        if (t > 0.0f) orthpart += t * t;
                    }
                }
            }
            break;
        }

        // okey pooling into LDS slots (single pass, pos+neg) — proven numerics
        const int wbase = (mb * 128) / 25;
#pragma unroll
        for (int mi = 0; mi < 2; ++mi) {
            int f0 = mb * 128 + wv * 32 + mi * 16 + kg * 4;
            int w0 = f0 / 25, w3 = (f0 + 3) / 25;
            int wsplit = w3 * 25;
#pragma unroll
            for (int ni = 0; ni < 5; ++ni) {
                int pc = ni * 16 + l15;
                float p0 = -1e30f, p1 = -1e30f, n0 = -1e30f, n1 = -1e30f;
#pragma unroll
                for (int jj = 0; jj < 4; ++jj) {
                    float v = acc[mi][ni][jj];
                    if (f0 + jj < wsplit) { p0 = fmaxf(p0, v); n0 = fmaxf(n0, -v); }
                    else                 { p1 = fmaxf(p1, v); n1 = fmaxf(n1, -v); }
                }
                atomicMax(&pool[(0 * 7 + (w3 - wbase)) * 80 + pc], okey(p1));
                atomicMax(&pool[(1 * 7 + (w3 - wbase)) * 80 + pc], okey(n1));
                if (w0 != w3) {
                    atomicMax(&pool[(0 * 7 + (w0 - wbase)) * 80 + pc], okey(p0));
                    atomicMax(&pool[(1 * 7 + (w0 - wbase)) * 80 + pc], okey(n0));
                }
            }
        }
        __syncthreads();
        // flush to global pool, re-zeroing in the same pass
        for (int e = tid; e < 1120; e += 256) {
            unsigned v = pool[e];
            pool[e] = 0u;
            if (!v) continue;
            int pass = e / 560, r2 = e % 560;
            int w = wbase + r2 / 80, p = r2 % 80;
            if (w < 48)
                atomicMax(&gpool[((size_t)(pass * B_ + b) * 48 + w) * 400 + pb * 80 + p], v);
        }
        __syncthreads();
    }

    if (isOrth) {
        for (int off = 32; off; off >>= 1) orthpart += __shfl_down(orthpart, off);
        __syncthreads();
        float* red = (float*)pool;
        if (lane == 0) red[wv] = orthpart;
        __syncthreads();
        if (tid == 0)
            ws[OFF_ORTHB + (nid - 640)] = (red[0] + red[1] + red[2] + red[3]) *
                                          (1.0f / ((float)P_ * (float)P_));
    }
}

// ======= finalize: PES from gpool + graphs scatter + scalars ================
__global__ __launch_bounds__(256) void graphs_kernel(const unsigned* __restrict__ gpool,
                                                     const int* __restrict__ length,
                                                     const float* __restrict__ ws,
                                                     float* __restrict__ out) {
    int idx = blockIdx.x * 256 + threadIdx.x;
    if (idx == 0) {
        float sn = 0.f;
        for (int i = 0; i < PAT_BLKS; ++i) sn += ws[OFF_NORMB + i];
        out[(size_t)B_ * N_ * N_] = sn;
        float so = 0.f;
        for (int i = 0; i < 20; ++i) so += ws[OFF_ORTHB + i];
        out[(size_t)B_ * N_ * N_ + 1] = so;
    }
    if (idx >= B_ * P_) return;
    int b = idx / P_;
    int p = idx - b * P_;

    const unsigned* gp0 = gpool + (size_t)b * 48 * 400 + p;
    const unsigned* gp1 = gpool + (size_t)(B_ + b) * 48 * 400 + p;
    float s = 0.f;
#pragma unroll
    for (int w = 0; w < 48; ++w)
        s += dekey(gp0[w * 400]) + dekey(gp1[w * 400]);
    float rsap = 1.0f / (float)(length[b] / STRIDE_);
    float e = s * 0.5f * rsap;

    const float* keyval = ws + OFF_KEYVAL;
    const int* keyidx = (const int*)(ws + OFF_KEYIDX);
    float va[3] = { keyval[p * 4 + 0], keyval[p * 4 + 1], keyval[p * 4 + 2] };
    int ia[3] = { keyidx[p * 4 + 0], keyidx[p * 4 + 1], keyidx[p * 4 + 2] };

    float* g = out + (size_t)b * N_ * N_;
#pragma unroll
    for (int a = 0; a < 3; a++) {
#pragma unroll
        for (int c = 0; c < 3; c++) {
            float scale = (ia[a] == ia[c]) ? 1.0f : 6.0f;
            atomicAdd(&g[ia[a] * N_ + ia[c]], va[a] * va[c] * e * scale);
        }
    }
}

// ---------------- fallback path (fp32, ws-size independent) -----------------
__global__ __launch_bounds__(256) void main_kernel(const float* __restrict__ x,
                                                   const int* __restrict__ length,
                                                   const float* __restrict__ ws,
                                                   float* __restrict__ pes) {
    __shared__ float xs[N_][STRIDE_ + 1];
    __shared__ float rnorm[STRIDE_];
    __shared__ float poolp[P_][5];
    __shared__ float pooln[P_][5];

    int w = blockIdx.x;
    int b = blockIdx.y;
    const float* xb = x + (size_t)b * N_ * T_ + (size_t)w * STRIDE_;

    for (int i = threadIdx.x; i < N_ * STRIDE_; i += 256) {
        int n = i / STRIDE_;
        int t = i - n * STRIDE_;
        xs[n][t] = xb[n * T_ + t];
    }
    __syncthreads();

    if (threadIdx.x < STRIDE_) {
        float ssf = 0.0f;
        for (int n = 0; n < N_; n++) { float vv = xs[n][threadIdx.x]; ssf += vv * vv; }
        rnorm[threadIdx.x] = 1.0f / sqrtf(ssf + EPS_);
    }
    __syncthreads();

    int pt = threadIdx.x % 50;
    int tt = threadIdx.x / 50;

    if (tt < 5) {
        float acc[8][5];
#pragma unroll
        for (int i = 0; i < 8; i++)
#pragma unroll
            for (int j = 0; j < 5; j++) acc[i][j] = 0.0f;

        const float4* np4 = (const float4*)(ws + OFF_NPATT);
        int pbq = pt * 2;
        for (int n = 0; n < N_; n++) {
            float4 q0 = np4[n * (P_ / 4) + pbq];
            float4 q1 = np4[n * (P_ / 4) + pbq + 1];
            float qa[8] = { q0.x, q0.y, q0.z, q0.w, q1.x, q1.y, q1.z, q1.w };
            float xv0 = xs[n][tt * 5 + 0];
            float xv1 = xs[n][tt * 5 + 1];
            float xv2 = xs[n][tt * 5 + 2];
            float xv3 = xs[n][tt * 5 + 3];
            float xv4 = xs[n][tt * 5 + 4];
#pragma unroll
            for (int i = 0; i < 8; i++) {
                acc[i][0] += qa[i] * xv0;
                acc[i][1] += qa[i] * xv1;
                acc[i][2] += qa[i] * xv2;
                acc[i][3] += qa[i] * xv3;
                acc[i][4] += qa[i] * xv4;
            }
        }
#pragma unroll
        for (int i = 0; i < 8; i++) {
            float pm = -1e30f, nm = -1e30f;
#pragma unroll
            for (int j = 0; j < 5; j++) {
                float s = acc[i][j] * rnorm[tt * 5 + j];
                pm = fmaxf(pm, s);
                nm = fmaxf(nm, -s);
            }
            poolp[pt * 8 + i][tt] = pm;
            pooln[pt * 8 + i][tt] = nm;
        }
    }
    __syncthreads();

    float rsap = 1.0f / (float)(length[b] / STRIDE_);
    for (int p = threadIdx.x; p < P_; p += 256) {
        float pm = poolp[p][0], nm = pooln[p][0];
#pragma unroll
        for (int q = 1; q < 5; q++) {
            pm = fmaxf(pm, poolp[p][q]);
            nm = fmaxf(nm, pooln[p][q]);
        }
        atomicAdd(&pes[b * P_ + p], (pm + nm) * 0.5f * rsap);
    }
}

__global__ __launch_bounds__(256) void fb_graphs_kernel(const float* __restrict__ ws,
                                                        float* __restrict__ out) {
    int idx = blockIdx.x * 256 + threadIdx.x;
    if (idx == 0) {
        out[(size_t)B_ * N_ * N_] = ws[OFF_NORM];
        out[(size_t)B_ * N_ * N_ + 1] = ws[OFF_ORTH];
    }
    if (idx >= B_ * P_) return;
    int b = idx / P_;
    int p = idx - b * P_;
    float e = ws[OFF_PES + b * P_ + p];
    const float* keyval = ws + OFF_KEYVAL;
    const int* keyidx = (const int*)(ws + OFF_KEYIDX);
    float va[3] = { keyval[p * 4 + 0], keyval[p * 4 + 1], keyval[p * 4 + 2] };
    int ia[3] = { keyidx[p * 4 + 0], keyidx[p * 4 + 1], keyidx[p * 4 + 2] };
    float* g = out + (size_t)b * N_ * N_;
#pragma unroll
    for (int a = 0; a < 3; a++)
#pragma unroll
        for (int c = 0; c < 3; c++) {
            float scale = (ia[a] == ia[c]) ? 1.0f : 6.0f;
            atomicAdd(&g[ia[a] * N_ + ia[c]], va[a] * va[c] * e * scale);
        }
}

__global__ __launch_bounds__(64) void pat_kernel(const float* __restrict__ patterns,
                                                 float* __restrict__ ws) {
    float d2 = pat_body(patterns, ws, blockIdx.x, threadIdx.x & 63);
    if (threadIdx.x == 0) atomicAdd(ws + OFF_NORM, d2);
}
__global__ __launch_bounds__(256) void orth_kernel(float* __restrict__ ws) {
    __shared__ float rowi[N_];
    __shared__ float red[256];
    const float* npatT = ws + OFF_NPATT;
    int i = blockIdx.x;
    for (int k = threadIdx.x; k < N_; k += 256) rowi[k] = npatT[k * P_ + i];
    __syncthreads();
    float partial = 0.0f;
    for (int j = threadIdx.x; j < P_; j += 256) {
        if (j == i) continue;
        float s = 0.0f;
        for (int k = 0; k < N_; k++) s += rowi[k] * npatT[k * P_ + j];
        float t = (fabsf(s) - 0.3f) * (1.0f / 0.70001f);
        if (t > 0.0f) partial += t * t;
    }
    red[threadIdx.x] = partial;
    __syncthreads();
    for (int sft = 128; sft; sft >>= 1) {
        if (threadIdx.x < sft) red[threadIdx.x] += red[threadIdx.x + sft];
        __syncthreads();
    }
    if (threadIdx.x == 0)
        atomicAdd(ws + OFF_ORTH, red[0] * (1.0f / ((float)P_ * (float)P_)));
}

extern "C" void kernel_launch(void* const* d_in, const int* in_sizes, int n_in,
                              void* d_out, int out_size, void* d_ws, size_t ws_size,
                              hipStream_t stream) {
    const float* x = (const float*)d_in[0];
    const float* patterns = (const float*)d_in[1];
    const int* length = (const int*)d_in[2];
    float* out = (float*)d_out;
    float* ws = (float*)d_ws;

    if (ws_size >= (size_t)WS_FAST_FLOATS * sizeof(float)) {
        unsigned* gpool = (unsigned*)(ws + OFF_GPOOL);
        prep_kernel<<<PREP_BLKS, 256, 0, stream>>>(x, patterns, ws, out);
        work_kernel<<<660, 256, 0, stream>>>(ws, gpool);
        graphs_kernel<<<(B_ * P_ + 255) / 256, 256, 0, stream>>>(gpool, length, ws, out);
    } else {
        hipMemsetAsync(d_out, 0, (size_t)B_ * N_ * N_ * sizeof(float), stream);
        hipMemsetAsync(ws + OFF_PES, 0, (size_t)(B_ * P_) * sizeof(float), stream);
        hipMemsetAsync(ws + OFF_NORM, 0, sizeof(float), stream);
        hipMemsetAsync(ws + OFF_ORTH, 0, sizeof(float), stream);
        pat_kernel<<<P_, 64, 0, stream>>>(patterns, ws);
        orth_kernel<<<P_, 256, 0, stream>>>(ws);
        main_kernel<<<dim3(T_ / STRIDE_, B_), 256, 0, stream>>>(x, length, ws, ws + OFF_PES);
        fb_graphs_kernel<<<(B_ * P_ + 255) / 256, 256, 0, stream>>>(ws, out);
    }
}

// Round 12
// 68.176 us; speedup vs baseline: 2.2358x; 1.1079x over previous
//
#include <hip/hip_runtime.h>
#include <math.h>

#define B_ 64
#define N_ 200
#define P_ 400
#define T_ 1200
#define TPAD 1280
#define PPAD 512
#define STRIDE_ 25
#define EPS_ 1e-9f
#define KPAD 224
#define BSTRIDE 232   // LDS B row stride in shorts (464B row: 2-way max, free)

// ws layout (float offsets)
#define OFF_NPATT  0            // [N_][P_] f32 (fallback orth path)
#define OFF_NPB16  80000        // [P_][KPAD] bf16 row-major patterns
#define OFF_KEYVAL 124800       // [P_][4]
#define OFF_KEYIDX 126400       // [P_][4] int
#define OFF_PES    128000       // [B_][P_] PES (written by pes_kernel, no zero needed)
#define OFF_NORMB  153600       // [100] per-pat-block norm partials
#define OFF_ORTHB  153700       // [20] per-orth-block partials
#define OFF_NORM   OFF_NORMB    // fallback scalar slot
#define OFF_ORTH   OFF_ORTHB
#define OFF_NPBT   153728       // [28][PPAD][8] bf16 K-outer patterns (57344 f32)
#define OFF_XN     211072       // [B_][28][TPAD][8] bf16 K-outer frames (9175040 f32)
#define OFF_GPOOL  9386112      // [2][B_][48][400] okey uints (2457600)
#define WS_FAST_FLOATS (9386112 + 2457600)

// prep block roles (no d_out zeroing anymore)
#define ZG_BLKS  40             // zero gpool
#define ZP_BLKS  2              // zero npbT pad rows
#define PAT_BLKS 100
#define TN_BLKS  (20 * B_)      // 1280
#define Z_ALL    (ZG_BLKS + ZP_BLKS)
#define PREP_BLKS (Z_ALL + PAT_BLKS + TN_BLKS)

typedef float f4v __attribute__((ext_vector_type(4)));
typedef short s8v __attribute__((ext_vector_type(8)));

__device__ inline unsigned short f2bf(float f) {
    union { float f; unsigned u; } v; v.f = f;
    unsigned r = v.u + 0x7FFFu + ((v.u >> 16) & 1u);
    return (unsigned short)(r >> 16);
}
__device__ inline unsigned okey(float f) {
    unsigned u = __float_as_uint(f);
    return (u & 0x80000000u) ? ~u : (u | 0x80000000u);
}
__device__ inline float dekey(unsigned k) {
    unsigned u = (k & 0x80000000u) ? (k & 0x7fffffffu) : ~k;
    return __uint_as_float(u);
}

// ======= pat body (one wave, one pattern). Returns lane0's norm term. =======
__device__ float pat_body(const float* __restrict__ patterns, float* __restrict__ ws,
                          int p, int lane) {
    float v0 = patterns[p * N_ + lane];
    float v1 = patterns[p * N_ + lane + 64];
    float v2 = patterns[p * N_ + lane + 128];
    float v3 = (lane < 8) ? patterns[p * N_ + lane + 192] : 0.0f;

    float ss = v0 * v0 + v1 * v1 + v2 * v2 + v3 * v3;
    for (int off = 32; off; off >>= 1) ss += __shfl_down(ss, off);
    ss = __shfl(ss, 0);

    float rn = 1.0f / sqrtf(ss + EPS_);
    float s0 = v0 * rn, s1 = v1 * rn, s2 = v2 * rn, s3 = v3 * rn;

    float* npatT = ws + OFF_NPATT;
    npatT[(lane) * P_ + p] = s0;
    npatT[(lane + 64) * P_ + p] = s1;
    npatT[(lane + 128) * P_ + p] = s2;
    if (lane < 8) npatT[(lane + 192) * P_ + p] = s3;

    unsigned short* npb = (unsigned short*)(ws + OFF_NPB16);
    unsigned short b0 = f2bf(s0), b1 = f2bf(s1), b2 = f2bf(s2), b3 = f2bf(s3);
    npb[p * KPAD + lane] = b0;
    npb[p * KPAD + lane + 64] = b1;
    npb[p * KPAD + lane + 128] = b2;
    if (lane < 8) npb[p * KPAD + lane + 192] = b3;
    if (lane < 24) npb[p * KPAD + 200 + lane] = 0;

    unsigned short* npbT = (unsigned short*)(ws + OFF_NPBT);
    {
        int k0 = lane, k1 = lane + 64, k2 = lane + 128;
        npbT[(k0 >> 3) * (PPAD * 8) + p * 8 + (k0 & 7)] = b0;
        npbT[(k1 >> 3) * (PPAD * 8) + p * 8 + (k1 & 7)] = b1;
        npbT[(k2 >> 3) * (PPAD * 8) + p * 8 + (k2 & 7)] = b2;
        if (lane < 8) {
            int k3 = lane + 192;
            npbT[(k3 >> 3) * (PPAD * 8) + p * 8 + (k3 & 7)] = b3;
        }
        if (lane < 24) {
            int k4 = 200 + lane;
            npbT[(k4 >> 3) * (PPAD * 8) + p * 8 + (k4 & 7)] = 0;
        }
    }

    float a0 = fabsf(s0), a1 = fabsf(s1), a2 = fabsf(s2), a3 = fabsf(s3);

    int ch0 = -1, ch1 = -1, ch2 = -1;
    float cs0 = 0.f, cs1 = 0.f, cs2 = 0.f;

    for (int r = 0; r < 3; r++) {
        float bv = -1.0f;
        int bi = 1 << 30;
        {
            int n = lane;
            bool sk = (n == ch0) || (n == ch1) || (n == ch2);
            if (!sk && a0 > bv) { bv = a0; bi = n; }
        }
        {
            int n = lane + 64;
            bool sk = (n == ch0) || (n == ch1) || (n == ch2);
            if (!sk && (a1 > bv || (a1 == bv && n < bi))) { bv = a1; bi = n; }
        }
        {
            int n = lane + 128;
            bool sk = (n == ch0) || (n == ch1) || (n == ch2);
            if (!sk && (a2 > bv || (a2 == bv && n < bi))) { bv = a2; bi = n; }
        }
        if (lane < 8) {
            int n = lane + 192;
            bool sk = (n == ch0) || (n == ch1) || (n == ch2);
            if (!sk && (a3 > bv || (a3 == bv && n < bi))) { bv = a3; bi = n; }
        }
        for (int off = 32; off; off >>= 1) {
            float ov = __shfl_down(bv, off);
            int oi = __shfl_down(bi, off);
            if (ov > bv || (ov == bv && oi < bi)) { bv = ov; bi = oi; }
        }
        bi = __shfl(bi, 0);
        int slot = bi >> 6, src = bi & 63;
        float mine = (slot == 0) ? s0 : (slot == 1) ? s1 : (slot == 2) ? s2 : s3;
        float sval = __shfl(mine, src);
        if (r == 0) { ch0 = bi; cs0 = sval; }
        else if (r == 1) { ch1 = bi; cs1 = sval; }
        else { ch2 = bi; cs2 = sval; }
    }

    float d2 = 0.f;
    if (lane == 0) {
        float* keyval = ws + OFF_KEYVAL;
        int* keyidx = (int*)(ws + OFF_KEYIDX);
        keyval[p * 4 + 0] = cs0; keyval[p * 4 + 1] = cs1; keyval[p * 4 + 2] = cs2;
        keyval[p * 4 + 3] = 0.f;
        keyidx[p * 4 + 0] = ch0; keyidx[p * 4 + 1] = ch1; keyidx[p * 4 + 2] = ch2;
        keyidx[p * 4 + 3] = -1;
        float lenp = sqrtf(ss) * rn;
        float lentopp = sqrtf(cs0 * cs0 + cs1 * cs1 + cs2 * cs2);
        float d = 1.0f - lentopp / lenp;
        d2 = d * d * (1.0f / (float)P_);
    }
    return d2;
}

// == prep: zero gpool/pad (0..41) + pat (42..141) + tnorm (142..1421) ========
__global__ __launch_bounds__(256) void prep_kernel(const float* __restrict__ x,
                                                   const float* __restrict__ patterns,
                                                   float* __restrict__ ws) {
    __shared__ unsigned short xt16[64 * 210];   // bf16 staging (26.9 KB)
    __shared__ float psums[256];
    __shared__ float rns[64];
    __shared__ float sh4[4];

    const int tid = threadIdx.x;

    if (blockIdx.x < Z_ALL) {
        int zb = blockIdx.x;
        if (zb < ZG_BLKS) {
            // zero gpool: 614400 uint4 over 40 blocks
            uint4* gp4 = (uint4*)(ws + OFF_GPOOL);
            int base = zb * 15360 + tid;
#pragma unroll
            for (int i = 0; i < 60; ++i)
                gp4[base + i * 256] = make_uint4(0, 0, 0, 0);
        } else {
            // zero npbT pad rows [400..512) for all 28 segs: 12544 u32
            unsigned* p32 = (unsigned*)(ws + OFF_NPBT);
            int lb = zb - ZG_BLKS;     // 0..1
            for (int e = lb * 256 + tid; e < 12544; e += ZP_BLKS * 256) {
                int seg = e / 448, r32 = e % 448;
                p32[seg * 2048 + 1600 + r32] = 0u;
            }
        }
        return;
    }

    if (blockIdx.x < Z_ALL + PAT_BLKS) {
        int pblk = blockIdx.x - Z_ALL;
        int wv = tid >> 6, lane = tid & 63;
        int p = pblk * 4 + wv;
        float d2 = pat_body(patterns, ws, p, lane);
        if (lane == 0) sh4[wv] = d2;
        __syncthreads();
        if (tid == 0)
            ws[OFF_NORMB + pblk] = sh4[0] + sh4[1] + sh4[2] + sh4[3];
        return;
    }

    const int blk = blockIdx.x - Z_ALL - PAT_BLKS;
    const int t = tid & 63, r = tid >> 6;
    const int b = blk / 20;
    const int t0 = (blk % 20) * 64;          // 0..1216 (pad t zeroed below)
    const bool valid = (t0 + t) < T_;

    float ss = 0.0f;
    if (valid) {
        const float* xp = x + (size_t)b * N_ * T_ + t0 + t;
#pragma unroll 5
        for (int i = 0; i < 50; ++i) {
            int n = r * 50 + i;
            float v = xp[(size_t)n * T_];
            ss += v * v;
            xt16[t * 210 + n] = f2bf(v);
        }
    }
    psums[tid] = ss;
    __syncthreads();
    if (tid < 64) {
        float s = psums[tid] + psums[tid + 64] + psums[tid + 128] + psums[tid + 192];
        rns[tid] = rsqrtf(s + EPS_);
    }
    __syncthreads();

    // K-outer write: xnT[b][seg][t][8]; pad -> zeros
    unsigned short* xnT = (unsigned short*)(ws + OFF_XN);
#pragma unroll
    for (int j = 0; j < 7; ++j) {
        int idx = tid + 256 * j;            // 1792 = 28 segs x 64 t
        int seg = idx >> 6, tt = idx & 63;
        s8v ov = (s8v){0, 0, 0, 0, 0, 0, 0, 0};
        if (seg < 25 && (t0 + tt) < T_) {
            float rn = rns[tt];
            const unsigned* src = (const unsigned*)&xt16[tt * 210 + seg * 8];
            unsigned o[4];
#pragma unroll
            for (int i = 0; i < 4; ++i) {
                unsigned u = src[i];
                float lo = __uint_as_float(u << 16) * rn;
                float hi = __uint_as_float(u & 0xffff0000u) * rn;
                o[i] = (unsigned)f2bf(lo) | ((unsigned)f2bf(hi) << 16);
            }
            ov = (s8v){(short)(o[0] & 0xffff), (short)(o[0] >> 16),
                       (short)(o[1] & 0xffff), (short)(o[1] >> 16),
                       (short)(o[2] & 0xffff), (short)(o[2] >> 16),
                       (short)(o[3] & 0xffff), (short)(o[3] >> 16)};
        }
        *(s8v*)(xnT + (((size_t)b * 28 + seg) * TPAD + t0 + tt) * 8) = ov;
    }
}

// ======= work: gemm (nid 0..639, 5 mb-tiles each) + orth (640..659) =========
__global__ __launch_bounds__(256, 4) void work_kernel(float* __restrict__ ws,
                                                      unsigned* __restrict__ gpool) {
    __shared__ short ldsB[80 * BSTRIDE];       // 37.1 KB
    __shared__ unsigned pool[2 * 7 * 80];      // 4.5 KB

    const int tid = threadIdx.x;
    // bijective XCD swizzle over 660 blocks: q=82, r=4
    int orig = blockIdx.x;
    int xcd = orig & 7, rem = orig >> 3;
    int nid = (xcd < 4 ? xcd * 83 : 4 * 83 + (xcd - 4) * 82) + rem;

    const bool isOrth = (nid >= 640);
    int pb, mbg, b;
    if (isOrth) { int o = nid - 640; pb = o % 5; mbg = o / 5; b = 0; }
    else        { pb = nid % 5; mbg = (nid / 5) % 2; b = nid / 10; }

    const unsigned short* npb = (const unsigned short*)(ws + OFF_NPB16) + (size_t)(pb * 80) * KPAD;

    // stage B once: 80 rows x 224 shorts = 2240 16B units
#pragma unroll
    for (int j = 0; j < 9; ++j) {
        int idx = tid + 256 * j;
        if (idx < 2240) {
            int row = idx / 28, seg = idx % 28;
            *(s8v*)(&ldsB[row * BSTRIDE + seg * 8]) = *(const s8v*)(npb + (size_t)row * KPAD + seg * 8);
        }
    }
    for (int i = tid; i < 1120; i += 256) pool[i] = 0u;
    __syncthreads();

    const int wv = tid >> 6;
    const int lane = tid & 63;
    const int l15 = lane & 15, kg = lane >> 4;

    const int ROWS = isOrth ? PPAD : TPAD;
    const unsigned short* abase = isOrth
        ? (const unsigned short*)(ws + OFF_NPBT)
        : (const unsigned short*)(ws + OFF_XN) + (size_t)b * 28 * TPAD * 8;
    const int segstep = 4 * ROWS * 8;
    const int niter = isOrth ? 1 : 5;

    float orthpart = 0.f;

    for (int it = 0; it < niter; ++it) {
        const int mb = isOrth ? mbg : (mbg * 5 + it);
        const int row0 = mb * 128 + wv * 32 + l15;
        const unsigned short* ar0 = abase + ((size_t)kg * ROWS + row0) * 8;
        const unsigned short* ar1 = ar0 + 16 * 8;

        f4v acc[2][5];
#pragma unroll
        for (int mi = 0; mi < 2; ++mi)
#pragma unroll
            for (int ni = 0; ni < 5; ++ni) acc[mi][ni] = (f4v){0.f, 0.f, 0.f, 0.f};

        s8v A[4][2];
#pragma unroll
        for (int c = 0; c < 4; ++c) {
            A[c][0] = *(const s8v*)(ar0 + c * segstep);
            A[c][1] = *(const s8v*)(ar1 + c * segstep);
        }

#pragma unroll
        for (int c = 0; c < 7; ++c) {
            if (c + 4 < 7) {
                A[(c + 4) & 3][0] = *(const s8v*)(ar0 + (c + 4) * segstep);
                A[(c + 4) & 3][1] = *(const s8v*)(ar1 + (c + 4) * segstep);
            }
            s8v bf[5];
#pragma unroll
            for (int ni = 0; ni < 5; ++ni)
                bf[ni] = *(const s8v*)(&ldsB[(ni * 16 + l15) * BSTRIDE + c * 32 + kg * 8]);
#pragma unroll
            for (int ni = 0; ni < 5; ++ni) {
                acc[0][ni] = __builtin_amdgcn_mfma_f32_16x16x32_bf16(A[c & 3][0], bf[ni], acc[0][ni], 0, 0, 0);
                acc[1][ni] = __builtin_amdgcn_mfma_f32_16x16x32_bf16(A[c & 3][1], bf[ni], acc[1][ni], 0, 0, 0);
            }
        }

        if (isOrth) {
#pragma unroll
            for (int mi = 0; mi < 2; ++mi) {
                int rb = mb * 128 + wv * 32 + mi * 16 + kg * 4;
#pragma unroll
                for (int ni = 0; ni < 5; ++ni) {
                    int col = pb * 80 + ni * 16 + l15;
#pragma unroll
                    for (int jj = 0; jj < 4; ++jj) {
                        if (rb + jj == col) continue;
                        float t = (fabsf(acc[mi][ni][jj]) - 0.3f) * (1.0f / 0.70001f);
                        if (t > 0.0f) orthpart += t * t;
                    }
                }
            }
            break;
        }

        // okey pooling into LDS slots (single pass, pos+neg) — proven numerics
        const int wbase = (mb * 128) / 25;
#pragma unroll
        for (int mi = 0; mi < 2; ++mi) {
            int f0 = mb * 128 + wv * 32 + mi * 16 + kg * 4;
            int w0 = f0 / 25, w3 = (f0 + 3) / 25;
            int wsplit = w3 * 25;
#pragma unroll
            for (int ni = 0; ni < 5; ++ni) {
                int pc = ni * 16 + l15;
                float p0 = -1e30f, p1 = -1e30f, n0 = -1e30f, n1 = -1e30f;
#pragma unroll
                for (int jj = 0; jj < 4; ++jj) {
                    float v = acc[mi][ni][jj];
                    if (f0 + jj < wsplit) { p0 = fmaxf(p0, v); n0 = fmaxf(n0, -v); }
                    else                 { p1 = fmaxf(p1, v); n1 = fmaxf(n1, -v); }
                }
                atomicMax(&pool[(0 * 7 + (w3 - wbase)) * 80 + pc], okey(p1));
                atomicMax(&pool[(1 * 7 + (w3 - wbase)) * 80 + pc], okey(n1));
                if (w0 != w3) {
                    atomicMax(&pool[(0 * 7 + (w0 - wbase)) * 80 + pc], okey(p0));
                    atomicMax(&pool[(1 * 7 + (w0 - wbase)) * 80 + pc], okey(n0));
                }
            }
        }
        __syncthreads();
        // flush to global pool, re-zeroing in the same pass
        for (int e = tid; e < 1120; e += 256) {
            unsigned v = pool[e];
            pool[e] = 0u;
            if (!v) continue;
            int pass = e / 560, r2 = e % 560;
            int w = wbase + r2 / 80, p = r2 % 80;
            if (w < 48)
                atomicMax(&gpool[((size_t)(pass * B_ + b) * 48 + w) * 400 + pb * 80 + p], v);
        }
        __syncthreads();
    }

    if (isOrth) {
        for (int off = 32; off; off >>= 1) orthpart += __shfl_down(orthpart, off);
        __syncthreads();
        float* red = (float*)pool;
        if (lane == 0) red[wv] = orthpart;
        __syncthreads();
        if (tid == 0)
            ws[OFF_ORTHB + (nid - 640)] = (red[0] + red[1] + red[2] + red[3]) *
                                          (1.0f / ((float)P_ * (float)P_));
    }
}

// ======= pes: reduce gpool over windows -> PES (pure writes, no zero) =======
__global__ __launch_bounds__(256) void pes_kernel(const unsigned* __restrict__ gpool,
                                                  const int* __restrict__ length,
                                                  float* __restrict__ ws) {
    int idx = blockIdx.x * 256 + threadIdx.x;
    if (idx >= B_ * P_) return;
    int b = idx / P_;
    int p = idx - b * P_;
    const unsigned* gp0 = gpool + (size_t)b * 48 * 400 + p;
    const unsigned* gp1 = gpool + (size_t)(B_ + b) * 48 * 400 + p;
    float s = 0.f;
#pragma unroll
    for (int w = 0; w < 48; ++w)
        s += dekey(gp0[w * 400]) + dekey(gp1[w * 400]);
    float rsap = 1.0f / (float)(length[b] / STRIDE_);
    ws[OFF_PES + b * P_ + p] = s * 0.5f * rsap;
}

// ======= graphs_row: write-once row-gather (no pre-zero, no global atomics) ==
// 1600 blocks: b = blk/25, rows n0 = (blk%25)*8. Each block scans all 400
// patterns, accumulates hits into a zeroed LDS 8x200 row buffer, streams it.
__global__ __launch_bounds__(256) void graphs_row_kernel(const float* __restrict__ ws,
                                                         float* __restrict__ out) {
    __shared__ float rowbuf[8 * 200];      // 6.4 KB
    __shared__ int   ki[400][4];           // 6.4 KB
    __shared__ float kv[400][4];           // 6.4 KB
    __shared__ float el[400];              // 1.6 KB

    const int tid = threadIdx.x;
    const int b = blockIdx.x / 25;
    const int n0 = (blockIdx.x % 25) * 8;

    for (int i = tid; i < 1600; i += 256) rowbuf[i] = 0.f;
    for (int p = tid; p < 400; p += 256) {
        *(int4*)ki[p] = ((const int4*)(ws + OFF_KEYIDX))[p];
        *(float4*)kv[p] = ((const float4*)(ws + OFF_KEYVAL))[p];
        el[p] = ws[OFF_PES + b * P_ + p];
    }
    __syncthreads();

    for (int p = tid; p < 400; p += 256) {
        float e = el[p];
#pragma unroll
        for (int a = 0; a < 3; ++a) {
            int n = ki[p][a];
            if (n < n0 || n >= n0 + 8) continue;
            float va = kv[p][a] * e;
#pragma unroll
            for (int c = 0; c < 3; ++c) {
                float scale = (a == c) ? 1.0f : 6.0f;
                atomicAdd(&rowbuf[(n - n0) * 200 + ki[p][c]], va * kv[p][c] * scale);
            }
        }
    }
    __syncthreads();

    // stream the 8x200 chunk (exactly-once, coalesced float4)
    float4* dst = (float4*)(out + (size_t)b * N_ * N_ + (size_t)n0 * N_);
    const float4* srcb = (const float4*)rowbuf;
    for (int i = tid; i < 400; i += 256) dst[i] = srcb[i];

    // scalars (exactly-once, block 0)
    if (blockIdx.x == 0 && tid == 0) {
        float sn = 0.f;
        for (int i = 0; i < PAT_BLKS; ++i) sn += ws[OFF_NORMB + i];
        float so = 0.f;
        for (int i = 0; i < 20; ++i) so += ws[OFF_ORTHB + i];
        out[(size_t)B_ * N_ * N_] = sn;
        out[(size_t)B_ * N_ * N_ + 1] = so;
    }
}

// ---------------- fallback path (fp32, ws-size independent) -----------------
__global__ __launch_bounds__(256) void main_kernel(const float* __restrict__ x,
                                                   const int* __restrict__ length,
                                                   const float* __restrict__ ws,
                                                   float* __restrict__ pes) {
    __shared__ float xs[N_][STRIDE_ + 1];
    __shared__ float rnorm[STRIDE_];
    __shared__ float poolp[P_][5];
    __shared__ float pooln[P_][5];

    int w = blockIdx.x;
    int b = blockIdx.y;
    const float* xb = x + (size_t)b * N_ * T_ + (size_t)w * STRIDE_;

    for (int i = threadIdx.x; i < N_ * STRIDE_; i += 256) {
        int n = i / STRIDE_;
        int t = i - n * STRIDE_;
        xs[n][t] = xb[n * T_ + t];
    }
    __syncthreads();

    if (threadIdx.x < STRIDE_) {
        float ssf = 0.0f;
        for (int n = 0; n < N_; n++) { float vv = xs[n][threadIdx.x]; ssf += vv * vv; }
        rnorm[threadIdx.x] = 1.0f / sqrtf(ssf + EPS_);
    }
    __syncthreads();

    int pt = threadIdx.x % 50;
    int tt = threadIdx.x / 50;

    if (tt < 5) {
        float acc[8][5];
#pragma unroll
        for (int i = 0; i < 8; i++)
#pragma unroll
            for (int j = 0; j < 5; j++) acc[i][j] = 0.0f;

        const float4* np4 = (const float4*)(ws + OFF_NPATT);
        int pbq = pt * 2;
        for (int n = 0; n < N_; n++) {
            float4 q0 = np4[n * (P_ / 4) + pbq];
            float4 q1 = np4[n * (P_ / 4) + pbq + 1];
            float qa[8] = { q0.x, q0.y, q0.z, q0.w, q1.x, q1.y, q1.z, q1.w };
            float xv0 = xs[n][tt * 5 + 0];
            float xv1 = xs[n][tt * 5 + 1];
            float xv2 = xs[n][tt * 5 + 2];
            float xv3 = xs[n][tt * 5 + 3];
            float xv4 = xs[n][tt * 5 + 4];
#pragma unroll
            for (int i = 0; i < 8; i++) {
                acc[i][0] += qa[i] * xv0;
                acc[i][1] += qa[i] * xv1;
                acc[i][2] += qa[i] * xv2;
                acc[i][3] += qa[i] * xv3;
                acc[i][4] += qa[i] * xv4;
            }
        }
#pragma unroll
        for (int i = 0; i < 8; i++) {
            float pm = -1e30f, nm = -1e30f;
#pragma unroll
            for (int j = 0; j < 5; j++) {
                float s = acc[i][j] * rnorm[tt * 5 + j];
                pm = fmaxf(pm, s);
                nm = fmaxf(nm, -s);
            }
            poolp[pt * 8 + i][tt] = pm;
            pooln[pt * 8 + i][tt] = nm;
        }
    }
    __syncthreads();

    float rsap = 1.0f / (float)(length[b] / STRIDE_);
    for (int p = threadIdx.x; p < P_; p += 256) {
        float pm = poolp[p][0], nm = pooln[p][0];
#pragma unroll
        for (int q = 1; q < 5; q++) {
            pm = fmaxf(pm, poolp[p][q]);
            nm = fmaxf(nm, pooln[p][q]);
        }
        atomicAdd(&pes[b * P_ + p], (pm + nm) * 0.5f * rsap);
    }
}

__global__ __launch_bounds__(256) void fb_graphs_kernel(const float* __restrict__ ws,
                                                        float* __restrict__ out) {
    int idx = blockIdx.x * 256 + threadIdx.x;
    if (idx == 0) {
        out[(size_t)B_ * N_ * N_] = ws[OFF_NORM];
        out[(size_t)B_ * N_ * N_ + 1] = ws[OFF_ORTH];
    }
    if (idx >= B_ * P_) return;
    int b = idx / P_;
    int p = idx - b * P_;
    float e = ws[OFF_PES + b * P_ + p];
    const float* keyval = ws + OFF_KEYVAL;
    const int* keyidx = (const int*)(ws + OFF_KEYIDX);
    float va[3] = { keyval[p * 4 + 0], keyval[p * 4 + 1], keyval[p * 4 + 2] };
    int ia[3] = { keyidx[p * 4 + 0], keyidx[p * 4 + 1], keyidx[p * 4 + 2] };
    float* g = out + (size_t)b * N_ * N_;
#pragma unroll
    for (int a = 0; a < 3; a++)
#pragma unroll
        for (int c = 0; c < 3; c++) {
            float scale = (ia[a] == ia[c]) ? 1.0f : 6.0f;
            atomicAdd(&g[ia[a] * N_ + ia[c]], va[a] * va[c] * e * scale);
        }
}

__global__ __launch_bounds__(64) void pat_kernel(const float* __restrict__ patterns,
                                                 float* __restrict__ ws) {
    float d2 = pat_body(patterns, ws, blockIdx.x, threadIdx.x & 63);
    if (threadIdx.x == 0) atomicAdd(ws + OFF_NORM, d2);
}
__global__ __launch_bounds__(256) void orth_kernel(float* __restrict__ ws) {
    __shared__ float rowi[N_];
    __shared__ float red[256];
    const float* npatT = ws + OFF_NPATT;
    int i = blockIdx.x;
    for (int k = threadIdx.x; k < N_; k += 256) rowi[k] = npatT[k * P_ + i];
    __syncthreads();
    float partial = 0.0f;
    for (int j = threadIdx.x; j < P_; j += 256) {
        if (j == i) continue;
        float s = 0.0f;
        for (int k = 0; k < N_; k++) s += rowi[k] * npatT[k * P_ + j];
        float t = (fabsf(s) - 0.3f) * (1.0f / 0.70001f);
        if (t > 0.0f) partial += t * t;
    }
    red[threadIdx.x] = partial;
    __syncthreads();
    for (int sft = 128; sft; sft >>= 1) {
        if (threadIdx.x < sft) red[threadIdx.x] += red[threadIdx.x + sft];
        __syncthreads();
    }
    if (threadIdx.x == 0)
        atomicAdd(ws + OFF_ORTH, red[0] * (1.0f / ((float)P_ * (float)P_)));
}

extern "C" void kernel_launch(void* const* d_in, const int* in_sizes, int n_in,
                              void* d_out, int out_size, void* d_ws, size_t ws_size,
                              hipStream_t stream) {
    const float* x = (const float*)d_in[0];
    const float* patterns = (const float*)d_in[1];
    const int* length = (const int*)d_in[2];
    float* out = (float*)d_out;
    float* ws = (float*)d_ws;

    if (ws_size >= (size_t)WS_FAST_FLOATS * sizeof(float)) {
        unsigned* gpool = (unsigned*)(ws + OFF_GPOOL);
        prep_kernel<<<PREP_BLKS, 256, 0, stream>>>(x, patterns, ws);
        work_kernel<<<660, 256, 0, stream>>>(ws, gpool);
        pes_kernel<<<(B_ * P_ + 255) / 256, 256, 0, stream>>>(gpool, length, ws);
        graphs_row_kernel<<<B_ * 25, 256, 0, stream>>>(ws, out);
    } else {
        hipMemsetAsync(d_out, 0, (size_t)B_ * N_ * N_ * sizeof(float), stream);
        hipMemsetAsync(ws + OFF_PES, 0, (size_t)(B_ * P_) * sizeof(float), stream);
        hipMemsetAsync(ws + OFF_NORM, 0, sizeof(float), stream);
        hipMemsetAsync(ws + OFF_ORTH, 0, sizeof(float), stream);
        pat_kernel<<<P_, 64, 0, stream>>>(patterns, ws);
        orth_kernel<<<P_, 256, 0, stream>>>(ws);
        main_kernel<<<dim3(T_ / STRIDE_, B_), 256, 0, stream>>>(x, length, ws, ws + OFF_PES);
        fb_graphs_kernel<<<(B_ * P_ + 255) / 256, 256, 0, stream>>>(ws, out);
    }
}